// Round 1
// baseline (1556.790 us; speedup 1.0000x reference)
//
#include <hip/hip_runtime.h>
#include <hip/hip_bf16.h>

#define TB 2
#define TT 2048
#define TD 256
#define TE 64
#define TF 512
#define TN 4096      // TB*TT
#define TCAP 128     // 2*TN/TE
#define NITER 8

typedef __attribute__((ext_vector_type(8))) short bf16x8;
typedef __attribute__((ext_vector_type(4))) float f32x4;

__device__ inline float sanitize(float v){
  if (v != v) return 0.0f;
  const float FMAX = 3.402823466e+38f;
  if (v >  FMAX) return  FMAX;
  if (v < -FMAX) return -FMAX;
  return v;
}

__device__ inline short f2bf(float f){
  union { __hip_bfloat16 h; short s; } u;
  u.h = __float2bfloat16(f);
  return u.s;
}

__device__ inline float gelu_tanh(float x){
  float x3 = x*x*x;
  return 0.5f*x*(1.0f + tanhf(0.7978845608028654f*(x + 0.044715f*x3)));
}

// ---------------- setup kernels ----------------

// sanitize x -> x_work ; build x_target (t==0: x[0], else phase-rotated x[t-1])
__global__ void k_init(const float* __restrict__ xs, const float* __restrict__ cosp,
                       const float* __restrict__ sinp, float* __restrict__ xw,
                       float* __restrict__ xt){
  int idx = blockIdx.x*256 + threadIdx.x;          // over TN*TD
  if (idx >= TN*TD) return;
  int d = idx & (TD-1);
  int n = idx >> 8;                                 // TD = 256
  int t = n & (TT-1);
  float xr = sanitize(xs[2*idx]), xi = sanitize(xs[2*idx+1]);
  xw[2*idx] = xr; xw[2*idx+1] = xi;
  float tr, ti;
  if (t == 0){ tr = xr; ti = xi; }
  else {
    float pr = sanitize(xs[2*(idx-TD)]), pi = sanitize(xs[2*(idx-TD)+1]);
    float c = cosp[d], s = sinp[d];
    tr = pr*c - pi*s;
    ti = pr*s + pi*c;
  }
  xt[2*idx] = tr; xt[2*idx+1] = ti;
}

// gate_bias[n][e] = sum_d mag[n][d] * Wg[d][e]
__global__ __launch_bounds__(64) void k_gatebias(const float* __restrict__ xw,
                                                 const float* __restrict__ wg,
                                                 float* __restrict__ gb){
  __shared__ float mag[TD];
  int n = blockIdx.x, t = threadIdx.x;
  for (int d = t; d < TD; d += 64){
    float xr = xw[(size_t)n*TF + 2*d], xi = xw[(size_t)n*TF + 2*d + 1];
    mag[d] = sqrtf(xr*xr + xi*xi + 1e-8f);
  }
  __syncthreads();
  float acc = 0.f;
  for (int d = 0; d < TD; d++) acc += mag[d]*wg[d*TE + t];
  gb[(size_t)n*TE + t] = acc;
}

// ---------------- per-iteration kernels ----------------

// x_eff = x + sum_tau gains[tau] (*complex) x[t-tau]; write f32 + bf16 copies
__global__ void k_delay(const float* __restrict__ xw, const float* __restrict__ g,
                        float* __restrict__ xe, short* __restrict__ xbf){
  int idx = blockIdx.x*256 + threadIdx.x;          // over TN*TD
  if (idx >= TN*TD) return;
  int d = idx & (TD-1);
  int n = idx >> 8;
  int t = n & (TT-1);
  float ar = xw[2*idx], ai = xw[2*idx+1];
  const int taus[4] = {1,2,3,5};
  #pragma unroll
  for (int i = 0; i < 4; i++){
    int tau = taus[i];
    if (t >= tau){
      float pr = xw[2*(idx - tau*TD)], pi = xw[2*(idx - tau*TD)+1];
      float gr = g[2*(i*TD + d)],      gi = g[2*(i*TD + d)+1];
      ar += pr*gr - pi*gi;
      ai += pr*gi + pi*gr;
    }
  }
  xe[2*idx] = ar; xe[2*idx+1] = ai;
  xbf[2*idx] = f2bf(ar); xbf[2*idx+1] = f2bf(ai);
}

// logits = xf @ Wr + gate_bias; softmax over E; write scoresT[e][n]. 8 tokens/block.
__global__ __launch_bounds__(64) void k_router(const float* __restrict__ xe,
                                               const float* __restrict__ wr,
                                               const float* __restrict__ gb,
                                               float* __restrict__ scoresT){
  __shared__ float xrow[8][TF];
  int n0 = blockIdx.x * 8;
  int t = threadIdx.x;
  for (int q = 0; q < 8; q++){
    const float4* src = (const float4*)(xe + (size_t)(n0+q)*TF);
    float4* dst = (float4*)xrow[q];
    for (int i = t; i < TF/4; i += 64) dst[i] = src[i];
  }
  __syncthreads();
  float acc[8];
  #pragma unroll
  for (int q = 0; q < 8; q++) acc[q] = gb[(size_t)(n0+q)*TE + t];
  for (int k = 0; k < TF; k++){
    float w = wr[k*TE + t];
    #pragma unroll
    for (int q = 0; q < 8; q++) acc[q] += xrow[q][k]*w;
  }
  for (int q = 0; q < 8; q++){
    float m = acc[q];
    for (int off = 32; off; off >>= 1) m = fmaxf(m, __shfl_xor(m, off));
    float ex = expf(acc[q] - m);
    float s = ex;
    for (int off = 32; off; off >>= 1) s += __shfl_xor(s, off);
    scoresT[(size_t)t*TN + (n0+q)] = ex / s;
  }
}

// per-expert exact top-128 via radix select on positive-float bits
__global__ __launch_bounds__(256) void k_topk(const float* __restrict__ scoresT,
                                              int* __restrict__ topi, float* __restrict__ topv){
  int e = blockIdx.x;
  const float* sc = scoresT + (size_t)e*TN;
  __shared__ unsigned int hist[256];
  __shared__ unsigned int s_prefix;
  __shared__ int s_k, s_cnt, s_min;
  int tid = threadIdx.x;
  if (tid == 0){ s_prefix = 0u; s_k = TCAP; }
  __syncthreads();
  for (int pass = 0; pass < 4; pass++){
    int shift = 24 - 8*pass;
    for (int i = tid; i < 256; i += 256) hist[i] = 0u;
    __syncthreads();
    unsigned int pmask = (pass == 0) ? 0u : (0xFFFFFFFFu << (shift + 8));
    unsigned int pref = s_prefix;
    for (int nn = tid; nn < TN; nn += 256){
      unsigned int u = __float_as_uint(sc[nn]);
      if ((u & pmask) == pref) atomicAdd(&hist[(u >> shift) & 255], 1u);
    }
    __syncthreads();
    if (tid == 0){
      int k = s_k; unsigned int cum = 0; int dg = 0;
      for (dg = 255; dg >= 0; dg--){
        if (cum + hist[dg] >= (unsigned)k) break;
        cum += hist[dg];
      }
      s_k = k - (int)cum;
      s_prefix = pref | ((unsigned)dg << shift);
    }
    __syncthreads();
  }
  unsigned int thr = s_prefix;
  int need_eq = s_k;
  if (tid == 0) s_cnt = 0;
  __syncthreads();
  // strictly greater than threshold (set-exact; order irrelevant for scatter-add)
  for (int nn = tid; nn < TN; nn += 256){
    unsigned int u = __float_as_uint(sc[nn]);
    if (u > thr){
      int p = atomicAdd(&s_cnt, 1);
      topi[e*TCAP + p] = nn;
      topv[e*TCAP + p] = sc[nn];
    }
  }
  __syncthreads();
  int base = s_cnt;   // == TCAP - need_eq
  int last = -1;
  for (int i = 0; i < need_eq; i++){   // equal values: lowest indices first (jax tie-break)
    if (tid == 0) s_min = TN;
    __syncthreads();
    for (int nn = tid; nn < TN; nn += 256){
      if (nn > last && __float_as_uint(sc[nn]) == thr) atomicMin(&s_min, nn);
    }
    __syncthreads();
    int nsel = s_min;
    if (tid == 0){ topi[e*TCAP + base + i] = nsel; topv[e*TCAP + base + i] = sc[nsel]; }
    last = nsel;
    __syncthreads();
  }
}

// h[e] = gelu(xe_gathered @ W1[e]); 128x64 tile per block, bf16 MFMA 16x16x32
__global__ __launch_bounds__(256) void k_gemm1(const short* __restrict__ xbf,
                                               const float* __restrict__ W1,
                                               const int* __restrict__ topi,
                                               short* __restrict__ hbf){
  __shared__ __align__(16) short As[128][40];
  __shared__ __align__(16) short Bs[64][40];   // transposed: [col][k]
  __shared__ int rows[128];
  int e = blockIdx.y, n0 = blockIdx.x*64;
  int tid = threadIdx.x;
  if (tid < 128) rows[tid] = topi[e*TCAP + tid];
  __syncthreads();
  int w = tid >> 6, l = tid & 63;
  int lr = l & 15, lh = l >> 4;
  f32x4 acc[2][4];
  #pragma unroll
  for (int m = 0; m < 2; m++)
    #pragma unroll
    for (int j = 0; j < 4; j++)
      #pragma unroll
      for (int r = 0; r < 4; r++) acc[m][j][r] = 0.f;

  int am = tid >> 1, aseg = (tid & 1)*16;
  int br = tid >> 4, bc = (tid & 15)*4;
  const size_t arow = (size_t)rows[am]*TF;
  const float* Wbase = W1 + (size_t)e*TF*TF + n0;

  for (int kk = 0; kk < TF; kk += 32){
    const bf16x8* asrc = (const bf16x8*)(xbf + arow + kk + aseg);
    *(bf16x8*)&As[am][aseg]     = asrc[0];
    *(bf16x8*)&As[am][aseg + 8] = asrc[1];
    #pragma unroll
    for (int rr = br; rr < 32; rr += 16){
      float4 v = *(const float4*)(Wbase + (size_t)(kk+rr)*TF + bc);
      Bs[bc+0][rr] = f2bf(v.x); Bs[bc+1][rr] = f2bf(v.y);
      Bs[bc+2][rr] = f2bf(v.z); Bs[bc+3][rr] = f2bf(v.w);
    }
    __syncthreads();
    bf16x8 a0 = *(const bf16x8*)&As[32*w + lr][lh*8];
    bf16x8 a1 = *(const bf16x8*)&As[32*w + 16 + lr][lh*8];
    #pragma unroll
    for (int j = 0; j < 4; j++){
      bf16x8 b = *(const bf16x8*)&Bs[16*j + lr][lh*8];
      acc[0][j] = __builtin_amdgcn_mfma_f32_16x16x32_bf16(a0, b, acc[0][j], 0, 0, 0);
      acc[1][j] = __builtin_amdgcn_mfma_f32_16x16x32_bf16(a1, b, acc[1][j], 0, 0, 0);
    }
    __syncthreads();
  }
  short* hdst = hbf + (size_t)e*TCAP*TF;
  #pragma unroll
  for (int m = 0; m < 2; m++)
    #pragma unroll
    for (int j = 0; j < 4; j++)
      #pragma unroll
      for (int r = 0; r < 4; r++){
        int row = 32*w + 16*m + lh*4 + r;
        int col = n0 + 16*j + lr;
        hdst[(size_t)row*TF + col] = f2bf(gelu_tanh(acc[m][j][r]));
      }
}

// ye[e] = (h[e] @ W2[e]) * topv; atomic scatter-add into pred
__global__ __launch_bounds__(256) void k_gemm2(const short* __restrict__ hbf,
                                               const float* __restrict__ W2,
                                               const int* __restrict__ topi,
                                               const float* __restrict__ topv,
                                               float* __restrict__ pred){
  __shared__ __align__(16) short As[128][40];
  __shared__ __align__(16) short Bs[64][40];
  __shared__ int rows[128];
  __shared__ float tv[128];
  int e = blockIdx.y, n0 = blockIdx.x*64;
  int tid = threadIdx.x;
  if (tid < 128){ rows[tid] = topi[e*TCAP + tid]; tv[tid] = topv[e*TCAP + tid]; }
  __syncthreads();
  int w = tid >> 6, l = tid & 63;
  int lr = l & 15, lh = l >> 4;
  f32x4 acc[2][4];
  #pragma unroll
  for (int m = 0; m < 2; m++)
    #pragma unroll
    for (int j = 0; j < 4; j++)
      #pragma unroll
      for (int r = 0; r < 4; r++) acc[m][j][r] = 0.f;

  int am = tid >> 1, aseg = (tid & 1)*16;
  int br = tid >> 4, bc = (tid & 15)*4;
  const short* asrcbase = hbf + ((size_t)e*TCAP + am)*TF;
  const float* Wbase = W2 + (size_t)e*TF*TF + n0;

  for (int kk = 0; kk < TF; kk += 32){
    const bf16x8* asrc = (const bf16x8*)(asrcbase + kk + aseg);
    *(bf16x8*)&As[am][aseg]     = asrc[0];
    *(bf16x8*)&As[am][aseg + 8] = asrc[1];
    #pragma unroll
    for (int rr = br; rr < 32; rr += 16){
      float4 v = *(const float4*)(Wbase + (size_t)(kk+rr)*TF + bc);
      Bs[bc+0][rr] = f2bf(v.x); Bs[bc+1][rr] = f2bf(v.y);
      Bs[bc+2][rr] = f2bf(v.z); Bs[bc+3][rr] = f2bf(v.w);
    }
    __syncthreads();
    bf16x8 a0 = *(const bf16x8*)&As[32*w + lr][lh*8];
    bf16x8 a1 = *(const bf16x8*)&As[32*w + 16 + lr][lh*8];
    #pragma unroll
    for (int j = 0; j < 4; j++){
      bf16x8 b = *(const bf16x8*)&Bs[16*j + lr][lh*8];
      acc[0][j] = __builtin_amdgcn_mfma_f32_16x16x32_bf16(a0, b, acc[0][j], 0, 0, 0);
      acc[1][j] = __builtin_amdgcn_mfma_f32_16x16x32_bf16(a1, b, acc[1][j], 0, 0, 0);
    }
    __syncthreads();
  }
  #pragma unroll
  for (int m = 0; m < 2; m++)
    #pragma unroll
    for (int j = 0; j < 4; j++)
      #pragma unroll
      for (int r = 0; r < 4; r++){
        int row = 32*w + 16*m + lh*4 + r;
        int col = n0 + 16*j + lr;
        float v = acc[m][j][r] * tv[row];
        atomicAdd(&pred[(size_t)rows[row]*TF + col], v);
      }
}

// x += clip(0.05*(x_target - pred), -10, 10)
__global__ void k_update(float* __restrict__ xw, const float* __restrict__ xt,
                         const float* __restrict__ pred){
  int i = blockIdx.x*256 + threadIdx.x;
  if (i >= TN*TF) return;
  float u = 0.05f*(xt[i] - pred[i]);
  u = fminf(10.0f, fmaxf(-10.0f, u));
  xw[i] += u;
}

extern "C" void kernel_launch(void* const* d_in, const int* in_sizes, int n_in,
                              void* d_out, int out_size, void* d_ws, size_t ws_size,
                              hipStream_t stream){
  (void)in_sizes; (void)n_in; (void)out_size; (void)ws_size;
  const float* x_stream = (const float*)d_in[0];
  const float* gains    = (const float*)d_in[1];
  const float* Wg       = (const float*)d_in[2];
  const float* Wr       = (const float*)d_in[3];
  const float* W1       = (const float*)d_in[4];
  const float* W2       = (const float*)d_in[5];
  const float* cosp     = (const float*)d_in[6];
  const float* sinp     = (const float*)d_in[7];
  // d_in[8] = local_iters (device scalar) == 8 per setup_inputs; loop count fixed.

  size_t off = 0;
  char* base = (char*)d_ws;
  auto alloc = [&](size_t bytes) -> void* {
    void* p = base + off;
    off += (bytes + 255) & ~(size_t)255;
    return p;
  };
  float* x_work  = (float*)alloc((size_t)TN*TF*4);
  float* x_targ  = (float*)alloc((size_t)TN*TF*4);
  float* x_eff   = (float*)alloc((size_t)TN*TF*4);
  short* xf_bf   = (short*)alloc((size_t)TN*TF*2);
  float* gateb   = (float*)alloc((size_t)TN*TE*4);
  float* scoresT = (float*)alloc((size_t)TE*TN*4);
  int*   topi    = (int*)  alloc((size_t)TE*TCAP*4);
  float* topv    = (float*)alloc((size_t)TE*TCAP*4);
  short* h_bf    = (short*)alloc((size_t)TE*TCAP*TF*2);
  float* pred    = (float*)alloc((size_t)TN*TF*4);

  k_init<<<(TN*TD + 255)/256, 256, 0, stream>>>(x_stream, cosp, sinp, x_work, x_targ);
  k_gatebias<<<TN, 64, 0, stream>>>(x_work, Wg, gateb);

  for (int it = 0; it < NITER; it++){
    k_delay<<<(TN*TD + 255)/256, 256, 0, stream>>>(x_work, gains, x_eff, xf_bf);
    k_router<<<TN/8, 64, 0, stream>>>(x_eff, Wr, gateb, scoresT);
    k_topk<<<TE, 256, 0, stream>>>(scoresT, topi, topv);
    hipMemsetAsync(pred, 0, (size_t)TN*TF*4, stream);
    k_gemm1<<<dim3(TF/64, TE), 256, 0, stream>>>(xf_bf, W1, topi, h_bf);
    k_gemm2<<<dim3(TF/64, TE), 256, 0, stream>>>(h_bf, W2, topi, topv, pred);
    k_update<<<(TN*TF + 255)/256, 256, 0, stream>>>(x_work, x_targ, pred);
  }
  hipMemcpyAsync(d_out, x_work, (size_t)TN*TF*4, hipMemcpyDeviceToDevice, stream);
}

// Round 3
// 854.507 us; speedup vs baseline: 1.8219x; 1.8219x over previous
//
#include <hip/hip_runtime.h>
#include <hip/hip_bf16.h>

#define TB 2
#define TT 2048
#define TD 256
#define TE 64
#define TF 512
#define TN 4096      // TB*TT
#define TCAP 128     // 2*TN/TE
#define NITER 8

typedef __attribute__((ext_vector_type(8))) short bf16x8;
typedef __attribute__((ext_vector_type(4))) float f32x4;

__device__ inline float sanitize(float v){
  if (v != v) return 0.0f;
  const float FMAX = 3.402823466e+38f;
  if (v >  FMAX) return  FMAX;
  if (v < -FMAX) return -FMAX;
  return v;
}

__device__ inline short f2bf(float f){
  union { __hip_bfloat16 h; short s; } u;
  u.h = __float2bfloat16(f);
  return u.s;
}

__device__ inline float gelu_tanh(float x){
  float x3 = x*x*x;
  return 0.5f*x*(1.0f + tanhf(0.7978845608028654f*(x + 0.044715f*x3)));
}

// ---------------- setup kernels ----------------

__global__ void k_init(const float* __restrict__ xs, const float* __restrict__ cosp,
                       const float* __restrict__ sinp, float* __restrict__ xw,
                       float* __restrict__ xt){
  int idx = blockIdx.x*256 + threadIdx.x;          // over TN*TD
  if (idx >= TN*TD) return;
  int d = idx & (TD-1);
  int n = idx >> 8;
  int t = n & (TT-1);
  float xr = sanitize(xs[2*idx]), xi = sanitize(xs[2*idx+1]);
  xw[2*idx] = xr; xw[2*idx+1] = xi;
  float tr, ti;
  if (t == 0){ tr = xr; ti = xi; }
  else {
    float pr = sanitize(xs[2*(idx-TD)]), pi = sanitize(xs[2*(idx-TD)+1]);
    float c = cosp[d], s = sinp[d];
    tr = pr*c - pi*s;
    ti = pr*s + pi*c;
  }
  xt[2*idx] = tr; xt[2*idx+1] = ti;
}

__global__ __launch_bounds__(64) void k_gatebias(const float* __restrict__ xw,
                                                 const float* __restrict__ wg,
                                                 float* __restrict__ gb){
  __shared__ float mag[TD];
  int n = blockIdx.x, t = threadIdx.x;
  for (int d = t; d < TD; d += 64){
    float xr = xw[(size_t)n*TF + 2*d], xi = xw[(size_t)n*TF + 2*d + 1];
    mag[d] = sqrtf(xr*xr + xi*xi + 1e-8f);
  }
  __syncthreads();
  float acc = 0.f;
  for (int d = 0; d < TD; d++) acc += mag[d]*wg[d*TE + t];
  gb[(size_t)n*TE + t] = acc;
}

// cast+transpose weights: in f32 [e][k][n] -> out bf16 [e][n][k]
__global__ __launch_bounds__(256) void k_castw(const float* __restrict__ W, short* __restrict__ Wt){
  __shared__ float tile[64][68];
  int e = blockIdx.y;
  int kt = (blockIdx.x >> 3) * 64;
  int nt = (blockIdx.x & 7) * 64;
  int tid = threadIdx.x;
  {
    int row = tid >> 4;
    int c4 = (tid & 15) * 4;
    #pragma unroll
    for (int i = 0; i < 4; i++){
      int r = row + i*16;
      float4 v = *(const float4*)(W + ((size_t)e*TF + kt + r)*TF + nt + c4);
      *(float4*)&tile[r][c4] = v;
    }
  }
  __syncthreads();
  #pragma unroll
  for (int i = 0; i < 2; i++){
    int un = tid + i*256;
    int nrow = un >> 3;
    int k8 = (un & 7) * 8;
    bf16x8 o;
    #pragma unroll
    for (int j = 0; j < 8; j++) o[j] = f2bf(tile[k8+j][nrow]);
    *(bf16x8*)(Wt + ((size_t)e*TF + nt + nrow)*TF + kt + k8) = o;
  }
}

// ---------------- per-iteration kernels ----------------

__global__ void k_delay(const float* __restrict__ xw, const float* __restrict__ g,
                        float* __restrict__ xe, short* __restrict__ xbf){
  int idx = blockIdx.x*256 + threadIdx.x;          // over TN*TD
  if (idx >= TN*TD) return;
  int d = idx & (TD-1);
  int n = idx >> 8;
  int t = n & (TT-1);
  float ar = xw[2*idx], ai = xw[2*idx+1];
  const int taus[4] = {1,2,3,5};
  #pragma unroll
  for (int i = 0; i < 4; i++){
    int tau = taus[i];
    if (t >= tau){
      float pr = xw[2*(idx - tau*TD)], pi = xw[2*(idx - tau*TD)+1];
      float gr = g[2*(i*TD + d)],      gi = g[2*(i*TD + d)+1];
      ar += pr*gr - pi*gi;
      ai += pr*gi + pi*gr;
    }
  }
  xe[2*idx] = ar; xe[2*idx+1] = ai;
  xbf[2*idx] = f2bf(ar); xbf[2*idx+1] = f2bf(ai);
}

// tiled f32 router GEMM + fused softmax. 32 tok x 64 exp per block, 256 thr.
__global__ __launch_bounds__(256) void k_router2(const float* __restrict__ xe,
                                                 const float* __restrict__ wr,
                                                 const float* __restrict__ gb,
                                                 float* __restrict__ scoresT){
  __shared__ float At[64][34];   // [k][tok]
  __shared__ float Bt[64][68];   // [k][e]
  int n0 = blockIdx.x * 32;
  int tid = threadIdx.x;
  int ty = tid >> 4;    // 0..15 -> token pair
  int tx = tid & 15;    // expert quad
  float acc[2][4];
  #pragma unroll
  for (int q = 0; q < 2; q++){
    int n = n0 + 2*ty + q;
    #pragma unroll
    for (int j = 0; j < 4; j++) acc[q][j] = gb[(size_t)n*TE + 4*tx + j];
  }
  int tokA = tid >> 3;            // 0..31
  int ksegA = (tid & 7) * 8;      // 0..56
  int rB = tid >> 2;              // 0..63
  int c16B = (tid & 3) * 16;      // 16 consecutive experts per thread
  for (int kk = 0; kk < TF; kk += 64){
    {
      const float4* src = (const float4*)(xe + (size_t)(n0+tokA)*TF + kk + ksegA);
      float4 v0 = src[0], v1 = src[1];
      At[ksegA+0][tokA]=v0.x; At[ksegA+1][tokA]=v0.y; At[ksegA+2][tokA]=v0.z; At[ksegA+3][tokA]=v0.w;
      At[ksegA+4][tokA]=v1.x; At[ksegA+5][tokA]=v1.y; At[ksegA+6][tokA]=v1.z; At[ksegA+7][tokA]=v1.w;
    }
    #pragma unroll
    for (int jj = 0; jj < 4; jj++)
      *(float4*)&Bt[rB][c16B + 4*jj] =
        *(const float4*)(wr + (size_t)(kk+rB)*TE + c16B + 4*jj);
    __syncthreads();
    #pragma unroll
    for (int k = 0; k < 64; k++){
      float2 a = *(const float2*)&At[k][2*ty];
      float4 b = *(const float4*)&Bt[k][4*tx];
      acc[0][0] += a.x*b.x; acc[0][1] += a.x*b.y; acc[0][2] += a.x*b.z; acc[0][3] += a.x*b.w;
      acc[1][0] += a.y*b.x; acc[1][1] += a.y*b.y; acc[1][2] += a.y*b.z; acc[1][3] += a.y*b.w;
    }
    __syncthreads();
  }
  #pragma unroll
  for (int q = 0; q < 2; q++){
    float m = fmaxf(fmaxf(acc[q][0],acc[q][1]), fmaxf(acc[q][2],acc[q][3]));
    #pragma unroll
    for (int off = 1; off < 16; off <<= 1) m = fmaxf(m, __shfl_xor(m, off));
    float e0 = expf(acc[q][0]-m), e1 = expf(acc[q][1]-m);
    float e2 = expf(acc[q][2]-m), e3 = expf(acc[q][3]-m);
    float s = e0+e1+e2+e3;
    #pragma unroll
    for (int off = 1; off < 16; off <<= 1) s += __shfl_xor(s, off);
    float inv = 1.0f / s;
    int n = n0 + 2*ty + q;
    scoresT[(size_t)(4*tx+0)*TN + n] = e0*inv;
    scoresT[(size_t)(4*tx+1)*TN + n] = e1*inv;
    scoresT[(size_t)(4*tx+2)*TN + n] = e2*inv;
    scoresT[(size_t)(4*tx+3)*TN + n] = e3*inv;
  }
}

// per-expert exact top-128: registers + 3-round radix (12/12/8 bits), parallel threshold find
__global__ __launch_bounds__(1024) void k_topk2(const float* __restrict__ scoresT,
                                                int* __restrict__ topi, float* __restrict__ topv){
  int e = blockIdx.x;
  const float* sc = scoresT + (size_t)e*TN;
  __shared__ unsigned int hist[4096];
  __shared__ unsigned int chunkSum[64];
  __shared__ unsigned int s_prefix;
  __shared__ int s_k, s_cnt, s_min;
  int tid = threadIdx.x;
  unsigned int u[4];
  #pragma unroll
  for (int i = 0; i < 4; i++) u[i] = __float_as_uint(sc[tid + i*1024]);
  if (tid == 0){ s_prefix = 0u; s_k = TCAP; }

  const int shifts[3]  = {20, 8, 0};
  const int nbins[3]   = {4096, 4096, 256};
  const unsigned int pmasks[3] = {0u, 0xFFF00000u, 0xFFFFFF00u};
  for (int r = 0; r < 3; r++){
    int shift = shifts[r], nb = nbins[r];
    unsigned int bmask = (unsigned)nb - 1u;
    int logC = (nb == 4096) ? 6 : 2;     // bins per chunk: nb/64
    for (int i = tid; i < nb; i += 1024) hist[i] = 0u;
    if (tid < 64) chunkSum[tid] = 0u;
    __syncthreads();
    unsigned int pref = s_prefix;
    unsigned int pmask = pmasks[r];
    #pragma unroll
    for (int i = 0; i < 4; i++)
      if ((u[i] & pmask) == pref) atomicAdd(&hist[(u[i] >> shift) & bmask], 1u);
    __syncthreads();
    for (int b = tid; b < nb; b += 1024){
      unsigned int h = hist[b];
      if (h) atomicAdd(&chunkSum[b >> logC], h);
    }
    __syncthreads();
    if (tid < 64){
      int chunk = 63 - tid;                     // lane order = descending chunk
      unsigned int s = chunkSum[chunk];
      unsigned int scan = s;
      #pragma unroll
      for (int d = 1; d < 64; d <<= 1){
        unsigned int t = __shfl_up(scan, d);
        if (tid >= d) scan += t;
      }
      unsigned int excl = scan - s;
      int k = s_k;
      if (excl < (unsigned)k && scan >= (unsigned)k){
        int C = 1 << logC;
        unsigned int cum = excl;
        for (int b = C-1; b >= 0; b--){
          unsigned int h = hist[(chunk << logC) + b];
          cum += h;
          if (cum >= (unsigned)k){
            s_k = k - (int)(cum - h);
            s_prefix = pref | ((unsigned)((chunk << logC) + b) << shift);
            break;
          }
        }
      }
    }
    __syncthreads();
  }
  unsigned int thr = s_prefix;
  int need_eq = s_k;
  if (tid == 0) s_cnt = 0;
  __syncthreads();
  #pragma unroll
  for (int i = 0; i < 4; i++){
    if (u[i] > thr){
      int p = atomicAdd(&s_cnt, 1);
      topi[e*TCAP + p] = tid + i*1024;
      topv[e*TCAP + p] = __uint_as_float(u[i]);
    }
  }
  __syncthreads();
  int base = s_cnt;
  int last = -1;
  for (int i = 0; i < need_eq; i++){
    __syncthreads();
    if (tid == 0) s_min = TN;
    __syncthreads();
    #pragma unroll
    for (int j = 0; j < 4; j++){
      int n = tid + j*1024;
      if (u[j] == thr && n > last) atomicMin(&s_min, n);
    }
    __syncthreads();
    int nsel = s_min;
    if (tid == 0){ topi[e*TCAP + base + i] = nsel; topv[e*TCAP + base + i] = __uint_as_float(thr); }
    last = nsel;
  }
}

// ---- GEMMs with pre-transposed bf16 weights Wt [e][n][k] ----

__global__ __launch_bounds__(256) void k_gemm1b(const short* __restrict__ xbf,
                                                const short* __restrict__ W1t,
                                                const int* __restrict__ topi,
                                                short* __restrict__ hbf){
  __shared__ __align__(16) short As[128][40];
  __shared__ __align__(16) short Bs[64][40];
  __shared__ int rows[128];
  int e = blockIdx.y, n0 = blockIdx.x*64;
  int tid = threadIdx.x;
  if (tid < 128) rows[tid] = topi[e*TCAP + tid];
  __syncthreads();
  int w = tid >> 6, l = tid & 63;
  int lr = l & 15, lh = l >> 4;
  f32x4 acc[2][4];
  #pragma unroll
  for (int m = 0; m < 2; m++)
    #pragma unroll
    for (int j = 0; j < 4; j++)
      #pragma unroll
      for (int r = 0; r < 4; r++) acc[m][j][r] = 0.f;

  int am = tid >> 1, aseg = (tid & 1)*16;
  const size_t arow = (size_t)rows[am]*TF;
  int bn = tid >> 2, bseg = (tid & 3)*8;
  const short* Bbase = W1t + ((size_t)e*TF + n0 + bn)*TF + bseg;

  for (int kk = 0; kk < TF; kk += 32){
    const bf16x8* asrc = (const bf16x8*)(xbf + arow + kk + aseg);
    *(bf16x8*)&As[am][aseg]     = asrc[0];
    *(bf16x8*)&As[am][aseg + 8] = asrc[1];
    *(bf16x8*)&Bs[bn][bseg]     = *(const bf16x8*)(Bbase + kk);
    __syncthreads();
    bf16x8 a0 = *(const bf16x8*)&As[32*w + lr][lh*8];
    bf16x8 a1 = *(const bf16x8*)&As[32*w + 16 + lr][lh*8];
    #pragma unroll
    for (int j = 0; j < 4; j++){
      bf16x8 b = *(const bf16x8*)&Bs[16*j + lr][lh*8];
      acc[0][j] = __builtin_amdgcn_mfma_f32_16x16x32_bf16(a0, b, acc[0][j], 0, 0, 0);
      acc[1][j] = __builtin_amdgcn_mfma_f32_16x16x32_bf16(a1, b, acc[1][j], 0, 0, 0);
    }
    __syncthreads();
  }
  short* hdst = hbf + (size_t)e*TCAP*TF;
  #pragma unroll
  for (int m = 0; m < 2; m++)
    #pragma unroll
    for (int j = 0; j < 4; j++)
      #pragma unroll
      for (int r = 0; r < 4; r++){
        int row = 32*w + 16*m + lh*4 + r;
        int col = n0 + 16*j + lr;
        hdst[(size_t)row*TF + col] = f2bf(gelu_tanh(acc[m][j][r]));
      }
}

__global__ __launch_bounds__(256) void k_gemm2b(const short* __restrict__ hbf,
                                                const short* __restrict__ W2t,
                                                const int* __restrict__ topi,
                                                const float* __restrict__ topv,
                                                float* __restrict__ pred){
  __shared__ __align__(16) short As[128][40];
  __shared__ __align__(16) short Bs[64][40];
  __shared__ int rows[128];
  __shared__ float tv[128];
  int e = blockIdx.y, n0 = blockIdx.x*64;
  int tid = threadIdx.x;
  if (tid < 128){ rows[tid] = topi[e*TCAP + tid]; tv[tid] = topv[e*TCAP + tid]; }
  __syncthreads();
  int w = tid >> 6, l = tid & 63;
  int lr = l & 15, lh = l >> 4;
  f32x4 acc[2][4];
  #pragma unroll
  for (int m = 0; m < 2; m++)
    #pragma unroll
    for (int j = 0; j < 4; j++)
      #pragma unroll
      for (int r = 0; r < 4; r++) acc[m][j][r] = 0.f;

  int am = tid >> 1, aseg = (tid & 1)*16;
  const short* asrcbase = hbf + ((size_t)e*TCAP + am)*TF;
  int bn = tid >> 2, bseg = (tid & 3)*8;
  const short* Bbase = W2t + ((size_t)e*TF + n0 + bn)*TF + bseg;

  for (int kk = 0; kk < TF; kk += 32){
    const bf16x8* asrc = (const bf16x8*)(asrcbase + kk + aseg);
    *(bf16x8*)&As[am][aseg]     = asrc[0];
    *(bf16x8*)&As[am][aseg + 8] = asrc[1];
    *(bf16x8*)&Bs[bn][bseg]     = *(const bf16x8*)(Bbase + kk);
    __syncthreads();
    bf16x8 a0 = *(const bf16x8*)&As[32*w + lr][lh*8];
    bf16x8 a1 = *(const bf16x8*)&As[32*w + 16 + lr][lh*8];
    #pragma unroll
    for (int j = 0; j < 4; j++){
      bf16x8 b = *(const bf16x8*)&Bs[16*j + lr][lh*8];
      acc[0][j] = __builtin_amdgcn_mfma_f32_16x16x32_bf16(a0, b, acc[0][j], 0, 0, 0);
      acc[1][j] = __builtin_amdgcn_mfma_f32_16x16x32_bf16(a1, b, acc[1][j], 0, 0, 0);
    }
    __syncthreads();
  }
  #pragma unroll
  for (int m = 0; m < 2; m++)
    #pragma unroll
    for (int j = 0; j < 4; j++)
      #pragma unroll
      for (int r = 0; r < 4; r++){
        int row = 32*w + 16*m + lh*4 + r;
        int col = n0 + 16*j + lr;
        float v = acc[m][j][r] * tv[row];
        atomicAdd(&pred[(size_t)rows[row]*TF + col], v);
      }
}

// ---- fallback GEMMs (f32 weights converted in-kernel) ----

__global__ __launch_bounds__(256) void k_gemm1(const short* __restrict__ xbf,
                                               const float* __restrict__ W1,
                                               const int* __restrict__ topi,
                                               short* __restrict__ hbf){
  __shared__ __align__(16) short As[128][40];
  __shared__ __align__(16) short Bs[64][40];
  __shared__ int rows[128];
  int e = blockIdx.y, n0 = blockIdx.x*64;
  int tid = threadIdx.x;
  if (tid < 128) rows[tid] = topi[e*TCAP + tid];
  __syncthreads();
  int w = tid >> 6, l = tid & 63;
  int lr = l & 15, lh = l >> 4;
  f32x4 acc[2][4];
  #pragma unroll
  for (int m = 0; m < 2; m++)
    #pragma unroll
    for (int j = 0; j < 4; j++)
      #pragma unroll
      for (int r = 0; r < 4; r++) acc[m][j][r] = 0.f;
  int am = tid >> 1, aseg = (tid & 1)*16;
  int br = tid >> 4, bc = (tid & 15)*4;
  const size_t arow = (size_t)rows[am]*TF;
  const float* Wbase = W1 + (size_t)e*TF*TF + n0;
  for (int kk = 0; kk < TF; kk += 32){
    const bf16x8* asrc = (const bf16x8*)(xbf + arow + kk + aseg);
    *(bf16x8*)&As[am][aseg]     = asrc[0];
    *(bf16x8*)&As[am][aseg + 8] = asrc[1];
    #pragma unroll
    for (int rr = br; rr < 32; rr += 16){
      float4 v = *(const float4*)(Wbase + (size_t)(kk+rr)*TF + bc);
      Bs[bc+0][rr] = f2bf(v.x); Bs[bc+1][rr] = f2bf(v.y);
      Bs[bc+2][rr] = f2bf(v.z); Bs[bc+3][rr] = f2bf(v.w);
    }
    __syncthreads();
    bf16x8 a0 = *(const bf16x8*)&As[32*w + lr][lh*8];
    bf16x8 a1 = *(const bf16x8*)&As[32*w + 16 + lr][lh*8];
    #pragma unroll
    for (int j = 0; j < 4; j++){
      bf16x8 b = *(const bf16x8*)&Bs[16*j + lr][lh*8];
      acc[0][j] = __builtin_amdgcn_mfma_f32_16x16x32_bf16(a0, b, acc[0][j], 0, 0, 0);
      acc[1][j] = __builtin_amdgcn_mfma_f32_16x16x32_bf16(a1, b, acc[1][j], 0, 0, 0);
    }
    __syncthreads();
  }
  short* hdst = hbf + (size_t)e*TCAP*TF;
  #pragma unroll
  for (int m = 0; m < 2; m++)
    #pragma unroll
    for (int j = 0; j < 4; j++)
      #pragma unroll
      for (int r = 0; r < 4; r++){
        int row = 32*w + 16*m + lh*4 + r;
        int col = n0 + 16*j + lr;
        hdst[(size_t)row*TF + col] = f2bf(gelu_tanh(acc[m][j][r]));
      }
}

__global__ __launch_bounds__(256) void k_gemm2(const short* __restrict__ hbf,
                                               const float* __restrict__ W2,
                                               const int* __restrict__ topi,
                                               const float* __restrict__ topv,
                                               float* __restrict__ pred){
  __shared__ __align__(16) short As[128][40];
  __shared__ __align__(16) short Bs[64][40];
  __shared__ int rows[128];
  __shared__ float tv[128];
  int e = blockIdx.y, n0 = blockIdx.x*64;
  int tid = threadIdx.x;
  if (tid < 128){ rows[tid] = topi[e*TCAP + tid]; tv[tid] = topv[e*TCAP + tid]; }
  __syncthreads();
  int w = tid >> 6, l = tid & 63;
  int lr = l & 15, lh = l >> 4;
  f32x4 acc[2][4];
  #pragma unroll
  for (int m = 0; m < 2; m++)
    #pragma unroll
    for (int j = 0; j < 4; j++)
      #pragma unroll
      for (int r = 0; r < 4; r++) acc[m][j][r] = 0.f;
  int am = tid >> 1, aseg = (tid & 1)*16;
  int br = tid >> 4, bc = (tid & 15)*4;
  const short* asrcbase = hbf + ((size_t)e*TCAP + am)*TF;
  const float* Wbase = W2 + (size_t)e*TF*TF + n0;
  for (int kk = 0; kk < TF; kk += 32){
    const bf16x8* asrc = (const bf16x8*)(asrcbase + kk + aseg);
    *(bf16x8*)&As[am][aseg]     = asrc[0];
    *(bf16x8*)&As[am][aseg + 8] = asrc[1];
    #pragma unroll
    for (int rr = br; rr < 32; rr += 16){
      float4 v = *(const float4*)(Wbase + (size_t)(kk+rr)*TF + bc);
      Bs[bc+0][rr] = f2bf(v.x); Bs[bc+1][rr] = f2bf(v.y);
      Bs[bc+2][rr] = f2bf(v.z); Bs[bc+3][rr] = f2bf(v.w);
    }
    __syncthreads();
    bf16x8 a0 = *(const bf16x8*)&As[32*w + lr][lh*8];
    bf16x8 a1 = *(const bf16x8*)&As[32*w + 16 + lr][lh*8];
    #pragma unroll
    for (int j = 0; j < 4; j++){
      bf16x8 b = *(const bf16x8*)&Bs[16*j + lr][lh*8];
      acc[0][j] = __builtin_amdgcn_mfma_f32_16x16x32_bf16(a0, b, acc[0][j], 0, 0, 0);
      acc[1][j] = __builtin_amdgcn_mfma_f32_16x16x32_bf16(a1, b, acc[1][j], 0, 0, 0);
    }
    __syncthreads();
  }
  #pragma unroll
  for (int m = 0; m < 2; m++)
    #pragma unroll
    for (int j = 0; j < 4; j++)
      #pragma unroll
      for (int r = 0; r < 4; r++){
        int row = 32*w + 16*m + lh*4 + r;
        int col = n0 + 16*j + lr;
        float v = acc[m][j][r] * tv[row];
        atomicAdd(&pred[(size_t)rows[row]*TF + col], v);
      }
}

__global__ void k_update(float* __restrict__ xw, const float* __restrict__ xt,
                         const float* __restrict__ pred){
  int i = blockIdx.x*256 + threadIdx.x;
  if (i >= TN*TF) return;
  float u = 0.05f*(xt[i] - pred[i]);
  u = fminf(10.0f, fmaxf(-10.0f, u));
  xw[i] += u;
}

extern "C" void kernel_launch(void* const* d_in, const int* in_sizes, int n_in,
                              void* d_out, int out_size, void* d_ws, size_t ws_size,
                              hipStream_t stream){
  (void)in_sizes; (void)n_in; (void)out_size;
  const float* x_stream = (const float*)d_in[0];
  const float* gains    = (const float*)d_in[1];
  const float* Wg       = (const float*)d_in[2];
  const float* Wr       = (const float*)d_in[3];
  const float* W1       = (const float*)d_in[4];
  const float* W2       = (const float*)d_in[5];
  const float* cosp     = (const float*)d_in[6];
  const float* sinp     = (const float*)d_in[7];

  size_t off = 0;
  char* base = (char*)d_ws;
  auto alloc = [&](size_t bytes) -> void* {
    void* p = base + off;
    off += (bytes + 255) & ~(size_t)255;
    return p;
  };
  float* x_work  = (float*)alloc((size_t)TN*TF*4);
  float* x_targ  = (float*)alloc((size_t)TN*TF*4);
  float* x_eff   = (float*)alloc((size_t)TN*TF*4);
  short* xf_bf   = (short*)alloc((size_t)TN*TF*2);
  float* gateb   = (float*)alloc((size_t)TN*TE*4);
  float* scoresT = (float*)alloc((size_t)TE*TN*4);
  int*   topi    = (int*)  alloc((size_t)TE*TCAP*4);
  float* topv    = (float*)alloc((size_t)TE*TCAP*4);
  short* h_bf    = (short*)alloc((size_t)TE*TCAP*TF*2);
  float* pred    = (float*)alloc((size_t)TN*TF*4);
  short* W1t     = (short*)alloc((size_t)TE*TF*TF*2);
  short* W2t     = (short*)alloc((size_t)TE*TF*TF*2);
  bool useT = (off <= ws_size);

  k_init<<<(TN*TD + 255)/256, 256, 0, stream>>>(x_stream, cosp, sinp, x_work, x_targ);
  k_gatebias<<<TN, 64, 0, stream>>>(x_work, Wg, gateb);
  if (useT){
    k_castw<<<dim3(64, TE), 256, 0, stream>>>(W1, W1t);
    k_castw<<<dim3(64, TE), 256, 0, stream>>>(W2, W2t);
  }

  for (int it = 0; it < NITER; it++){
    k_delay<<<(TN*TD + 255)/256, 256, 0, stream>>>(x_work, gains, x_eff, xf_bf);
    k_router2<<<TN/32, 256, 0, stream>>>(x_eff, Wr, gateb, scoresT);
    k_topk2<<<TE, 1024, 0, stream>>>(scoresT, topi, topv);
    hipMemsetAsync(pred, 0, (size_t)TN*TF*4, stream);
    if (useT){
      k_gemm1b<<<dim3(TF/64, TE), 256, 0, stream>>>(xf_bf, W1t, topi, h_bf);
      k_gemm2b<<<dim3(TF/64, TE), 256, 0, stream>>>(h_bf, W2t, topi, topv, pred);
    } else {
      k_gemm1<<<dim3(TF/64, TE), 256, 0, stream>>>(xf_bf, W1, topi, h_bf);
      k_gemm2<<<dim3(TF/64, TE), 256, 0, stream>>>(h_bf, W2, topi, topv, pred);
    }
    k_update<<<(TN*TF + 255)/256, 256, 0, stream>>>(x_work, x_targ, pred);
  }
  hipMemcpyAsync(d_out, x_work, (size_t)TN*TF*4, hipMemcpyDeviceToDevice, stream);
}

// Round 4
// 840.211 us; speedup vs baseline: 1.8529x; 1.0170x over previous
//
#include <hip/hip_runtime.h>
#include <hip/hip_bf16.h>

#define TB 2
#define TT 2048
#define TD 256
#define TE 64
#define TF 512
#define TN 4096      // TB*TT
#define TCAP 128     // 2*TN/TE
#define NITER 8

typedef __attribute__((ext_vector_type(8))) short bf16x8;
typedef __attribute__((ext_vector_type(4))) float f32x4;

__device__ inline float sanitize(float v){
  if (v != v) return 0.0f;
  const float FMAX = 3.402823466e+38f;
  if (v >  FMAX) return  FMAX;
  if (v < -FMAX) return -FMAX;
  return v;
}

__device__ inline short f2bf(float f){
  union { __hip_bfloat16 h; short s; } u;
  u.h = __float2bfloat16(f);
  return u.s;
}

__device__ inline float gelu_tanh(float x){
  float x3 = x*x*x;
  return 0.5f*x*(1.0f + tanhf(0.7978845608028654f*(x + 0.044715f*x3)));
}

// async global->LDS, 16B per lane. Dest must be wave-uniform base + lane*16
// (our slot layouts satisfy this). AS-casts compile under both builtin signatures.
__device__ __forceinline__ void gload16(const void* g, void* l){
  __builtin_amdgcn_global_load_lds(
      (__attribute__((address_space(1))) void*)g,
      (__attribute__((address_space(3))) void*)l, 16, 0, 0);
}

// ---------------- setup kernels ----------------

__global__ void k_init(const float* __restrict__ xs, const float* __restrict__ cosp,
                       const float* __restrict__ sinp, float* __restrict__ xw,
                       float* __restrict__ xt){
  int idx = blockIdx.x*256 + threadIdx.x;          // over TN*TD
  if (idx >= TN*TD) return;
  int d = idx & (TD-1);
  int n = idx >> 8;
  int t = n & (TT-1);
  float xr = sanitize(xs[2*idx]), xi = sanitize(xs[2*idx+1]);
  xw[2*idx] = xr; xw[2*idx+1] = xi;
  float tr, ti;
  if (t == 0){ tr = xr; ti = xi; }
  else {
    float pr = sanitize(xs[2*(idx-TD)]), pi = sanitize(xs[2*(idx-TD)+1]);
    float c = cosp[d], s = sinp[d];
    tr = pr*c - pi*s;
    ti = pr*s + pi*c;
  }
  xt[2*idx] = tr; xt[2*idx+1] = ti;
}

__global__ __launch_bounds__(64) void k_gatebias(const float* __restrict__ xw,
                                                 const float* __restrict__ wg,
                                                 float* __restrict__ gb){
  __shared__ float mag[TD];
  int n = blockIdx.x, t = threadIdx.x;
  for (int d = t; d < TD; d += 64){
    float xr = xw[(size_t)n*TF + 2*d], xi = xw[(size_t)n*TF + 2*d + 1];
    mag[d] = sqrtf(xr*xr + xi*xi + 1e-8f);
  }
  __syncthreads();
  float acc = 0.f;
  for (int d = 0; d < TD; d++) acc += mag[d]*wg[d*TE + t];
  gb[(size_t)n*TE + t] = acc;
}

// cast+transpose weights: in f32 [e][k][n] -> out bf16 [e][n][k]
__global__ __launch_bounds__(256) void k_castw(const float* __restrict__ W, short* __restrict__ Wt){
  __shared__ float tile[64][68];
  int e = blockIdx.y;
  int kt = (blockIdx.x >> 3) * 64;
  int nt = (blockIdx.x & 7) * 64;
  int tid = threadIdx.x;
  {
    int row = tid >> 4;
    int c4 = (tid & 15) * 4;
    #pragma unroll
    for (int i = 0; i < 4; i++){
      int r = row + i*16;
      float4 v = *(const float4*)(W + ((size_t)e*TF + kt + r)*TF + nt + c4);
      *(float4*)&tile[r][c4] = v;
    }
  }
  __syncthreads();
  #pragma unroll
  for (int i = 0; i < 2; i++){
    int un = tid + i*256;
    int nrow = un >> 3;
    int k8 = (un & 7) * 8;
    bf16x8 o;
    #pragma unroll
    for (int j = 0; j < 8; j++) o[j] = f2bf(tile[k8+j][nrow]);
    *(bf16x8*)(Wt + ((size_t)e*TF + nt + nrow)*TF + kt + k8) = o;
  }
}

// ---------------- per-iteration kernels ----------------

__global__ void k_delay(const float* __restrict__ xw, const float* __restrict__ g,
                        float* __restrict__ xe, short* __restrict__ xbf){
  int idx = blockIdx.x*256 + threadIdx.x;          // over TN*TD
  if (idx >= TN*TD) return;
  int d = idx & (TD-1);
  int n = idx >> 8;
  int t = n & (TT-1);
  float ar = xw[2*idx], ai = xw[2*idx+1];
  const int taus[4] = {1,2,3,5};
  #pragma unroll
  for (int i = 0; i < 4; i++){
    int tau = taus[i];
    if (t >= tau){
      float pr = xw[2*(idx - tau*TD)], pi = xw[2*(idx - tau*TD)+1];
      float gr = g[2*(i*TD + d)],      gi = g[2*(i*TD + d)+1];
      ar += pr*gr - pi*gi;
      ai += pr*gi + pi*gr;
    }
  }
  xe[2*idx] = ar; xe[2*idx+1] = ai;
  xbf[2*idx] = f2bf(ar); xbf[2*idx+1] = f2bf(ai);
}

// tiled f32 router GEMM + fused softmax. 32 tok x 64 exp per block, 256 thr.
__global__ __launch_bounds__(256) void k_router2(const float* __restrict__ xe,
                                                 const float* __restrict__ wr,
                                                 const float* __restrict__ gb,
                                                 float* __restrict__ scoresT){
  __shared__ float At[64][34];   // [k][tok]
  __shared__ float Bt[64][68];   // [k][e]
  int n0 = blockIdx.x * 32;
  int tid = threadIdx.x;
  int ty = tid >> 4;    // 0..15 -> token pair
  int tx = tid & 15;    // expert quad
  float acc[2][4];
  #pragma unroll
  for (int q = 0; q < 2; q++){
    int n = n0 + 2*ty + q;
    #pragma unroll
    for (int j = 0; j < 4; j++) acc[q][j] = gb[(size_t)n*TE + 4*tx + j];
  }
  int tokA = tid >> 3;            // 0..31
  int ksegA = (tid & 7) * 8;      // 0..56
  int rB = tid >> 2;              // 0..63
  int c16B = (tid & 3) * 16;      // 16 consecutive experts per thread
  for (int kk = 0; kk < TF; kk += 64){
    {
      const float4* src = (const float4*)(xe + (size_t)(n0+tokA)*TF + kk + ksegA);
      float4 v0 = src[0], v1 = src[1];
      At[ksegA+0][tokA]=v0.x; At[ksegA+1][tokA]=v0.y; At[ksegA+2][tokA]=v0.z; At[ksegA+3][tokA]=v0.w;
      At[ksegA+4][tokA]=v1.x; At[ksegA+5][tokA]=v1.y; At[ksegA+6][tokA]=v1.z; At[ksegA+7][tokA]=v1.w;
    }
    #pragma unroll
    for (int jj = 0; jj < 4; jj++)
      *(float4*)&Bt[rB][c16B + 4*jj] =
        *(const float4*)(wr + (size_t)(kk+rB)*TE + c16B + 4*jj);
    __syncthreads();
    #pragma unroll
    for (int k = 0; k < 64; k++){
      float2 a = *(const float2*)&At[k][2*ty];
      float4 b = *(const float4*)&Bt[k][4*tx];
      acc[0][0] += a.x*b.x; acc[0][1] += a.x*b.y; acc[0][2] += a.x*b.z; acc[0][3] += a.x*b.w;
      acc[1][0] += a.y*b.x; acc[1][1] += a.y*b.y; acc[1][2] += a.y*b.z; acc[1][3] += a.y*b.w;
    }
    __syncthreads();
  }
  #pragma unroll
  for (int q = 0; q < 2; q++){
    float m = fmaxf(fmaxf(acc[q][0],acc[q][1]), fmaxf(acc[q][2],acc[q][3]));
    #pragma unroll
    for (int off = 1; off < 16; off <<= 1) m = fmaxf(m, __shfl_xor(m, off));
    float e0 = expf(acc[q][0]-m), e1 = expf(acc[q][1]-m);
    float e2 = expf(acc[q][2]-m), e3 = expf(acc[q][3]-m);
    float s = e0+e1+e2+e3;
    #pragma unroll
    for (int off = 1; off < 16; off <<= 1) s += __shfl_xor(s, off);
    float inv = 1.0f / s;
    int n = n0 + 2*ty + q;
    scoresT[(size_t)(4*tx+0)*TN + n] = e0*inv;
    scoresT[(size_t)(4*tx+1)*TN + n] = e1*inv;
    scoresT[(size_t)(4*tx+2)*TN + n] = e2*inv;
    scoresT[(size_t)(4*tx+3)*TN + n] = e3*inv;
  }
}

// per-expert exact top-128: registers + 3-round radix (12/12/8 bits), parallel threshold find
__global__ __launch_bounds__(1024) void k_topk2(const float* __restrict__ scoresT,
                                                int* __restrict__ topi, float* __restrict__ topv){
  int e = blockIdx.x;
  const float* sc = scoresT + (size_t)e*TN;
  __shared__ unsigned int hist[4096];
  __shared__ unsigned int chunkSum[64];
  __shared__ unsigned int s_prefix;
  __shared__ int s_k, s_cnt, s_min;
  int tid = threadIdx.x;
  unsigned int u[4];
  #pragma unroll
  for (int i = 0; i < 4; i++) u[i] = __float_as_uint(sc[tid + i*1024]);
  if (tid == 0){ s_prefix = 0u; s_k = TCAP; }

  const int shifts[3]  = {20, 8, 0};
  const int nbins[3]   = {4096, 4096, 256};
  const unsigned int pmasks[3] = {0u, 0xFFF00000u, 0xFFFFFF00u};
  for (int r = 0; r < 3; r++){
    int shift = shifts[r], nb = nbins[r];
    unsigned int bmask = (unsigned)nb - 1u;
    int logC = (nb == 4096) ? 6 : 2;     // bins per chunk: nb/64
    for (int i = tid; i < nb; i += 1024) hist[i] = 0u;
    if (tid < 64) chunkSum[tid] = 0u;
    __syncthreads();
    unsigned int pref = s_prefix;
    unsigned int pmask = pmasks[r];
    #pragma unroll
    for (int i = 0; i < 4; i++)
      if ((u[i] & pmask) == pref) atomicAdd(&hist[(u[i] >> shift) & bmask], 1u);
    __syncthreads();
    for (int b = tid; b < nb; b += 1024){
      unsigned int h = hist[b];
      if (h) atomicAdd(&chunkSum[b >> logC], h);
    }
    __syncthreads();
    if (tid < 64){
      int chunk = 63 - tid;                     // lane order = descending chunk
      unsigned int s = chunkSum[chunk];
      unsigned int scan = s;
      #pragma unroll
      for (int d = 1; d < 64; d <<= 1){
        unsigned int t = __shfl_up(scan, d);
        if (tid >= d) scan += t;
      }
      unsigned int excl = scan - s;
      int k = s_k;
      if (excl < (unsigned)k && scan >= (unsigned)k){
        int C = 1 << logC;
        unsigned int cum = excl;
        for (int b = C-1; b >= 0; b--){
          unsigned int h = hist[(chunk << logC) + b];
          cum += h;
          if (cum >= (unsigned)k){
            s_k = k - (int)(cum - h);
            s_prefix = pref | ((unsigned)((chunk << logC) + b) << shift);
            break;
          }
        }
      }
    }
    __syncthreads();
  }
  unsigned int thr = s_prefix;
  int need_eq = s_k;
  if (tid == 0) s_cnt = 0;
  __syncthreads();
  #pragma unroll
  for (int i = 0; i < 4; i++){
    if (u[i] > thr){
      int p = atomicAdd(&s_cnt, 1);
      topi[e*TCAP + p] = tid + i*1024;
      topv[e*TCAP + p] = __uint_as_float(u[i]);
    }
  }
  __syncthreads();
  int base = s_cnt;
  int last = -1;
  for (int i = 0; i < need_eq; i++){
    __syncthreads();
    if (tid == 0) s_min = TN;
    __syncthreads();
    #pragma unroll
    for (int j = 0; j < 4; j++){
      int n = tid + j*1024;
      if (u[j] == thr && n > last) atomicMin(&s_min, n);
    }
    __syncthreads();
    int nsel = s_min;
    if (tid == 0){ topi[e*TCAP + base + i] = nsel; topv[e*TCAP + base + i] = __uint_as_float(thr); }
    last = nsel;
  }
}

// ---- GEMMs: bf16 Wt [e][n][k], global_load_lds staging, double-buffered prefetch ----
// BM=128 (all cap rows), BN=64, BK=32. 256 thr = 4 waves, wave w owns rows 32w..32w+31.

__global__ __launch_bounds__(256) void k_gemm1c(const short* __restrict__ xbf,
                                                const short* __restrict__ W1t,
                                                const int* __restrict__ topi,
                                                short* __restrict__ hbf){
  __shared__ __align__(16) short As[2][128*32];
  __shared__ __align__(16) short Bs[2][64*32];
  __shared__ int rows[128];
  int e = blockIdx.y, n0 = blockIdx.x*64;
  int tid = threadIdx.x;
  if (tid < 128) rows[tid] = topi[e*TCAP + tid];
  __syncthreads();
  int r4 = tid >> 2, c8 = (tid & 3)*8;
  const short* sA0 = xbf + (size_t)rows[r4]*TF + c8;        // slot tid      -> A row r4
  const short* sA1 = xbf + (size_t)rows[r4 + 64]*TF + c8;   // slot tid+256  -> A row r4+64
  const short* sB  = W1t + ((size_t)e*TF + n0 + r4)*TF + c8;

  int w = tid >> 6, l = tid & 63;
  int lr = l & 15, lh = l >> 4;
  int aOff0 = (32*w + lr)*32 + lh*8;
  int aOff1 = aOff0 + 16*32;
  int bOff0 = lr*32 + lh*8;

  f32x4 acc[2][4];
  #pragma unroll
  for (int m = 0; m < 2; m++)
    #pragma unroll
    for (int j = 0; j < 4; j++)
      #pragma unroll
      for (int r = 0; r < 4; r++) acc[m][j][r] = 0.f;

  // prologue stage into buf 0
  gload16(sA0, &As[0][tid*8]);
  gload16(sA1, &As[0][2048 + tid*8]);
  gload16(sB,  &Bs[0][tid*8]);
  __syncthreads();

  int cur = 0;
  for (int t16 = 0; t16 < 16; t16++){
    if (t16 < 15){
      int kk = t16*32 + 32;
      gload16(sA0 + kk, &As[cur^1][tid*8]);
      gload16(sA1 + kk, &As[cur^1][2048 + tid*8]);
      gload16(sB  + kk, &Bs[cur^1][tid*8]);
    }
    bf16x8 a0 = *(const bf16x8*)&As[cur][aOff0];
    bf16x8 a1 = *(const bf16x8*)&As[cur][aOff1];
    #pragma unroll
    for (int j = 0; j < 4; j++){
      bf16x8 b = *(const bf16x8*)&Bs[cur][bOff0 + j*16*32];
      acc[0][j] = __builtin_amdgcn_mfma_f32_16x16x32_bf16(a0, b, acc[0][j], 0, 0, 0);
      acc[1][j] = __builtin_amdgcn_mfma_f32_16x16x32_bf16(a1, b, acc[1][j], 0, 0, 0);
    }
    __syncthreads();
    cur ^= 1;
  }
  short* hdst = hbf + (size_t)e*TCAP*TF;
  #pragma unroll
  for (int m = 0; m < 2; m++)
    #pragma unroll
    for (int j = 0; j < 4; j++)
      #pragma unroll
      for (int r = 0; r < 4; r++){
        int row = 32*w + 16*m + lh*4 + r;
        int col = n0 + 16*j + lr;
        hdst[(size_t)row*TF + col] = f2bf(gelu_tanh(acc[m][j][r]));
      }
}

__global__ __launch_bounds__(256) void k_gemm2c(const short* __restrict__ hbf,
                                                const short* __restrict__ W2t,
                                                const int* __restrict__ topi,
                                                const float* __restrict__ topv,
                                                float* __restrict__ pred){
  __shared__ __align__(16) short As[2][128*32];
  __shared__ __align__(16) short Bs[2][64*32];
  __shared__ int rows[128];
  __shared__ float tv[128];
  int e = blockIdx.y, n0 = blockIdx.x*64;
  int tid = threadIdx.x;
  if (tid < 128){ rows[tid] = topi[e*TCAP + tid]; tv[tid] = topv[e*TCAP + tid]; }
  __syncthreads();
  int r4 = tid >> 2, c8 = (tid & 3)*8;
  const short* sA0 = hbf + ((size_t)e*TCAP + r4)*TF + c8;
  const short* sA1 = sA0 + (size_t)64*TF;
  const short* sB  = W2t + ((size_t)e*TF + n0 + r4)*TF + c8;

  int w = tid >> 6, l = tid & 63;
  int lr = l & 15, lh = l >> 4;
  int aOff0 = (32*w + lr)*32 + lh*8;
  int aOff1 = aOff0 + 16*32;
  int bOff0 = lr*32 + lh*8;

  f32x4 acc[2][4];
  #pragma unroll
  for (int m = 0; m < 2; m++)
    #pragma unroll
    for (int j = 0; j < 4; j++)
      #pragma unroll
      for (int r = 0; r < 4; r++) acc[m][j][r] = 0.f;

  gload16(sA0, &As[0][tid*8]);
  gload16(sA1, &As[0][2048 + tid*8]);
  gload16(sB,  &Bs[0][tid*8]);
  __syncthreads();

  int cur = 0;
  for (int t16 = 0; t16 < 16; t16++){
    if (t16 < 15){
      int kk = t16*32 + 32;
      gload16(sA0 + kk, &As[cur^1][tid*8]);
      gload16(sA1 + kk, &As[cur^1][2048 + tid*8]);
      gload16(sB  + kk, &Bs[cur^1][tid*8]);
    }
    bf16x8 a0 = *(const bf16x8*)&As[cur][aOff0];
    bf16x8 a1 = *(const bf16x8*)&As[cur][aOff1];
    #pragma unroll
    for (int j = 0; j < 4; j++){
      bf16x8 b = *(const bf16x8*)&Bs[cur][bOff0 + j*16*32];
      acc[0][j] = __builtin_amdgcn_mfma_f32_16x16x32_bf16(a0, b, acc[0][j], 0, 0, 0);
      acc[1][j] = __builtin_amdgcn_mfma_f32_16x16x32_bf16(a1, b, acc[1][j], 0, 0, 0);
    }
    __syncthreads();
    cur ^= 1;
  }
  #pragma unroll
  for (int m = 0; m < 2; m++)
    #pragma unroll
    for (int j = 0; j < 4; j++)
      #pragma unroll
      for (int r = 0; r < 4; r++){
        int row = 32*w + 16*m + lh*4 + r;
        int col = n0 + 16*j + lr;
        float v = acc[m][j][r] * tv[row];
        atomicAdd(&pred[(size_t)rows[row]*TF + col], v);
      }
}

// ---- fallback GEMMs (f32 weights converted in-kernel) ----

__global__ __launch_bounds__(256) void k_gemm1(const short* __restrict__ xbf,
                                               const float* __restrict__ W1,
                                               const int* __restrict__ topi,
                                               short* __restrict__ hbf){
  __shared__ __align__(16) short As[128][40];
  __shared__ __align__(16) short Bs[64][40];
  __shared__ int rows[128];
  int e = blockIdx.y, n0 = blockIdx.x*64;
  int tid = threadIdx.x;
  if (tid < 128) rows[tid] = topi[e*TCAP + tid];
  __syncthreads();
  int w = tid >> 6, l = tid & 63;
  int lr = l & 15, lh = l >> 4;
  f32x4 acc[2][4];
  #pragma unroll
  for (int m = 0; m < 2; m++)
    #pragma unroll
    for (int j = 0; j < 4; j++)
      #pragma unroll
      for (int r = 0; r < 4; r++) acc[m][j][r] = 0.f;
  int am = tid >> 1, aseg = (tid & 1)*16;
  int br = tid >> 4, bc = (tid & 15)*4;
  const size_t arow = (size_t)rows[am]*TF;
  const float* Wbase = W1 + (size_t)e*TF*TF + n0;
  for (int kk = 0; kk < TF; kk += 32){
    const bf16x8* asrc = (const bf16x8*)(xbf + arow + kk + aseg);
    *(bf16x8*)&As[am][aseg]     = asrc[0];
    *(bf16x8*)&As[am][aseg + 8] = asrc[1];
    #pragma unroll
    for (int rr = br; rr < 32; rr += 16){
      float4 v = *(const float4*)(Wbase + (size_t)(kk+rr)*TF + bc);
      Bs[bc+0][rr] = f2bf(v.x); Bs[bc+1][rr] = f2bf(v.y);
      Bs[bc+2][rr] = f2bf(v.z); Bs[bc+3][rr] = f2bf(v.w);
    }
    __syncthreads();
    bf16x8 a0 = *(const bf16x8*)&As[32*w + lr][lh*8];
    bf16x8 a1 = *(const bf16x8*)&As[32*w + 16 + lr][lh*8];
    #pragma unroll
    for (int j = 0; j < 4; j++){
      bf16x8 b = *(const bf16x8*)&Bs[16*j + lr][lh*8];
      acc[0][j] = __builtin_amdgcn_mfma_f32_16x16x32_bf16(a0, b, acc[0][j], 0, 0, 0);
      acc[1][j] = __builtin_amdgcn_mfma_f32_16x16x32_bf16(a1, b, acc[1][j], 0, 0, 0);
    }
    __syncthreads();
  }
  short* hdst = hbf + (size_t)e*TCAP*TF;
  #pragma unroll
  for (int m = 0; m < 2; m++)
    #pragma unroll
    for (int j = 0; j < 4; j++)
      #pragma unroll
      for (int r = 0; r < 4; r++){
        int row = 32*w + 16*m + lh*4 + r;
        int col = n0 + 16*j + lr;
        hdst[(size_t)row*TF + col] = f2bf(gelu_tanh(acc[m][j][r]));
      }
}

__global__ __launch_bounds__(256) void k_gemm2(const short* __restrict__ hbf,
                                               const float* __restrict__ W2,
                                               const int* __restrict__ topi,
                                               const float* __restrict__ topv,
                                               float* __restrict__ pred){
  __shared__ __align__(16) short As[128][40];
  __shared__ __align__(16) short Bs[64][40];
  __shared__ int rows[128];
  __shared__ float tv[128];
  int e = blockIdx.y, n0 = blockIdx.x*64;
  int tid = threadIdx.x;
  if (tid < 128){ rows[tid] = topi[e*TCAP + tid]; tv[tid] = topv[e*TCAP + tid]; }
  __syncthreads();
  int w = tid >> 6, l = tid & 63;
  int lr = l & 15, lh = l >> 4;
  f32x4 acc[2][4];
  #pragma unroll
  for (int m = 0; m < 2; m++)
    #pragma unroll
    for (int j = 0; j < 4; j++)
      #pragma unroll
      for (int r = 0; r < 4; r++) acc[m][j][r] = 0.f;
  int am = tid >> 1, aseg = (tid & 1)*16;
  int br = tid >> 4, bc = (tid & 15)*4;
  const short* asrcbase = hbf + ((size_t)e*TCAP + am)*TF;
  const float* Wbase = W2 + (size_t)e*TF*TF + n0;
  for (int kk = 0; kk < TF; kk += 32){
    const bf16x8* asrc = (const bf16x8*)(asrcbase + kk + aseg);
    *(bf16x8*)&As[am][aseg]     = asrc[0];
    *(bf16x8*)&As[am][aseg + 8] = asrc[1];
    #pragma unroll
    for (int rr = br; rr < 32; rr += 16){
      float4 v = *(const float4*)(Wbase + (size_t)(kk+rr)*TF + bc);
      Bs[bc+0][rr] = f2bf(v.x); Bs[bc+1][rr] = f2bf(v.y);
      Bs[bc+2][rr] = f2bf(v.z); Bs[bc+3][rr] = f2bf(v.w);
    }
    __syncthreads();
    bf16x8 a0 = *(const bf16x8*)&As[32*w + lr][lh*8];
    bf16x8 a1 = *(const bf16x8*)&As[32*w + 16 + lr][lh*8];
    #pragma unroll
    for (int j = 0; j < 4; j++){
      bf16x8 b = *(const bf16x8*)&Bs[16*j + lr][lh*8];
      acc[0][j] = __builtin_amdgcn_mfma_f32_16x16x32_bf16(a0, b, acc[0][j], 0, 0, 0);
      acc[1][j] = __builtin_amdgcn_mfma_f32_16x16x32_bf16(a1, b, acc[1][j], 0, 0, 0);
    }
    __syncthreads();
  }
  #pragma unroll
  for (int m = 0; m < 2; m++)
    #pragma unroll
    for (int j = 0; j < 4; j++)
      #pragma unroll
      for (int r = 0; r < 4; r++){
        int row = 32*w + 16*m + lh*4 + r;
        int col = n0 + 16*j + lr;
        float v = acc[m][j][r] * tv[row];
        atomicAdd(&pred[(size_t)rows[row]*TF + col], v);
      }
}

// dst = xw + clip(0.05*(xt - pred)); also zeroes pred for the next iteration/replay.
__global__ void k_update2(float* dst, const float* xw,
                          const float* __restrict__ xt, float* __restrict__ pred){
  int i = blockIdx.x*256 + threadIdx.x;
  if (i >= TN*TF) return;
  float p = pred[i];
  pred[i] = 0.f;
  float u = 0.05f*(xt[i] - p);
  u = fminf(10.0f, fmaxf(-10.0f, u));
  dst[i] = xw[i] + u;
}

extern "C" void kernel_launch(void* const* d_in, const int* in_sizes, int n_in,
                              void* d_out, int out_size, void* d_ws, size_t ws_size,
                              hipStream_t stream){
  (void)in_sizes; (void)n_in; (void)out_size;
  const float* x_stream = (const float*)d_in[0];
  const float* gains    = (const float*)d_in[1];
  const float* Wg       = (const float*)d_in[2];
  const float* Wr       = (const float*)d_in[3];
  const float* W1       = (const float*)d_in[4];
  const float* W2       = (const float*)d_in[5];
  const float* cosp     = (const float*)d_in[6];
  const float* sinp     = (const float*)d_in[7];

  size_t off = 0;
  char* base = (char*)d_ws;
  auto alloc = [&](size_t bytes) -> void* {
    void* p = base + off;
    off += (bytes + 255) & ~(size_t)255;
    return p;
  };
  float* x_work  = (float*)alloc((size_t)TN*TF*4);
  float* x_targ  = (float*)alloc((size_t)TN*TF*4);
  float* x_eff   = (float*)alloc((size_t)TN*TF*4);
  short* xf_bf   = (short*)alloc((size_t)TN*TF*2);
  float* gateb   = (float*)alloc((size_t)TN*TE*4);
  float* scoresT = (float*)alloc((size_t)TE*TN*4);
  int*   topi    = (int*)  alloc((size_t)TE*TCAP*4);
  float* topv    = (float*)alloc((size_t)TE*TCAP*4);
  short* h_bf    = (short*)alloc((size_t)TE*TCAP*TF*2);
  float* pred    = (float*)alloc((size_t)TN*TF*4);
  short* W1t     = (short*)alloc((size_t)TE*TF*TF*2);
  short* W2t     = (short*)alloc((size_t)TE*TF*TF*2);
  bool useT = (off <= ws_size);

  k_init<<<(TN*TD + 255)/256, 256, 0, stream>>>(x_stream, cosp, sinp, x_work, x_targ);
  k_gatebias<<<TN, 64, 0, stream>>>(x_work, Wg, gateb);
  if (useT){
    k_castw<<<dim3(64, TE), 256, 0, stream>>>(W1, W1t);
    k_castw<<<dim3(64, TE), 256, 0, stream>>>(W2, W2t);
  }
  hipMemsetAsync(pred, 0, (size_t)TN*TF*4, stream);   // first-call poison clear; k_update2 keeps it zeroed after

  for (int it = 0; it < NITER; it++){
    k_delay<<<(TN*TD + 255)/256, 256, 0, stream>>>(x_work, gains, x_eff, xf_bf);
    k_router2<<<TN/32, 256, 0, stream>>>(x_eff, Wr, gateb, scoresT);
    k_topk2<<<TE, 1024, 0, stream>>>(scoresT, topi, topv);
    if (useT){
      k_gemm1c<<<dim3(TF/64, TE), 256, 0, stream>>>(xf_bf, W1t, topi, h_bf);
      k_gemm2c<<<dim3(TF/64, TE), 256, 0, stream>>>(h_bf, W2t, topi, topv, pred);
    } else {
      k_gemm1<<<dim3(TF/64, TE), 256, 0, stream>>>(xf_bf, W1, topi, h_bf);
      k_gemm2<<<dim3(TF/64, TE), 256, 0, stream>>>(h_bf, W2, topi, topv, pred);
    }
    float* dst = (it == NITER-1) ? (float*)d_out : x_work;
    k_update2<<<(TN*TF + 255)/256, 256, 0, stream>>>(dst, x_work, x_targ, pred);
  }
}

// Round 5
// 807.557 us; speedup vs baseline: 1.9278x; 1.0404x over previous
//
#include <hip/hip_runtime.h>
#include <hip/hip_bf16.h>

#define TB 2
#define TT 2048
#define TD 256
#define TE 64
#define TF 512
#define TN 4096      // TB*TT
#define TCAP 128     // 2*TN/TE
#define NITER 8

typedef __attribute__((ext_vector_type(8))) short bf16x8;
typedef __attribute__((ext_vector_type(4))) float f32x4;

__device__ inline float sanitize(float v){
  if (v != v) return 0.0f;
  const float FMAX = 3.402823466e+38f;
  if (v >  FMAX) return  FMAX;
  if (v < -FMAX) return -FMAX;
  return v;
}

__device__ inline short f2bf(float f){
  union { __hip_bfloat16 h; short s; } u;
  u.h = __float2bfloat16(f);
  return u.s;
}

__device__ inline float gelu_tanh(float x){
  float x3 = x*x*x;
  return 0.5f*x*(1.0f + tanhf(0.7978845608028654f*(x + 0.044715f*x3)));
}

// async global->LDS, 16B per lane; dest = wave-uniform base + lane*16 (our layouts satisfy this)
__device__ __forceinline__ void gload16(const void* g, void* l){
  __builtin_amdgcn_global_load_lds(
      (__attribute__((address_space(1))) void*)g,
      (__attribute__((address_space(3))) void*)l, 16, 0, 0);
}

// ---------------- setup kernels ----------------

__global__ void k_init(const float* __restrict__ xs, const float* __restrict__ cosp,
                       const float* __restrict__ sinp, float* __restrict__ xw,
                       float* __restrict__ xt){
  int idx = blockIdx.x*256 + threadIdx.x;          // over TN*TD
  if (idx >= TN*TD) return;
  int d = idx & (TD-1);
  int n = idx >> 8;
  int t = n & (TT-1);
  float xr = sanitize(xs[2*idx]), xi = sanitize(xs[2*idx+1]);
  xw[2*idx] = xr; xw[2*idx+1] = xi;
  float tr, ti;
  if (t == 0){ tr = xr; ti = xi; }
  else {
    float pr = sanitize(xs[2*(idx-TD)]), pi = sanitize(xs[2*(idx-TD)+1]);
    float c = cosp[d], s = sinp[d];
    tr = pr*c - pi*s;
    ti = pr*s + pi*c;
  }
  xt[2*idx] = tr; xt[2*idx+1] = ti;
}

__global__ __launch_bounds__(64) void k_gatebias(const float* __restrict__ xw,
                                                 const float* __restrict__ wg,
                                                 float* __restrict__ gb){
  __shared__ float mag[TD];
  int n = blockIdx.x, t = threadIdx.x;
  for (int d = t; d < TD; d += 64){
    float xr = xw[(size_t)n*TF + 2*d], xi = xw[(size_t)n*TF + 2*d + 1];
    mag[d] = sqrtf(xr*xr + xi*xi + 1e-8f);
  }
  __syncthreads();
  float acc = 0.f;
  for (int d = 0; d < TD; d++) acc += mag[d]*wg[d*TE + t];
  gb[(size_t)n*TE + t] = acc;
}

// cast+transpose weights: in f32 [e][k][n] -> out bf16 [e][n][k]
__global__ __launch_bounds__(256) void k_castw(const float* __restrict__ W, short* __restrict__ Wt){
  __shared__ float tile[64][68];
  int e = blockIdx.y;
  int kt = (blockIdx.x >> 3) * 64;
  int nt = (blockIdx.x & 7) * 64;
  int tid = threadIdx.x;
  {
    int row = tid >> 4;
    int c4 = (tid & 15) * 4;
    #pragma unroll
    for (int i = 0; i < 4; i++){
      int r = row + i*16;
      float4 v = *(const float4*)(W + ((size_t)e*TF + kt + r)*TF + nt + c4);
      *(float4*)&tile[r][c4] = v;
    }
  }
  __syncthreads();
  #pragma unroll
  for (int i = 0; i < 2; i++){
    int un = tid + i*256;
    int nrow = un >> 3;
    int k8 = (un & 7) * 8;
    bf16x8 o;
    #pragma unroll
    for (int j = 0; j < 8; j++) o[j] = f2bf(tile[k8+j][nrow]);
    *(bf16x8*)(Wt + ((size_t)e*TF + nt + nrow)*TF + kt + k8) = o;
  }
}

// ---------------- fused update + delay + router ----------------

// load 16 consecutive floats of row-offset `off`, applying the local-lr update if upd.
__device__ __forceinline__ void load_row16(const float* __restrict__ xw,
                                           const float* __restrict__ xt,
                                           const float* __restrict__ pr,
                                           size_t off, int upd, float* o){
  const float4* a4 = (const float4*)(xw + off);
  if (upd){
    const float4* t4 = (const float4*)(xt + off);
    const float4* p4 = (const float4*)(pr + off);
    #pragma unroll
    for (int j = 0; j < 4; j++){
      float4 a = a4[j], t = t4[j], p = p4[j];
      float u;
      u = 0.05f*(t.x - p.x); u = fminf(10.f, fmaxf(-10.f, u)); o[4*j+0] = a.x + u;
      u = 0.05f*(t.y - p.y); u = fminf(10.f, fmaxf(-10.f, u)); o[4*j+1] = a.y + u;
      u = 0.05f*(t.z - p.z); u = fminf(10.f, fmaxf(-10.f, u)); o[4*j+2] = a.z + u;
      u = 0.05f*(t.w - p.w); u = fminf(10.f, fmaxf(-10.f, u)); o[4*j+3] = a.w + u;
    }
  } else {
    #pragma unroll
    for (int j = 0; j < 4; j++){
      float4 a = a4[j];
      o[4*j+0] = a.x; o[4*j+1] = a.y; o[4*j+2] = a.z; o[4*j+3] = a.w;
    }
  }
}

// 8 tokens per block, 256 threads. Computes x_cur = update(xOld, predR), writes xNew (own rows),
// zeroes predW (own rows), computes x_eff (delay embed), writes xbf (bf16) + router scores.
__global__ __launch_bounds__(256) void k_fuse(
    const float* __restrict__ xOld, float* __restrict__ xNew,
    const float* __restrict__ xt, const float* __restrict__ predR,
    float* __restrict__ predW, const float* __restrict__ g,
    const float* __restrict__ wr, const float* __restrict__ gb,
    short* __restrict__ xbf, float* __restrict__ scoresT, int upd)
{
  __shared__ float xeff[8][516];
  __shared__ float Bt[64][68];
  int tid = threadIdx.x;
  int tok = tid >> 5;            // 0..7
  int kq  = (tid & 31) * 16;     // 16 consecutive floats
  int n   = blockIdx.x*8 + tok;
  int t   = n & (TT-1);
  size_t rowoff = (size_t)n*TF + kq;

  float cur[16], eff[16];
  load_row16(xOld, xt, predR, rowoff, upd, cur);
  #pragma unroll
  for (int q = 0; q < 16; q++) eff[q] = cur[q];
  const int taus[4] = {1,2,3,5};
  int d0 = kq >> 1;
  #pragma unroll
  for (int i = 0; i < 4; i++){
    int tau = taus[i];
    if (t >= tau){
      float nb[16];
      load_row16(xOld, xt, predR, rowoff - (size_t)tau*TF, upd, nb);
      #pragma unroll
      for (int p = 0; p < 8; p++){
        float gr = g[2*(i*TD + d0 + p)];
        float gi = g[2*(i*TD + d0 + p) + 1];
        eff[2*p]   += nb[2*p]*gr - nb[2*p+1]*gi;
        eff[2*p+1] += nb[2*p]*gi + nb[2*p+1]*gr;
      }
    }
  }
  {
    float4* xn = (float4*)(xNew + rowoff);
    float4* pz = (float4*)(predW + rowoff);
    float4 z = make_float4(0.f, 0.f, 0.f, 0.f);
    #pragma unroll
    for (int j = 0; j < 4; j++){
      xn[j] = make_float4(cur[4*j], cur[4*j+1], cur[4*j+2], cur[4*j+3]);
      pz[j] = z;
    }
    bf16x8 o0, o1;
    #pragma unroll
    for (int q = 0; q < 8; q++){ o0[q] = f2bf(eff[q]); o1[q] = f2bf(eff[8+q]); }
    *(bf16x8*)(xbf + rowoff)     = o0;
    *(bf16x8*)(xbf + rowoff + 8) = o1;
    #pragma unroll
    for (int j = 0; j < 4; j++)
      *(float4*)&xeff[tok][kq + 4*j] = make_float4(eff[4*j], eff[4*j+1], eff[4*j+2], eff[4*j+3]);
  }
  __syncthreads();

  // router: thread (tok, tx) computes experts {2tx, 2tx+1} for token n
  int tx = tid & 31;
  float acc0 = gb[(size_t)n*TE + 2*tx];
  float acc1 = gb[(size_t)n*TE + 2*tx + 1];
  int rB = tid >> 2, c16 = (tid & 3)*16;
  for (int kk = 0; kk < TF; kk += 64){
    #pragma unroll
    for (int jj = 0; jj < 4; jj++)
      *(float4*)&Bt[rB][c16 + 4*jj] = *(const float4*)(wr + (size_t)(kk+rB)*TE + c16 + 4*jj);
    __syncthreads();
    #pragma unroll
    for (int k = 0; k < 64; k++){
      float a = xeff[tok][kk + k];
      float2 b = *(const float2*)&Bt[k][2*tx];
      acc0 += a*b.x; acc1 += a*b.y;
    }
    __syncthreads();
  }
  float m = fmaxf(acc0, acc1);
  #pragma unroll
  for (int off = 1; off < 32; off <<= 1) m = fmaxf(m, __shfl_xor(m, off));
  float e0 = expf(acc0 - m), e1 = expf(acc1 - m);
  float s = e0 + e1;
  #pragma unroll
  for (int off = 1; off < 32; off <<= 1) s += __shfl_xor(s, off);
  float inv = 1.0f / s;
  scoresT[(size_t)(2*tx)*TN + n]     = e0*inv;
  scoresT[(size_t)(2*tx+1)*TN + n]   = e1*inv;
}

// per-expert exact top-128: registers + 3-round radix (12/12/8 bits), parallel threshold find
__global__ __launch_bounds__(1024) void k_topk2(const float* __restrict__ scoresT,
                                                int* __restrict__ topi, float* __restrict__ topv){
  int e = blockIdx.x;
  const float* sc = scoresT + (size_t)e*TN;
  __shared__ unsigned int hist[4096];
  __shared__ unsigned int chunkSum[64];
  __shared__ unsigned int s_prefix;
  __shared__ int s_k, s_cnt, s_min;
  int tid = threadIdx.x;
  unsigned int u[4];
  #pragma unroll
  for (int i = 0; i < 4; i++) u[i] = __float_as_uint(sc[tid + i*1024]);
  if (tid == 0){ s_prefix = 0u; s_k = TCAP; }

  const int shifts[3]  = {20, 8, 0};
  const int nbins[3]   = {4096, 4096, 256};
  const unsigned int pmasks[3] = {0u, 0xFFF00000u, 0xFFFFFF00u};
  for (int r = 0; r < 3; r++){
    int shift = shifts[r], nb = nbins[r];
    unsigned int bmask = (unsigned)nb - 1u;
    int logC = (nb == 4096) ? 6 : 2;     // bins per chunk: nb/64
    for (int i = tid; i < nb; i += 1024) hist[i] = 0u;
    if (tid < 64) chunkSum[tid] = 0u;
    __syncthreads();
    unsigned int pref = s_prefix;
    unsigned int pmask = pmasks[r];
    #pragma unroll
    for (int i = 0; i < 4; i++)
      if ((u[i] & pmask) == pref) atomicAdd(&hist[(u[i] >> shift) & bmask], 1u);
    __syncthreads();
    for (int b = tid; b < nb; b += 1024){
      unsigned int h = hist[b];
      if (h) atomicAdd(&chunkSum[b >> logC], h);
    }
    __syncthreads();
    if (tid < 64){
      int chunk = 63 - tid;                     // lane order = descending chunk
      unsigned int s = chunkSum[chunk];
      unsigned int scan = s;
      #pragma unroll
      for (int d = 1; d < 64; d <<= 1){
        unsigned int t = __shfl_up(scan, d);
        if (tid >= d) scan += t;
      }
      unsigned int excl = scan - s;
      int k = s_k;
      if (excl < (unsigned)k && scan >= (unsigned)k){
        int C = 1 << logC;
        unsigned int cum = excl;
        for (int b = C-1; b >= 0; b--){
          unsigned int h = hist[(chunk << logC) + b];
          cum += h;
          if (cum >= (unsigned)k){
            s_k = k - (int)(cum - h);
            s_prefix = pref | ((unsigned)((chunk << logC) + b) << shift);
            break;
          }
        }
      }
    }
    __syncthreads();
  }
  unsigned int thr = s_prefix;
  int need_eq = s_k;
  if (tid == 0) s_cnt = 0;
  __syncthreads();
  #pragma unroll
  for (int i = 0; i < 4; i++){
    if (u[i] > thr){
      int p = atomicAdd(&s_cnt, 1);
      topi[e*TCAP + p] = tid + i*1024;
      topv[e*TCAP + p] = __uint_as_float(u[i]);
    }
  }
  __syncthreads();
  int base = s_cnt;
  int last = -1;
  for (int i = 0; i < need_eq; i++){
    __syncthreads();
    if (tid == 0) s_min = TN;
    __syncthreads();
    #pragma unroll
    for (int j = 0; j < 4; j++){
      int n = tid + j*1024;
      if (u[j] == thr && n > last) atomicMin(&s_min, n);
    }
    __syncthreads();
    int nsel = s_min;
    if (tid == 0){ topi[e*TCAP + base + i] = nsel; topv[e*TCAP + base + i] = __uint_as_float(thr); }
    last = nsel;
  }
}

// ---- GEMMs: bf16 Wt [e][n][k], global_load_lds staging, double-buffered prefetch ----

__global__ __launch_bounds__(256) void k_gemm1c(const short* __restrict__ xbf,
                                                const short* __restrict__ W1t,
                                                const int* __restrict__ topi,
                                                short* __restrict__ hbf){
  __shared__ __align__(16) short As[2][128*32];
  __shared__ __align__(16) short Bs[2][64*32];
  __shared__ int rows[128];
  int e = blockIdx.y, n0 = blockIdx.x*64;
  int tid = threadIdx.x;
  if (tid < 128) rows[tid] = topi[e*TCAP + tid];
  __syncthreads();
  int r4 = tid >> 2, c8 = (tid & 3)*8;
  const short* sA0 = xbf + (size_t)rows[r4]*TF + c8;
  const short* sA1 = xbf + (size_t)rows[r4 + 64]*TF + c8;
  const short* sB  = W1t + ((size_t)e*TF + n0 + r4)*TF + c8;

  int w = tid >> 6, l = tid & 63;
  int lr = l & 15, lh = l >> 4;
  int aOff0 = (32*w + lr)*32 + lh*8;
  int aOff1 = aOff0 + 16*32;
  int bOff0 = lr*32 + lh*8;

  f32x4 acc[2][4];
  #pragma unroll
  for (int m = 0; m < 2; m++)
    #pragma unroll
    for (int j = 0; j < 4; j++)
      #pragma unroll
      for (int r = 0; r < 4; r++) acc[m][j][r] = 0.f;

  gload16(sA0, &As[0][tid*8]);
  gload16(sA1, &As[0][2048 + tid*8]);
  gload16(sB,  &Bs[0][tid*8]);
  __syncthreads();

  int cur = 0;
  for (int t16 = 0; t16 < 16; t16++){
    if (t16 < 15){
      int kk = t16*32 + 32;
      gload16(sA0 + kk, &As[cur^1][tid*8]);
      gload16(sA1 + kk, &As[cur^1][2048 + tid*8]);
      gload16(sB  + kk, &Bs[cur^1][tid*8]);
    }
    bf16x8 a0 = *(const bf16x8*)&As[cur][aOff0];
    bf16x8 a1 = *(const bf16x8*)&As[cur][aOff1];
    #pragma unroll
    for (int j = 0; j < 4; j++){
      bf16x8 b = *(const bf16x8*)&Bs[cur][bOff0 + j*16*32];
      acc[0][j] = __builtin_amdgcn_mfma_f32_16x16x32_bf16(a0, b, acc[0][j], 0, 0, 0);
      acc[1][j] = __builtin_amdgcn_mfma_f32_16x16x32_bf16(a1, b, acc[1][j], 0, 0, 0);
    }
    __syncthreads();
    cur ^= 1;
  }
  short* hdst = hbf + (size_t)e*TCAP*TF;
  #pragma unroll
  for (int m = 0; m < 2; m++)
    #pragma unroll
    for (int j = 0; j < 4; j++)
      #pragma unroll
      for (int r = 0; r < 4; r++){
        int row = 32*w + 16*m + lh*4 + r;
        int col = n0 + 16*j + lr;
        hdst[(size_t)row*TF + col] = f2bf(gelu_tanh(acc[m][j][r]));
      }
}

__global__ __launch_bounds__(256) void k_gemm2c(const short* __restrict__ hbf,
                                                const short* __restrict__ W2t,
                                                const int* __restrict__ topi,
                                                const float* __restrict__ topv,
                                                float* __restrict__ pred){
  __shared__ __align__(16) short As[2][128*32];
  __shared__ __align__(16) short Bs[2][64*32];
  __shared__ int rows[128];
  __shared__ float tv[128];
  int e = blockIdx.y, n0 = blockIdx.x*64;
  int tid = threadIdx.x;
  if (tid < 128){ rows[tid] = topi[e*TCAP + tid]; tv[tid] = topv[e*TCAP + tid]; }
  __syncthreads();
  int r4 = tid >> 2, c8 = (tid & 3)*8;
  const short* sA0 = hbf + ((size_t)e*TCAP + r4)*TF + c8;
  const short* sA1 = sA0 + (size_t)64*TF;
  const short* sB  = W2t + ((size_t)e*TF + n0 + r4)*TF + c8;

  int w = tid >> 6, l = tid & 63;
  int lr = l & 15, lh = l >> 4;
  int aOff0 = (32*w + lr)*32 + lh*8;
  int aOff1 = aOff0 + 16*32;
  int bOff0 = lr*32 + lh*8;

  f32x4 acc[2][4];
  #pragma unroll
  for (int m = 0; m < 2; m++)
    #pragma unroll
    for (int j = 0; j < 4; j++)
      #pragma unroll
      for (int r = 0; r < 4; r++) acc[m][j][r] = 0.f;

  gload16(sA0, &As[0][tid*8]);
  gload16(sA1, &As[0][2048 + tid*8]);
  gload16(sB,  &Bs[0][tid*8]);
  __syncthreads();

  int cur = 0;
  for (int t16 = 0; t16 < 16; t16++){
    if (t16 < 15){
      int kk = t16*32 + 32;
      gload16(sA0 + kk, &As[cur^1][tid*8]);
      gload16(sA1 + kk, &As[cur^1][2048 + tid*8]);
      gload16(sB  + kk, &Bs[cur^1][tid*8]);
    }
    bf16x8 a0 = *(const bf16x8*)&As[cur][aOff0];
    bf16x8 a1 = *(const bf16x8*)&As[cur][aOff1];
    #pragma unroll
    for (int j = 0; j < 4; j++){
      bf16x8 b = *(const bf16x8*)&Bs[cur][bOff0 + j*16*32];
      acc[0][j] = __builtin_amdgcn_mfma_f32_16x16x32_bf16(a0, b, acc[0][j], 0, 0, 0);
      acc[1][j] = __builtin_amdgcn_mfma_f32_16x16x32_bf16(a1, b, acc[1][j], 0, 0, 0);
    }
    __syncthreads();
    cur ^= 1;
  }
  #pragma unroll
  for (int m = 0; m < 2; m++)
    #pragma unroll
    for (int j = 0; j < 4; j++)
      #pragma unroll
      for (int r = 0; r < 4; r++){
        int row = 32*w + 16*m + lh*4 + r;
        int col = n0 + 16*j + lr;
        float v = acc[m][j][r] * tv[row];
        atomicAdd(&pred[(size_t)rows[row]*TF + col], v);
      }
}

// ---- fallback GEMMs (f32 weights converted in-kernel) ----

__global__ __launch_bounds__(256) void k_gemm1(const short* __restrict__ xbf,
                                               const float* __restrict__ W1,
                                               const int* __restrict__ topi,
                                               short* __restrict__ hbf){
  __shared__ __align__(16) short As[128][40];
  __shared__ __align__(16) short Bs[64][40];
  __shared__ int rows[128];
  int e = blockIdx.y, n0 = blockIdx.x*64;
  int tid = threadIdx.x;
  if (tid < 128) rows[tid] = topi[e*TCAP + tid];
  __syncthreads();
  int w = tid >> 6, l = tid & 63;
  int lr = l & 15, lh = l >> 4;
  f32x4 acc[2][4];
  #pragma unroll
  for (int m = 0; m < 2; m++)
    #pragma unroll
    for (int j = 0; j < 4; j++)
      #pragma unroll
      for (int r = 0; r < 4; r++) acc[m][j][r] = 0.f;
  int am = tid >> 1, aseg = (tid & 1)*16;
  int br = tid >> 4, bc = (tid & 15)*4;
  const size_t arow = (size_t)rows[am]*TF;
  const float* Wbase = W1 + (size_t)e*TF*TF + n0;
  for (int kk = 0; kk < TF; kk += 32){
    const bf16x8* asrc = (const bf16x8*)(xbf + arow + kk + aseg);
    *(bf16x8*)&As[am][aseg]     = asrc[0];
    *(bf16x8*)&As[am][aseg + 8] = asrc[1];
    #pragma unroll
    for (int rr = br; rr < 32; rr += 16){
      float4 v = *(const float4*)(Wbase + (size_t)(kk+rr)*TF + bc);
      Bs[bc+0][rr] = f2bf(v.x); Bs[bc+1][rr] = f2bf(v.y);
      Bs[bc+2][rr] = f2bf(v.z); Bs[bc+3][rr] = f2bf(v.w);
    }
    __syncthreads();
    bf16x8 a0 = *(const bf16x8*)&As[32*w + lr][lh*8];
    bf16x8 a1 = *(const bf16x8*)&As[32*w + 16 + lr][lh*8];
    #pragma unroll
    for (int j = 0; j < 4; j++){
      bf16x8 b = *(const bf16x8*)&Bs[16*j + lr][lh*8];
      acc[0][j] = __builtin_amdgcn_mfma_f32_16x16x32_bf16(a0, b, acc[0][j], 0, 0, 0);
      acc[1][j] = __builtin_amdgcn_mfma_f32_16x16x32_bf16(a1, b, acc[1][j], 0, 0, 0);
    }
    __syncthreads();
  }
  short* hdst = hbf + (size_t)e*TCAP*TF;
  #pragma unroll
  for (int m = 0; m < 2; m++)
    #pragma unroll
    for (int j = 0; j < 4; j++)
      #pragma unroll
      for (int r = 0; r < 4; r++){
        int row = 32*w + 16*m + lh*4 + r;
        int col = n0 + 16*j + lr;
        hdst[(size_t)row*TF + col] = f2bf(gelu_tanh(acc[m][j][r]));
      }
}

__global__ __launch_bounds__(256) void k_gemm2(const short* __restrict__ hbf,
                                               const float* __restrict__ W2,
                                               const int* __restrict__ topi,
                                               const float* __restrict__ topv,
                                               float* __restrict__ pred){
  __shared__ __align__(16) short As[128][40];
  __shared__ __align__(16) short Bs[64][40];
  __shared__ int rows[128];
  __shared__ float tv[128];
  int e = blockIdx.y, n0 = blockIdx.x*64;
  int tid = threadIdx.x;
  if (tid < 128){ rows[tid] = topi[e*TCAP + tid]; tv[tid] = topv[e*TCAP + tid]; }
  __syncthreads();
  int w = tid >> 6, l = tid & 63;
  int lr = l & 15, lh = l >> 4;
  f32x4 acc[2][4];
  #pragma unroll
  for (int m = 0; m < 2; m++)
    #pragma unroll
    for (int j = 0; j < 4; j++)
      #pragma unroll
      for (int r = 0; r < 4; r++) acc[m][j][r] = 0.f;
  int am = tid >> 1, aseg = (tid & 1)*16;
  int br = tid >> 4, bc = (tid & 15)*4;
  const short* asrcbase = hbf + ((size_t)e*TCAP + am)*TF;
  const float* Wbase = W2 + (size_t)e*TF*TF + n0;
  for (int kk = 0; kk < TF; kk += 32){
    const bf16x8* asrc = (const bf16x8*)(asrcbase + kk + aseg);
    *(bf16x8*)&As[am][aseg]     = asrc[0];
    *(bf16x8*)&As[am][aseg + 8] = asrc[1];
    #pragma unroll
    for (int rr = br; rr < 32; rr += 16){
      float4 v = *(const float4*)(Wbase + (size_t)(kk+rr)*TF + bc);
      Bs[bc+0][rr] = f2bf(v.x); Bs[bc+1][rr] = f2bf(v.y);
      Bs[bc+2][rr] = f2bf(v.z); Bs[bc+3][rr] = f2bf(v.w);
    }
    __syncthreads();
    bf16x8 a0 = *(const bf16x8*)&As[32*w + lr][lh*8];
    bf16x8 a1 = *(const bf16x8*)&As[32*w + 16 + lr][lh*8];
    #pragma unroll
    for (int j = 0; j < 4; j++){
      bf16x8 b = *(const bf16x8*)&Bs[16*j + lr][lh*8];
      acc[0][j] = __builtin_amdgcn_mfma_f32_16x16x32_bf16(a0, b, acc[0][j], 0, 0, 0);
      acc[1][j] = __builtin_amdgcn_mfma_f32_16x16x32_bf16(a1, b, acc[1][j], 0, 0, 0);
    }
    __syncthreads();
  }
  #pragma unroll
  for (int m = 0; m < 2; m++)
    #pragma unroll
    for (int j = 0; j < 4; j++)
      #pragma unroll
      for (int r = 0; r < 4; r++){
        int row = 32*w + 16*m + lh*4 + r;
        int col = n0 + 16*j + lr;
        float v = acc[m][j][r] * tv[row];
        atomicAdd(&pred[(size_t)rows[row]*TF + col], v);
      }
}

// out = x + clip(0.05*(xt - pred))
__global__ void k_final(float* __restrict__ out, const float* __restrict__ x,
                        const float* __restrict__ xt, const float* __restrict__ pred){
  int i = blockIdx.x*256 + threadIdx.x;
  if (i >= TN*TF) return;
  float u = 0.05f*(xt[i] - pred[i]);
  u = fminf(10.0f, fmaxf(-10.0f, u));
  out[i] = x[i] + u;
}

extern "C" void kernel_launch(void* const* d_in, const int* in_sizes, int n_in,
                              void* d_out, int out_size, void* d_ws, size_t ws_size,
                              hipStream_t stream){
  (void)in_sizes; (void)n_in; (void)out_size;
  const float* x_stream = (const float*)d_in[0];
  const float* gains    = (const float*)d_in[1];
  const float* Wg       = (const float*)d_in[2];
  const float* Wr       = (const float*)d_in[3];
  const float* W1       = (const float*)d_in[4];
  const float* W2       = (const float*)d_in[5];
  const float* cosp     = (const float*)d_in[6];
  const float* sinp     = (const float*)d_in[7];

  size_t off = 0;
  char* base = (char*)d_ws;
  auto alloc = [&](size_t bytes) -> void* {
    void* p = base + off;
    off += (bytes + 255) & ~(size_t)255;
    return p;
  };
  float* X0      = (float*)alloc((size_t)TN*TF*4);   // x ping
  float* X1      = (float*)alloc((size_t)TN*TF*4);   // x pong
  float* x_targ  = (float*)alloc((size_t)TN*TF*4);
  short* xf_bf   = (short*)alloc((size_t)TN*TF*2);
  float* gateb   = (float*)alloc((size_t)TN*TE*4);
  float* scoresT = (float*)alloc((size_t)TE*TN*4);
  int*   topi    = (int*)  alloc((size_t)TE*TCAP*4);
  float* topv    = (float*)alloc((size_t)TE*TCAP*4);
  short* h_bf    = (short*)alloc((size_t)TE*TCAP*TF*2);
  float* P0      = (float*)alloc((size_t)TN*TF*4);   // pred ping
  float* P1      = (float*)alloc((size_t)TN*TF*4);   // pred pong
  short* W1t     = (short*)alloc((size_t)TE*TF*TF*2);
  short* W2t     = (short*)alloc((size_t)TE*TF*TF*2);
  bool useT = (off <= ws_size);

  k_init<<<(TN*TD + 255)/256, 256, 0, stream>>>(x_stream, cosp, sinp, X0, x_targ);
  k_gatebias<<<TN, 64, 0, stream>>>(X0, Wg, gateb);
  if (useT){
    k_castw<<<dim3(64, TE), 256, 0, stream>>>(W1, W1t);
    k_castw<<<dim3(64, TE), 256, 0, stream>>>(W2, W2t);
  }

  for (int it = 0; it < NITER; it++){
    const float* xO = (it & 1) ? X1 : X0;
    float*       xN = (it & 1) ? X0 : X1;
    float*       pW = (it & 1) ? P1 : P0;
    const float* pR = (it & 1) ? P0 : P1;
    k_fuse<<<TN/8, 256, 0, stream>>>(xO, xN, x_targ, pR, pW, gains, Wr, gateb,
                                     xf_bf, scoresT, it > 0 ? 1 : 0);
    k_topk2<<<TE, 1024, 0, stream>>>(scoresT, topi, topv);
    if (useT){
      k_gemm1c<<<dim3(TF/64, TE), 256, 0, stream>>>(xf_bf, W1t, topi, h_bf);
      k_gemm2c<<<dim3(TF/64, TE), 256, 0, stream>>>(h_bf, W2t, topi, topv, pW);
    } else {
      k_gemm1<<<dim3(TF/64, TE), 256, 0, stream>>>(xf_bf, W1, topi, h_bf);
      k_gemm2<<<dim3(TF/64, TE), 256, 0, stream>>>(h_bf, W2, topi, topv, pW);
    }
  }
  // after it=7: x_cur(7) is in X0 (xN of it=7), pred(7) is in P1 (pW of it=7)
  k_final<<<(TN*TF + 255)/256, 256, 0, stream>>>((float*)d_out, X0, x_targ, P1);
}

// Round 6
// 777.801 us; speedup vs baseline: 2.0015x; 1.0383x over previous
//
#include <hip/hip_runtime.h>
#include <hip/hip_bf16.h>

#define TB 2
#define TT 2048
#define TD 256
#define TE 64
#define TF 512
#define TN 4096      // TB*TT
#define TCAP 128     // 2*TN/TE
#define NITER 8

typedef __attribute__((ext_vector_type(8))) short bf16x8;
typedef __attribute__((ext_vector_type(4))) float f32x4;

__device__ inline float sanitize(float v){
  if (v != v) return 0.0f;
  const float FMAX = 3.402823466e+38f;
  if (v >  FMAX) return  FMAX;
  if (v < -FMAX) return -FMAX;
  return v;
}

__device__ inline short f2bf(float f){
  union { __hip_bfloat16 h; short s; } u;
  u.h = __float2bfloat16(f);
  return u.s;
}

__device__ inline float gelu_tanh(float x){
  float x3 = x*x*x;
  return 0.5f*x*(1.0f + tanhf(0.7978845608028654f*(x + 0.044715f*x3)));
}

// async global->LDS, 16B per lane; dest = wave-uniform base + lane*16 (our layouts satisfy this)
__device__ __forceinline__ void gload16(const void* g, void* l){
  __builtin_amdgcn_global_load_lds(
      (__attribute__((address_space(1))) void*)g,
      (__attribute__((address_space(3))) void*)l, 16, 0, 0);
}

// ---------------- setup kernels ----------------

__global__ void k_init(const float* __restrict__ xs, const float* __restrict__ cosp,
                       const float* __restrict__ sinp, float* __restrict__ xw,
                       float* __restrict__ xt){
  int idx = blockIdx.x*256 + threadIdx.x;          // over TN*TD
  if (idx >= TN*TD) return;
  int d = idx & (TD-1);
  int n = idx >> 8;
  int t = n & (TT-1);
  float xr = sanitize(xs[2*idx]), xi = sanitize(xs[2*idx+1]);
  xw[2*idx] = xr; xw[2*idx+1] = xi;
  float tr, ti;
  if (t == 0){ tr = xr; ti = xi; }
  else {
    float pr = sanitize(xs[2*(idx-TD)]), pi = sanitize(xs[2*(idx-TD)+1]);
    float c = cosp[d], s = sinp[d];
    tr = pr*c - pi*s;
    ti = pr*s + pi*c;
  }
  xt[2*idx] = tr; xt[2*idx+1] = ti;
}

__global__ __launch_bounds__(64) void k_gatebias(const float* __restrict__ xw,
                                                 const float* __restrict__ wg,
                                                 float* __restrict__ gb){
  __shared__ float mag[TD];
  int n = blockIdx.x, t = threadIdx.x;
  for (int d = t; d < TD; d += 64){
    float xr = xw[(size_t)n*TF + 2*d], xi = xw[(size_t)n*TF + 2*d + 1];
    mag[d] = sqrtf(xr*xr + xi*xi + 1e-8f);
  }
  __syncthreads();
  float acc = 0.f;
  for (int d = 0; d < TD; d++) acc += mag[d]*wg[d*TE + t];
  gb[(size_t)n*TE + t] = acc;
}

// cast+transpose weights: in f32 [e][k][n] -> out bf16 [e][n][k]
__global__ __launch_bounds__(256) void k_castw(const float* __restrict__ W, short* __restrict__ Wt){
  __shared__ float tile[64][68];
  int e = blockIdx.y;
  int kt = (blockIdx.x >> 3) * 64;
  int nt = (blockIdx.x & 7) * 64;
  int tid = threadIdx.x;
  {
    int row = tid >> 4;
    int c4 = (tid & 15) * 4;
    #pragma unroll
    for (int i = 0; i < 4; i++){
      int r = row + i*16;
      float4 v = *(const float4*)(W + ((size_t)e*TF + kt + r)*TF + nt + c4);
      *(float4*)&tile[r][c4] = v;
    }
  }
  __syncthreads();
  #pragma unroll
  for (int i = 0; i < 2; i++){
    int un = tid + i*256;
    int nrow = un >> 3;
    int k8 = (un & 7) * 8;
    bf16x8 o;
    #pragma unroll
    for (int j = 0; j < 8; j++) o[j] = f2bf(tile[k8+j][nrow]);
    *(bf16x8*)(Wt + ((size_t)e*TF + nt + nrow)*TF + kt + k8) = o;
  }
}

// ---------------- fused update + delay + router ----------------

__device__ __forceinline__ void load_row16(const float* __restrict__ xw,
                                           const float* __restrict__ xt,
                                           const float* __restrict__ pr,
                                           size_t off, int upd, float* o){
  const float4* a4 = (const float4*)(xw + off);
  if (upd){
    const float4* t4 = (const float4*)(xt + off);
    const float4* p4 = (const float4*)(pr + off);
    #pragma unroll
    for (int j = 0; j < 4; j++){
      float4 a = a4[j], t = t4[j], p = p4[j];
      float u;
      u = 0.05f*(t.x - p.x); u = fminf(10.f, fmaxf(-10.f, u)); o[4*j+0] = a.x + u;
      u = 0.05f*(t.y - p.y); u = fminf(10.f, fmaxf(-10.f, u)); o[4*j+1] = a.y + u;
      u = 0.05f*(t.z - p.z); u = fminf(10.f, fmaxf(-10.f, u)); o[4*j+2] = a.z + u;
      u = 0.05f*(t.w - p.w); u = fminf(10.f, fmaxf(-10.f, u)); o[4*j+3] = a.w + u;
    }
  } else {
    #pragma unroll
    for (int j = 0; j < 4; j++){
      float4 a = a4[j];
      o[4*j+0] = a.x; o[4*j+1] = a.y; o[4*j+2] = a.z; o[4*j+3] = a.w;
    }
  }
}

// 8 tokens per block, 256 threads.
__global__ __launch_bounds__(256) void k_fuse(
    const float* __restrict__ xOld, float* __restrict__ xNew,
    const float* __restrict__ xt, const float* __restrict__ predR,
    float* __restrict__ predW, const float* __restrict__ g,
    const float* __restrict__ wr, const float* __restrict__ gb,
    short* __restrict__ xbf, float* __restrict__ scoresT, int upd)
{
  __shared__ float xeff[8][516];
  __shared__ float Bt[64][68];
  int tid = threadIdx.x;
  int tok = tid >> 5;            // 0..7
  int kq  = (tid & 31) * 16;     // 16 consecutive floats
  int n   = blockIdx.x*8 + tok;
  int t   = n & (TT-1);
  size_t rowoff = (size_t)n*TF + kq;

  float cur[16], eff[16];
  load_row16(xOld, xt, predR, rowoff, upd, cur);
  #pragma unroll
  for (int q = 0; q < 16; q++) eff[q] = cur[q];
  const int taus[4] = {1,2,3,5};
  int d0 = kq >> 1;
  #pragma unroll
  for (int i = 0; i < 4; i++){
    int tau = taus[i];
    if (t >= tau){
      float nb[16];
      load_row16(xOld, xt, predR, rowoff - (size_t)tau*TF, upd, nb);
      #pragma unroll
      for (int p = 0; p < 8; p++){
        float gr = g[2*(i*TD + d0 + p)];
        float gi = g[2*(i*TD + d0 + p) + 1];
        eff[2*p]   += nb[2*p]*gr - nb[2*p+1]*gi;
        eff[2*p+1] += nb[2*p]*gi + nb[2*p+1]*gr;
      }
    }
  }
  {
    float4* xn = (float4*)(xNew + rowoff);
    float4* pz = (float4*)(predW + rowoff);
    float4 z = make_float4(0.f, 0.f, 0.f, 0.f);
    #pragma unroll
    for (int j = 0; j < 4; j++){
      xn[j] = make_float4(cur[4*j], cur[4*j+1], cur[4*j+2], cur[4*j+3]);
      pz[j] = z;
    }
    bf16x8 o0, o1;
    #pragma unroll
    for (int q = 0; q < 8; q++){ o0[q] = f2bf(eff[q]); o1[q] = f2bf(eff[8+q]); }
    *(bf16x8*)(xbf + rowoff)     = o0;
    *(bf16x8*)(xbf + rowoff + 8) = o1;
    #pragma unroll
    for (int j = 0; j < 4; j++)
      *(float4*)&xeff[tok][kq + 4*j] = make_float4(eff[4*j], eff[4*j+1], eff[4*j+2], eff[4*j+3]);
  }
  __syncthreads();

  // router: thread (tok, tx) computes experts {2tx, 2tx+1} for token n
  int tx = tid & 31;
  float acc0 = gb[(size_t)n*TE + 2*tx];
  float acc1 = gb[(size_t)n*TE + 2*tx + 1];
  int rB = tid >> 2, c16 = (tid & 3)*16;
  for (int kk = 0; kk < TF; kk += 64){
    #pragma unroll
    for (int jj = 0; jj < 4; jj++)
      *(float4*)&Bt[rB][c16 + 4*jj] = *(const float4*)(wr + (size_t)(kk+rB)*TE + c16 + 4*jj);
    __syncthreads();
    #pragma unroll
    for (int k = 0; k < 64; k++){
      float a = xeff[tok][kk + k];
      float2 b = *(const float2*)&Bt[k][2*tx];
      acc0 += a*b.x; acc1 += a*b.y;
    }
    __syncthreads();
  }
  float m = fmaxf(acc0, acc1);
  #pragma unroll
  for (int off = 1; off < 32; off <<= 1) m = fmaxf(m, __shfl_xor(m, off));
  float e0 = expf(acc0 - m), e1 = expf(acc1 - m);
  float s = e0 + e1;
  #pragma unroll
  for (int off = 1; off < 32; off <<= 1) s += __shfl_xor(s, off);
  float inv = 1.0f / s;
  scoresT[(size_t)(2*tx)*TN + n]     = e0*inv;
  scoresT[(size_t)(2*tx+1)*TN + n]   = e1*inv;
}

// per-expert exact top-128: registers + 3-round radix (12/12/8 bits), parallel threshold find
__global__ __launch_bounds__(1024) void k_topk2(const float* __restrict__ scoresT,
                                                int* __restrict__ topi, float* __restrict__ topv){
  int e = blockIdx.x;
  const float* sc = scoresT + (size_t)e*TN;
  __shared__ unsigned int hist[4096];
  __shared__ unsigned int chunkSum[64];
  __shared__ unsigned int s_prefix;
  __shared__ int s_k, s_cnt, s_min;
  int tid = threadIdx.x;
  unsigned int u[4];
  #pragma unroll
  for (int i = 0; i < 4; i++) u[i] = __float_as_uint(sc[tid + i*1024]);
  if (tid == 0){ s_prefix = 0u; s_k = TCAP; }

  const int shifts[3]  = {20, 8, 0};
  const int nbins[3]   = {4096, 4096, 256};
  const unsigned int pmasks[3] = {0u, 0xFFF00000u, 0xFFFFFF00u};
  for (int r = 0; r < 3; r++){
    int shift = shifts[r], nb = nbins[r];
    unsigned int bmask = (unsigned)nb - 1u;
    int logC = (nb == 4096) ? 6 : 2;     // bins per chunk: nb/64
    for (int i = tid; i < nb; i += 1024) hist[i] = 0u;
    if (tid < 64) chunkSum[tid] = 0u;
    __syncthreads();
    unsigned int pref = s_prefix;
    unsigned int pmask = pmasks[r];
    #pragma unroll
    for (int i = 0; i < 4; i++)
      if ((u[i] & pmask) == pref) atomicAdd(&hist[(u[i] >> shift) & bmask], 1u);
    __syncthreads();
    for (int b = tid; b < nb; b += 1024){
      unsigned int h = hist[b];
      if (h) atomicAdd(&chunkSum[b >> logC], h);
    }
    __syncthreads();
    if (tid < 64){
      int chunk = 63 - tid;                     // lane order = descending chunk
      unsigned int s = chunkSum[chunk];
      unsigned int scan = s;
      #pragma unroll
      for (int d = 1; d < 64; d <<= 1){
        unsigned int t = __shfl_up(scan, d);
        if (tid >= d) scan += t;
      }
      unsigned int excl = scan - s;
      int k = s_k;
      if (excl < (unsigned)k && scan >= (unsigned)k){
        int C = 1 << logC;
        unsigned int cum = excl;
        for (int b = C-1; b >= 0; b--){
          unsigned int h = hist[(chunk << logC) + b];
          cum += h;
          if (cum >= (unsigned)k){
            s_k = k - (int)(cum - h);
            s_prefix = pref | ((unsigned)((chunk << logC) + b) << shift);
            break;
          }
        }
      }
    }
    __syncthreads();
  }
  unsigned int thr = s_prefix;
  int need_eq = s_k;
  if (tid == 0) s_cnt = 0;
  __syncthreads();
  #pragma unroll
  for (int i = 0; i < 4; i++){
    if (u[i] > thr){
      int p = atomicAdd(&s_cnt, 1);
      topi[e*TCAP + p] = tid + i*1024;
      topv[e*TCAP + p] = __uint_as_float(u[i]);
    }
  }
  __syncthreads();
  int base = s_cnt;
  int last = -1;
  for (int i = 0; i < need_eq; i++){
    __syncthreads();
    if (tid == 0) s_min = TN;
    __syncthreads();
    #pragma unroll
    for (int j = 0; j < 4; j++){
      int n = tid + j*1024;
      if (u[j] == thr && n > last) atomicMin(&s_min, n);
    }
    __syncthreads();
    int nsel = s_min;
    if (tid == 0){ topi[e*TCAP + base + i] = nsel; topv[e*TCAP + base + i] = __uint_as_float(thr); }
    last = nsel;
  }
}

// ---- GEMMs: bf16 Wt [e][n][k], gload_lds staging with XOR-swizzled source chunks ----
// Swizzle (rule #21, both sides): LDS dest linear; source k-chunk c ^= (row>>1)&3;
// read chunk lh ^= (lr>>1)&3. Breaks the 8-way bank conflict of the 64B-row layout.

__global__ __launch_bounds__(256) void k_gemm1c(const short* __restrict__ xbf,
                                                const short* __restrict__ W1t,
                                                const int* __restrict__ topi,
                                                short* __restrict__ hbf){
  __shared__ __align__(16) short As[2][128*32];
  __shared__ __align__(16) short Bs[2][64*32];
  __shared__ int rows[128];
  int bid = blockIdx.x;
  int swz = (bid & 7)*64 + (bid >> 3);     // XCD-contiguous: one XCD = 8 consecutive experts
  int e = swz >> 3, n0 = (swz & 7)*64;
  int tid = threadIdx.x;
  if (tid < 128) rows[tid] = topi[e*TCAP + tid];
  __syncthreads();
  int r4 = tid >> 2;
  int cs = (((tid & 3) ^ ((r4 >> 1) & 3)))*8;     // swizzled source k-chunk (shorts)
  const short* sA0 = xbf + (size_t)rows[r4]*TF + cs;
  const short* sA1 = xbf + (size_t)rows[r4 + 64]*TF + cs;
  const short* sB  = W1t + ((size_t)e*TF + n0 + r4)*TF + cs;

  int w = tid >> 6, l = tid & 63;
  int lr = l & 15, lh = l >> 4;
  int ch = (lh ^ ((lr >> 1) & 3))*8;              // swizzled read chunk (shorts)
  int aOff0 = (32*w + lr)*32 + ch;
  int aOff1 = aOff0 + 16*32;
  int bOff0 = lr*32 + ch;

  f32x4 acc[2][4];
  #pragma unroll
  for (int m = 0; m < 2; m++)
    #pragma unroll
    for (int j = 0; j < 4; j++)
      #pragma unroll
      for (int r = 0; r < 4; r++) acc[m][j][r] = 0.f;

  gload16(sA0, &As[0][tid*8]);
  gload16(sA1, &As[0][2048 + tid*8]);
  gload16(sB,  &Bs[0][tid*8]);
  __syncthreads();

  int cur = 0;
  for (int t16 = 0; t16 < 16; t16++){
    if (t16 < 15){
      int kk = t16*32 + 32;
      gload16(sA0 + kk, &As[cur^1][tid*8]);
      gload16(sA1 + kk, &As[cur^1][2048 + tid*8]);
      gload16(sB  + kk, &Bs[cur^1][tid*8]);
    }
    bf16x8 a0 = *(const bf16x8*)&As[cur][aOff0];
    bf16x8 a1 = *(const bf16x8*)&As[cur][aOff1];
    #pragma unroll
    for (int j = 0; j < 4; j++){
      bf16x8 b = *(const bf16x8*)&Bs[cur][bOff0 + j*16*32];
      acc[0][j] = __builtin_amdgcn_mfma_f32_16x16x32_bf16(a0, b, acc[0][j], 0, 0, 0);
      acc[1][j] = __builtin_amdgcn_mfma_f32_16x16x32_bf16(a1, b, acc[1][j], 0, 0, 0);
    }
    __syncthreads();
    cur ^= 1;
  }
  short* hdst = hbf + (size_t)e*TCAP*TF;
  #pragma unroll
  for (int m = 0; m < 2; m++)
    #pragma unroll
    for (int j = 0; j < 4; j++)
      #pragma unroll
      for (int r = 0; r < 4; r++){
        int row = 32*w + 16*m + lh*4 + r;
        int col = n0 + 16*j + lr;
        hdst[(size_t)row*TF + col] = f2bf(gelu_tanh(acc[m][j][r]));
      }
}

__global__ __launch_bounds__(256) void k_gemm2c(const short* __restrict__ hbf,
                                                const short* __restrict__ W2t,
                                                const int* __restrict__ topi,
                                                const float* __restrict__ topv,
                                                float* __restrict__ pred){
  __shared__ __align__(16) short As[2][128*32];
  __shared__ __align__(16) short Bs[2][64*32];
  __shared__ int rows[128];
  __shared__ float tv[128];
  int bid = blockIdx.x;
  int swz = (bid & 7)*64 + (bid >> 3);
  int e = swz >> 3, n0 = (swz & 7)*64;
  int tid = threadIdx.x;
  if (tid < 128){ rows[tid] = topi[e*TCAP + tid]; tv[tid] = topv[e*TCAP + tid]; }
  __syncthreads();
  int r4 = tid >> 2;
  int cs = (((tid & 3) ^ ((r4 >> 1) & 3)))*8;
  const short* sA0 = hbf + ((size_t)e*TCAP + r4)*TF + cs;
  const short* sA1 = sA0 + (size_t)64*TF;
  const short* sB  = W2t + ((size_t)e*TF + n0 + r4)*TF + cs;

  int w = tid >> 6, l = tid & 63;
  int lr = l & 15, lh = l >> 4;
  int ch = (lh ^ ((lr >> 1) & 3))*8;
  int aOff0 = (32*w + lr)*32 + ch;
  int aOff1 = aOff0 + 16*32;
  int bOff0 = lr*32 + ch;

  f32x4 acc[2][4];
  #pragma unroll
  for (int m = 0; m < 2; m++)
    #pragma unroll
    for (int j = 0; j < 4; j++)
      #pragma unroll
      for (int r = 0; r < 4; r++) acc[m][j][r] = 0.f;

  gload16(sA0, &As[0][tid*8]);
  gload16(sA1, &As[0][2048 + tid*8]);
  gload16(sB,  &Bs[0][tid*8]);
  __syncthreads();

  int cur = 0;
  for (int t16 = 0; t16 < 16; t16++){
    if (t16 < 15){
      int kk = t16*32 + 32;
      gload16(sA0 + kk, &As[cur^1][tid*8]);
      gload16(sA1 + kk, &As[cur^1][2048 + tid*8]);
      gload16(sB  + kk, &Bs[cur^1][tid*8]);
    }
    bf16x8 a0 = *(const bf16x8*)&As[cur][aOff0];
    bf16x8 a1 = *(const bf16x8*)&As[cur][aOff1];
    #pragma unroll
    for (int j = 0; j < 4; j++){
      bf16x8 b = *(const bf16x8*)&Bs[cur][bOff0 + j*16*32];
      acc[0][j] = __builtin_amdgcn_mfma_f32_16x16x32_bf16(a0, b, acc[0][j], 0, 0, 0);
      acc[1][j] = __builtin_amdgcn_mfma_f32_16x16x32_bf16(a1, b, acc[1][j], 0, 0, 0);
    }
    __syncthreads();
    cur ^= 1;
  }
  #pragma unroll
  for (int m = 0; m < 2; m++)
    #pragma unroll
    for (int j = 0; j < 4; j++)
      #pragma unroll
      for (int r = 0; r < 4; r++){
        int row = 32*w + 16*m + lh*4 + r;
        int col = n0 + 16*j + lr;
        float v = acc[m][j][r] * tv[row];
        atomicAdd(&pred[(size_t)rows[row]*TF + col], v);
      }
}

// ---- fallback GEMMs (f32 weights converted in-kernel) ----

__global__ __launch_bounds__(256) void k_gemm1(const short* __restrict__ xbf,
                                               const float* __restrict__ W1,
                                               const int* __restrict__ topi,
                                               short* __restrict__ hbf){
  __shared__ __align__(16) short As[128][40];
  __shared__ __align__(16) short Bs[64][40];
  __shared__ int rows[128];
  int e = blockIdx.y, n0 = blockIdx.x*64;
  int tid = threadIdx.x;
  if (tid < 128) rows[tid] = topi[e*TCAP + tid];
  __syncthreads();
  int w = tid >> 6, l = tid & 63;
  int lr = l & 15, lh = l >> 4;
  f32x4 acc[2][4];
  #pragma unroll
  for (int m = 0; m < 2; m++)
    #pragma unroll
    for (int j = 0; j < 4; j++)
      #pragma unroll
      for (int r = 0; r < 4; r++) acc[m][j][r] = 0.f;
  int am = tid >> 1, aseg = (tid & 1)*16;
  int br = tid >> 4, bc = (tid & 15)*4;
  const size_t arow = (size_t)rows[am]*TF;
  const float* Wbase = W1 + (size_t)e*TF*TF + n0;
  for (int kk = 0; kk < TF; kk += 32){
    const bf16x8* asrc = (const bf16x8*)(xbf + arow + kk + aseg);
    *(bf16x8*)&As[am][aseg]     = asrc[0];
    *(bf16x8*)&As[am][aseg + 8] = asrc[1];
    #pragma unroll
    for (int rr = br; rr < 32; rr += 16){
      float4 v = *(const float4*)(Wbase + (size_t)(kk+rr)*TF + bc);
      Bs[bc+0][rr] = f2bf(v.x); Bs[bc+1][rr] = f2bf(v.y);
      Bs[bc+2][rr] = f2bf(v.z); Bs[bc+3][rr] = f2bf(v.w);
    }
    __syncthreads();
    bf16x8 a0 = *(const bf16x8*)&As[32*w + lr][lh*8];
    bf16x8 a1 = *(const bf16x8*)&As[32*w + 16 + lr][lh*8];
    #pragma unroll
    for (int j = 0; j < 4; j++){
      bf16x8 b = *(const bf16x8*)&Bs[16*j + lr][lh*8];
      acc[0][j] = __builtin_amdgcn_mfma_f32_16x16x32_bf16(a0, b, acc[0][j], 0, 0, 0);
      acc[1][j] = __builtin_amdgcn_mfma_f32_16x16x32_bf16(a1, b, acc[1][j], 0, 0, 0);
    }
    __syncthreads();
  }
  short* hdst = hbf + (size_t)e*TCAP*TF;
  #pragma unroll
  for (int m = 0; m < 2; m++)
    #pragma unroll
    for (int j = 0; j < 4; j++)
      #pragma unroll
      for (int r = 0; r < 4; r++){
        int row = 32*w + 16*m + lh*4 + r;
        int col = n0 + 16*j + lr;
        hdst[(size_t)row*TF + col] = f2bf(gelu_tanh(acc[m][j][r]));
      }
}

__global__ __launch_bounds__(256) void k_gemm2(const short* __restrict__ hbf,
                                               const float* __restrict__ W2,
                                               const int* __restrict__ topi,
                                               const float* __restrict__ topv,
                                               float* __restrict__ pred){
  __shared__ __align__(16) short As[128][40];
  __shared__ __align__(16) short Bs[64][40];
  __shared__ int rows[128];
  __shared__ float tv[128];
  int e = blockIdx.y, n0 = blockIdx.x*64;
  int tid = threadIdx.x;
  if (tid < 128){ rows[tid] = topi[e*TCAP + tid]; tv[tid] = topv[e*TCAP + tid]; }
  __syncthreads();
  int w = tid >> 6, l = tid & 63;
  int lr = l & 15, lh = l >> 4;
  f32x4 acc[2][4];
  #pragma unroll
  for (int m = 0; m < 2; m++)
    #pragma unroll
    for (int j = 0; j < 4; j++)
      #pragma unroll
      for (int r = 0; r < 4; r++) acc[m][j][r] = 0.f;
  int am = tid >> 1, aseg = (tid & 1)*16;
  int br = tid >> 4, bc = (tid & 15)*4;
  const short* asrcbase = hbf + ((size_t)e*TCAP + am)*TF;
  const float* Wbase = W2 + (size_t)e*TF*TF + n0;
  for (int kk = 0; kk < TF; kk += 32){
    const bf16x8* asrc = (const bf16x8*)(asrcbase + kk + aseg);
    *(bf16x8*)&As[am][aseg]     = asrc[0];
    *(bf16x8*)&As[am][aseg + 8] = asrc[1];
    #pragma unroll
    for (int rr = br; rr < 32; rr += 16){
      float4 v = *(const float4*)(Wbase + (size_t)(kk+rr)*TF + bc);
      Bs[bc+0][rr] = f2bf(v.x); Bs[bc+1][rr] = f2bf(v.y);
      Bs[bc+2][rr] = f2bf(v.z); Bs[bc+3][rr] = f2bf(v.w);
    }
    __syncthreads();
    bf16x8 a0 = *(const bf16x8*)&As[32*w + lr][lh*8];
    bf16x8 a1 = *(const bf16x8*)&As[32*w + 16 + lr][lh*8];
    #pragma unroll
    for (int j = 0; j < 4; j++){
      bf16x8 b = *(const bf16x8*)&Bs[16*j + lr][lh*8];
      acc[0][j] = __builtin_amdgcn_mfma_f32_16x16x32_bf16(a0, b, acc[0][j], 0, 0, 0);
      acc[1][j] = __builtin_amdgcn_mfma_f32_16x16x32_bf16(a1, b, acc[1][j], 0, 0, 0);
    }
    __syncthreads();
  }
  #pragma unroll
  for (int m = 0; m < 2; m++)
    #pragma unroll
    for (int j = 0; j < 4; j++)
      #pragma unroll
      for (int r = 0; r < 4; r++){
        int row = 32*w + 16*m + lh*4 + r;
        int col = n0 + 16*j + lr;
        float v = acc[m][j][r] * tv[row];
        atomicAdd(&pred[(size_t)rows[row]*TF + col], v);
      }
}

// out = x + clip(0.05*(xt - pred))
__global__ void k_final(float* __restrict__ out, const float* __restrict__ x,
                        const float* __restrict__ xt, const float* __restrict__ pred){
  int i = blockIdx.x*256 + threadIdx.x;
  if (i >= TN*TF) return;
  float u = 0.05f*(xt[i] - pred[i]);
  u = fminf(10.0f, fmaxf(-10.0f, u));
  out[i] = x[i] + u;
}

extern "C" void kernel_launch(void* const* d_in, const int* in_sizes, int n_in,
                              void* d_out, int out_size, void* d_ws, size_t ws_size,
                              hipStream_t stream){
  (void)in_sizes; (void)n_in; (void)out_size;
  const float* x_stream = (const float*)d_in[0];
  const float* gains    = (const float*)d_in[1];
  const float* Wg       = (const float*)d_in[2];
  const float* Wr       = (const float*)d_in[3];
  const float* W1       = (const float*)d_in[4];
  const float* W2       = (const float*)d_in[5];
  const float* cosp     = (const float*)d_in[6];
  const float* sinp     = (const float*)d_in[7];

  size_t off = 0;
  char* base = (char*)d_ws;
  auto alloc = [&](size_t bytes) -> void* {
    void* p = base + off;
    off += (bytes + 255) & ~(size_t)255;
    return p;
  };
  float* X0      = (float*)alloc((size_t)TN*TF*4);   // x ping
  float* X1      = (float*)alloc((size_t)TN*TF*4);   // x pong
  float* x_targ  = (float*)alloc((size_t)TN*TF*4);
  short* xf_bf   = (short*)alloc((size_t)TN*TF*2);
  float* gateb   = (float*)alloc((size_t)TN*TE*4);
  float* scoresT = (float*)alloc((size_t)TE*TN*4);
  int*   topi    = (int*)  alloc((size_t)TE*TCAP*4);
  float* topv    = (float*)alloc((size_t)TE*TCAP*4);
  short* h_bf    = (short*)alloc((size_t)TE*TCAP*TF*2);
  float* P0      = (float*)alloc((size_t)TN*TF*4);   // pred ping
  float* P1      = (float*)alloc((size_t)TN*TF*4);   // pred pong
  short* W1t     = (short*)alloc((size_t)TE*TF*TF*2);
  short* W2t     = (short*)alloc((size_t)TE*TF*TF*2);
  bool useT = (off <= ws_size);

  k_init<<<(TN*TD + 255)/256, 256, 0, stream>>>(x_stream, cosp, sinp, X0, x_targ);
  k_gatebias<<<TN, 64, 0, stream>>>(X0, Wg, gateb);
  if (useT){
    k_castw<<<dim3(64, TE), 256, 0, stream>>>(W1, W1t);
    k_castw<<<dim3(64, TE), 256, 0, stream>>>(W2, W2t);
  }

  for (int it = 0; it < NITER; it++){
    const float* xO = (it & 1) ? X1 : X0;
    float*       xN = (it & 1) ? X0 : X1;
    float*       pW = (it & 1) ? P1 : P0;
    const float* pR = (it & 1) ? P0 : P1;
    k_fuse<<<TN/8, 256, 0, stream>>>(xO, xN, x_targ, pR, pW, gains, Wr, gateb,
                                     xf_bf, scoresT, it > 0 ? 1 : 0);
    k_topk2<<<TE, 1024, 0, stream>>>(scoresT, topi, topv);
    if (useT){
      k_gemm1c<<<TF/64*TE, 256, 0, stream>>>(xf_bf, W1t, topi, h_bf);
      k_gemm2c<<<TF/64*TE, 256, 0, stream>>>(h_bf, W2t, topi, topv, pW);
    } else {
      k_gemm1<<<dim3(TF/64, TE), 256, 0, stream>>>(xf_bf, W1, topi, h_bf);
      k_gemm2<<<dim3(TF/64, TE), 256, 0, stream>>>(h_bf, W2, topi, topv, pW);
    }
  }
  // after it=7: x_cur(7) is in X0 (xN of it=7), pred(7) is in P1 (pW of it=7)
  k_final<<<(TN*TF + 255)/256, 256, 0, stream>>>((float*)d_out, X0, x_targ, P1);
}

// Round 7
// 732.242 us; speedup vs baseline: 2.1261x; 1.0622x over previous
//
#include <hip/hip_runtime.h>
#include <hip/hip_bf16.h>

#define TB 2
#define TT 2048
#define TD 256
#define TE 64
#define TF 512
#define TN 4096      // TB*TT
#define TCAP 128     // 2*TN/TE
#define NITER 8

typedef __attribute__((ext_vector_type(8))) short bf16x8;
typedef __attribute__((ext_vector_type(4))) float f32x4;

__device__ inline float sanitize(float v){
  if (v != v) return 0.0f;
  const float FMAX = 3.402823466e+38f;
  if (v >  FMAX) return  FMAX;
  if (v < -FMAX) return -FMAX;
  return v;
}

__device__ inline short f2bf(float f){
  union { __hip_bfloat16 h; short s; } u;
  u.h = __float2bfloat16(f);
  return u.s;
}

__device__ inline float gelu_tanh(float x){
  float x3 = x*x*x;
  return 0.5f*x*(1.0f + tanhf(0.7978845608028654f*(x + 0.044715f*x3)));
}

// async global->LDS, 16B per lane; dest = wave-uniform base + lane*16 (our layouts satisfy this)
__device__ __forceinline__ void gload16(const void* g, void* l){
  __builtin_amdgcn_global_load_lds(
      (__attribute__((address_space(1))) void*)g,
      (__attribute__((address_space(3))) void*)l, 16, 0, 0);
}

// ---------------- setup kernels ----------------

__global__ void k_init(const float* __restrict__ xs, const float* __restrict__ cosp,
                       const float* __restrict__ sinp, float* __restrict__ xw,
                       float* __restrict__ xt){
  int idx = blockIdx.x*256 + threadIdx.x;          // over TN*TD
  if (idx >= TN*TD) return;
  int d = idx & (TD-1);
  int n = idx >> 8;
  int t = n & (TT-1);
  float xr = sanitize(xs[2*idx]), xi = sanitize(xs[2*idx+1]);
  xw[2*idx] = xr; xw[2*idx+1] = xi;
  float tr, ti;
  if (t == 0){ tr = xr; ti = xi; }
  else {
    float pr = sanitize(xs[2*(idx-TD)]), pi = sanitize(xs[2*(idx-TD)+1]);
    float c = cosp[d], s = sinp[d];
    tr = pr*c - pi*s;
    ti = pr*s + pi*c;
  }
  xt[2*idx] = tr; xt[2*idx+1] = ti;
}

__global__ __launch_bounds__(64) void k_gatebias(const float* __restrict__ xw,
                                                 const float* __restrict__ wg,
                                                 float* __restrict__ gb){
  __shared__ float mag[TD];
  int n = blockIdx.x, t = threadIdx.x;
  for (int d = t; d < TD; d += 64){
    float xr = xw[(size_t)n*TF + 2*d], xi = xw[(size_t)n*TF + 2*d + 1];
    mag[d] = sqrtf(xr*xr + xi*xi + 1e-8f);
  }
  __syncthreads();
  float acc = 0.f;
  for (int d = 0; d < TD; d++) acc += mag[d]*wg[d*TE + t];
  gb[(size_t)n*TE + t] = acc;
}

// cast+transpose weights: in f32 [e][k][n] -> out bf16 [e][n][k]
__global__ __launch_bounds__(256) void k_castw(const float* __restrict__ W, short* __restrict__ Wt){
  __shared__ float tile[64][68];
  int e = blockIdx.y;
  int kt = (blockIdx.x >> 3) * 64;
  int nt = (blockIdx.x & 7) * 64;
  int tid = threadIdx.x;
  {
    int row = tid >> 4;
    int c4 = (tid & 15) * 4;
    #pragma unroll
    for (int i = 0; i < 4; i++){
      int r = row + i*16;
      float4 v = *(const float4*)(W + ((size_t)e*TF + kt + r)*TF + nt + c4);
      *(float4*)&tile[r][c4] = v;
    }
  }
  __syncthreads();
  #pragma unroll
  for (int i = 0; i < 2; i++){
    int un = tid + i*256;
    int nrow = un >> 3;
    int k8 = (un & 7) * 8;
    bf16x8 o;
    #pragma unroll
    for (int j = 0; j < 8; j++) o[j] = f2bf(tile[k8+j][nrow]);
    *(bf16x8*)(Wt + ((size_t)e*TF + nt + nrow)*TF + kt + k8) = o;
  }
}

// ---------------- fused update + delay + router ----------------

__device__ __forceinline__ void load_row16(const float* __restrict__ xw,
                                           const float* __restrict__ xt,
                                           const float* __restrict__ pr,
                                           size_t off, int upd, float* o){
  const float4* a4 = (const float4*)(xw + off);
  if (upd){
    const float4* t4 = (const float4*)(xt + off);
    const float4* p4 = (const float4*)(pr + off);
    #pragma unroll
    for (int j = 0; j < 4; j++){
      float4 a = a4[j], t = t4[j], p = p4[j];
      float u;
      u = 0.05f*(t.x - p.x); u = fminf(10.f, fmaxf(-10.f, u)); o[4*j+0] = a.x + u;
      u = 0.05f*(t.y - p.y); u = fminf(10.f, fmaxf(-10.f, u)); o[4*j+1] = a.y + u;
      u = 0.05f*(t.z - p.z); u = fminf(10.f, fmaxf(-10.f, u)); o[4*j+2] = a.z + u;
      u = 0.05f*(t.w - p.w); u = fminf(10.f, fmaxf(-10.f, u)); o[4*j+3] = a.w + u;
    }
  } else {
    #pragma unroll
    for (int j = 0; j < 4; j++){
      float4 a = a4[j];
      o[4*j+0] = a.x; o[4*j+1] = a.y; o[4*j+2] = a.z; o[4*j+3] = a.w;
    }
  }
}

// 8 tokens per block, 256 threads.
__global__ __launch_bounds__(256) void k_fuse(
    const float* __restrict__ xOld, float* __restrict__ xNew,
    const float* __restrict__ xt, const float* __restrict__ predR,
    float* __restrict__ predW, const float* __restrict__ g,
    const float* __restrict__ wr, const float* __restrict__ gb,
    short* __restrict__ xbf, float* __restrict__ scoresT, int upd)
{
  __shared__ float xeff[8][516];
  __shared__ float Bt[64][68];
  int tid = threadIdx.x;
  int tok = tid >> 5;            // 0..7
  int kq  = (tid & 31) * 16;     // 16 consecutive floats
  int n   = blockIdx.x*8 + tok;
  int t   = n & (TT-1);
  size_t rowoff = (size_t)n*TF + kq;

  float cur[16], eff[16];
  load_row16(xOld, xt, predR, rowoff, upd, cur);
  #pragma unroll
  for (int q = 0; q < 16; q++) eff[q] = cur[q];
  const int taus[4] = {1,2,3,5};
  int d0 = kq >> 1;
  #pragma unroll
  for (int i = 0; i < 4; i++){
    int tau = taus[i];
    if (t >= tau){
      float nb[16];
      load_row16(xOld, xt, predR, rowoff - (size_t)tau*TF, upd, nb);
      #pragma unroll
      for (int p = 0; p < 8; p++){
        float gr = g[2*(i*TD + d0 + p)];
        float gi = g[2*(i*TD + d0 + p) + 1];
        eff[2*p]   += nb[2*p]*gr - nb[2*p+1]*gi;
        eff[2*p+1] += nb[2*p]*gi + nb[2*p+1]*gr;
      }
    }
  }
  {
    float4* xn = (float4*)(xNew + rowoff);
    float4* pz = (float4*)(predW + rowoff);
    float4 z = make_float4(0.f, 0.f, 0.f, 0.f);
    #pragma unroll
    for (int j = 0; j < 4; j++){
      xn[j] = make_float4(cur[4*j], cur[4*j+1], cur[4*j+2], cur[4*j+3]);
      pz[j] = z;
    }
    bf16x8 o0, o1;
    #pragma unroll
    for (int q = 0; q < 8; q++){ o0[q] = f2bf(eff[q]); o1[q] = f2bf(eff[8+q]); }
    *(bf16x8*)(xbf + rowoff)     = o0;
    *(bf16x8*)(xbf + rowoff + 8) = o1;
    #pragma unroll
    for (int j = 0; j < 4; j++)
      *(float4*)&xeff[tok][kq + 4*j] = make_float4(eff[4*j], eff[4*j+1], eff[4*j+2], eff[4*j+3]);
  }
  __syncthreads();

  // router: thread (tok, tx) computes experts {2tx, 2tx+1} for token n
  int tx = tid & 31;
  float acc0 = gb[(size_t)n*TE + 2*tx];
  float acc1 = gb[(size_t)n*TE + 2*tx + 1];
  int rB = tid >> 2, c16 = (tid & 3)*16;
  for (int kk = 0; kk < TF; kk += 64){
    #pragma unroll
    for (int jj = 0; jj < 4; jj++)
      *(float4*)&Bt[rB][c16 + 4*jj] = *(const float4*)(wr + (size_t)(kk+rB)*TE + c16 + 4*jj);
    __syncthreads();
    #pragma unroll
    for (int k = 0; k < 64; k++){
      float a = xeff[tok][kk + k];
      float2 b = *(const float2*)&Bt[k][2*tx];
      acc0 += a*b.x; acc1 += a*b.y;
    }
    __syncthreads();
  }
  float m = fmaxf(acc0, acc1);
  #pragma unroll
  for (int off = 1; off < 32; off <<= 1) m = fmaxf(m, __shfl_xor(m, off));
  float e0 = expf(acc0 - m), e1 = expf(acc1 - m);
  float s = e0 + e1;
  #pragma unroll
  for (int off = 1; off < 32; off <<= 1) s += __shfl_xor(s, off);
  float inv = 1.0f / s;
  scoresT[(size_t)(2*tx)*TN + n]     = e0*inv;
  scoresT[(size_t)(2*tx+1)*TN + n]   = e1*inv;
}

// per-expert exact top-128: registers + 3-round radix (12/12/8 bits), parallel threshold find
__global__ __launch_bounds__(1024) void k_topk2(const float* __restrict__ scoresT,
                                                int* __restrict__ topi, float* __restrict__ topv){
  int e = blockIdx.x;
  const float* sc = scoresT + (size_t)e*TN;
  __shared__ unsigned int hist[4096];
  __shared__ unsigned int chunkSum[64];
  __shared__ unsigned int s_prefix;
  __shared__ int s_k, s_cnt, s_min;
  int tid = threadIdx.x;
  unsigned int u[4];
  #pragma unroll
  for (int i = 0; i < 4; i++) u[i] = __float_as_uint(sc[tid + i*1024]);
  if (tid == 0){ s_prefix = 0u; s_k = TCAP; }

  const int shifts[3]  = {20, 8, 0};
  const int nbins[3]   = {4096, 4096, 256};
  const unsigned int pmasks[3] = {0u, 0xFFF00000u, 0xFFFFFF00u};
  for (int r = 0; r < 3; r++){
    int shift = shifts[r], nb = nbins[r];
    unsigned int bmask = (unsigned)nb - 1u;
    int logC = (nb == 4096) ? 6 : 2;     // bins per chunk: nb/64
    for (int i = tid; i < nb; i += 1024) hist[i] = 0u;
    if (tid < 64) chunkSum[tid] = 0u;
    __syncthreads();
    unsigned int pref = s_prefix;
    unsigned int pmask = pmasks[r];
    #pragma unroll
    for (int i = 0; i < 4; i++)
      if ((u[i] & pmask) == pref) atomicAdd(&hist[(u[i] >> shift) & bmask], 1u);
    __syncthreads();
    for (int b = tid; b < nb; b += 1024){
      unsigned int h = hist[b];
      if (h) atomicAdd(&chunkSum[b >> logC], h);
    }
    __syncthreads();
    if (tid < 64){
      int chunk = 63 - tid;                     // lane order = descending chunk
      unsigned int s = chunkSum[chunk];
      unsigned int scan = s;
      #pragma unroll
      for (int d = 1; d < 64; d <<= 1){
        unsigned int t = __shfl_up(scan, d);
        if (tid >= d) scan += t;
      }
      unsigned int excl = scan - s;
      int k = s_k;
      if (excl < (unsigned)k && scan >= (unsigned)k){
        int C = 1 << logC;
        unsigned int cum = excl;
        for (int b = C-1; b >= 0; b--){
          unsigned int h = hist[(chunk << logC) + b];
          cum += h;
          if (cum >= (unsigned)k){
            s_k = k - (int)(cum - h);
            s_prefix = pref | ((unsigned)((chunk << logC) + b) << shift);
            break;
          }
        }
      }
    }
    __syncthreads();
  }
  unsigned int thr = s_prefix;
  int need_eq = s_k;
  if (tid == 0) s_cnt = 0;
  __syncthreads();
  #pragma unroll
  for (int i = 0; i < 4; i++){
    if (u[i] > thr){
      int p = atomicAdd(&s_cnt, 1);
      topi[e*TCAP + p] = tid + i*1024;
      topv[e*TCAP + p] = __uint_as_float(u[i]);
    }
  }
  __syncthreads();
  int base = s_cnt;
  int last = -1;
  for (int i = 0; i < need_eq; i++){
    __syncthreads();
    if (tid == 0) s_min = TN;
    __syncthreads();
    #pragma unroll
    for (int j = 0; j < 4; j++){
      int n = tid + j*1024;
      if (u[j] == thr && n > last) atomicMin(&s_min, n);
    }
    __syncthreads();
    int nsel = s_min;
    if (tid == 0){ topi[e*TCAP + base + i] = nsel; topv[e*TCAP + base + i] = __uint_as_float(thr); }
    last = nsel;
  }
}

// ---- GEMMs: bf16 Wt [e][n][k], gload_lds + XOR-swizzle + COUNTED vmcnt pipeline ----
// Per K-step: issue prefetch -> vmcnt(3) (only current buffer's loads) -> s_barrier ->
// compute -> s_barrier. Prefetch stays in flight across barriers (T4).

__global__ __launch_bounds__(256) void k_gemm1c(const short* __restrict__ xbf,
                                                const short* __restrict__ W1t,
                                                const int* __restrict__ topi,
                                                short* __restrict__ hbf){
  __shared__ __align__(16) short As[2][128*32];
  __shared__ __align__(16) short Bs[2][64*32];
  __shared__ int rows[128];
  int bid = blockIdx.x;
  int swz = (bid & 7)*64 + (bid >> 3);     // XCD-contiguous: one XCD = 8 consecutive experts
  int e = swz >> 3, n0 = (swz & 7)*64;
  int tid = threadIdx.x;
  if (tid < 128) rows[tid] = topi[e*TCAP + tid];
  __syncthreads();
  int r4 = tid >> 2;
  int cs = (((tid & 3) ^ ((r4 >> 1) & 3)))*8;     // swizzled source k-chunk (shorts)
  const short* sA0 = xbf + (size_t)rows[r4]*TF + cs;
  const short* sA1 = xbf + (size_t)rows[r4 + 64]*TF + cs;
  const short* sB  = W1t + ((size_t)e*TF + n0 + r4)*TF + cs;

  int w = tid >> 6, l = tid & 63;
  int lr = l & 15, lh = l >> 4;
  int ch = (lh ^ ((lr >> 1) & 3))*8;              // swizzled read chunk (shorts)
  int aOff0 = (32*w + lr)*32 + ch;
  int aOff1 = aOff0 + 16*32;
  int bOff0 = lr*32 + ch;

  f32x4 acc[2][4];
  #pragma unroll
  for (int m = 0; m < 2; m++)
    #pragma unroll
    for (int j = 0; j < 4; j++)
      #pragma unroll
      for (int r = 0; r < 4; r++) acc[m][j][r] = 0.f;

  gload16(sA0, &As[0][tid*8]);
  gload16(sA1, &As[0][2048 + tid*8]);
  gload16(sB,  &Bs[0][tid*8]);

  int cur = 0;
  for (int t16 = 0; t16 < 16; t16++){
    if (t16 < 15){
      int kk = t16*32 + 32;
      gload16(sA0 + kk, &As[cur^1][tid*8]);
      gload16(sA1 + kk, &As[cur^1][2048 + tid*8]);
      gload16(sB  + kk, &Bs[cur^1][tid*8]);
      asm volatile("s_waitcnt vmcnt(3)" ::: "memory");
    } else {
      asm volatile("s_waitcnt vmcnt(0)" ::: "memory");
    }
    __builtin_amdgcn_sched_barrier(0);
    __builtin_amdgcn_s_barrier();          // current buffer loaded by ALL waves
    __builtin_amdgcn_sched_barrier(0);
    bf16x8 a0 = *(const bf16x8*)&As[cur][aOff0];
    bf16x8 a1 = *(const bf16x8*)&As[cur][aOff1];
    #pragma unroll
    for (int j = 0; j < 4; j++){
      bf16x8 b = *(const bf16x8*)&Bs[cur][bOff0 + j*16*32];
      acc[0][j] = __builtin_amdgcn_mfma_f32_16x16x32_bf16(a0, b, acc[0][j], 0, 0, 0);
      acc[1][j] = __builtin_amdgcn_mfma_f32_16x16x32_bf16(a1, b, acc[1][j], 0, 0, 0);
    }
    __builtin_amdgcn_sched_barrier(0);
    __builtin_amdgcn_s_barrier();          // all waves done reading -> safe to overwrite
    cur ^= 1;
  }
  short* hdst = hbf + (size_t)e*TCAP*TF;
  #pragma unroll
  for (int m = 0; m < 2; m++)
    #pragma unroll
    for (int j = 0; j < 4; j++)
      #pragma unroll
      for (int r = 0; r < 4; r++){
        int row = 32*w + 16*m + lh*4 + r;
        int col = n0 + 16*j + lr;
        hdst[(size_t)row*TF + col] = f2bf(gelu_tanh(acc[m][j][r]));
      }
}

__global__ __launch_bounds__(256) void k_gemm2c(const short* __restrict__ hbf,
                                                const short* __restrict__ W2t,
                                                const int* __restrict__ topi,
                                                const float* __restrict__ topv,
                                                float* __restrict__ pred){
  __shared__ __align__(16) short As[2][128*32];
  __shared__ __align__(16) short Bs[2][64*32];
  __shared__ int rows[128];
  __shared__ float tv[128];
  int bid = blockIdx.x;
  int swz = (bid & 7)*64 + (bid >> 3);
  int e = swz >> 3, n0 = (swz & 7)*64;
  int tid = threadIdx.x;
  if (tid < 128){ rows[tid] = topi[e*TCAP + tid]; tv[tid] = topv[e*TCAP + tid]; }
  __syncthreads();
  int r4 = tid >> 2;
  int cs = (((tid & 3) ^ ((r4 >> 1) & 3)))*8;
  const short* sA0 = hbf + ((size_t)e*TCAP + r4)*TF + cs;
  const short* sA1 = sA0 + (size_t)64*TF;
  const short* sB  = W2t + ((size_t)e*TF + n0 + r4)*TF + cs;

  int w = tid >> 6, l = tid & 63;
  int lr = l & 15, lh = l >> 4;
  int ch = (lh ^ ((lr >> 1) & 3))*8;
  int aOff0 = (32*w + lr)*32 + ch;
  int aOff1 = aOff0 + 16*32;
  int bOff0 = lr*32 + ch;

  f32x4 acc[2][4];
  #pragma unroll
  for (int m = 0; m < 2; m++)
    #pragma unroll
    for (int j = 0; j < 4; j++)
      #pragma unroll
      for (int r = 0; r < 4; r++) acc[m][j][r] = 0.f;

  gload16(sA0, &As[0][tid*8]);
  gload16(sA1, &As[0][2048 + tid*8]);
  gload16(sB,  &Bs[0][tid*8]);

  int cur = 0;
  for (int t16 = 0; t16 < 16; t16++){
    if (t16 < 15){
      int kk = t16*32 + 32;
      gload16(sA0 + kk, &As[cur^1][tid*8]);
      gload16(sA1 + kk, &As[cur^1][2048 + tid*8]);
      gload16(sB  + kk, &Bs[cur^1][tid*8]);
      asm volatile("s_waitcnt vmcnt(3)" ::: "memory");
    } else {
      asm volatile("s_waitcnt vmcnt(0)" ::: "memory");
    }
    __builtin_amdgcn_sched_barrier(0);
    __builtin_amdgcn_s_barrier();
    __builtin_amdgcn_sched_barrier(0);
    bf16x8 a0 = *(const bf16x8*)&As[cur][aOff0];
    bf16x8 a1 = *(const bf16x8*)&As[cur][aOff1];
    #pragma unroll
    for (int j = 0; j < 4; j++){
      bf16x8 b = *(const bf16x8*)&Bs[cur][bOff0 + j*16*32];
      acc[0][j] = __builtin_amdgcn_mfma_f32_16x16x32_bf16(a0, b, acc[0][j], 0, 0, 0);
      acc[1][j] = __builtin_amdgcn_mfma_f32_16x16x32_bf16(a1, b, acc[1][j], 0, 0, 0);
    }
    __builtin_amdgcn_sched_barrier(0);
    __builtin_amdgcn_s_barrier();
    cur ^= 1;
  }
  #pragma unroll
  for (int m = 0; m < 2; m++)
    #pragma unroll
    for (int j = 0; j < 4; j++)
      #pragma unroll
      for (int r = 0; r < 4; r++){
        int row = 32*w + 16*m + lh*4 + r;
        int col = n0 + 16*j + lr;
        float v = acc[m][j][r] * tv[row];
        atomicAdd(&pred[(size_t)rows[row]*TF + col], v);
      }
}

// ---- fallback GEMMs (f32 weights converted in-kernel) ----

__global__ __launch_bounds__(256) void k_gemm1(const short* __restrict__ xbf,
                                               const float* __restrict__ W1,
                                               const int* __restrict__ topi,
                                               short* __restrict__ hbf){
  __shared__ __align__(16) short As[128][40];
  __shared__ __align__(16) short Bs[64][40];
  __shared__ int rows[128];
  int e = blockIdx.y, n0 = blockIdx.x*64;
  int tid = threadIdx.x;
  if (tid < 128) rows[tid] = topi[e*TCAP + tid];
  __syncthreads();
  int w = tid >> 6, l = tid & 63;
  int lr = l & 15, lh = l >> 4;
  f32x4 acc[2][4];
  #pragma unroll
  for (int m = 0; m < 2; m++)
    #pragma unroll
    for (int j = 0; j < 4; j++)
      #pragma unroll
      for (int r = 0; r < 4; r++) acc[m][j][r] = 0.f;
  int am = tid >> 1, aseg = (tid & 1)*16;
  int br = tid >> 4, bc = (tid & 15)*4;
  const size_t arow = (size_t)rows[am]*TF;
  const float* Wbase = W1 + (size_t)e*TF*TF + n0;
  for (int kk = 0; kk < TF; kk += 32){
    const bf16x8* asrc = (const bf16x8*)(xbf + arow + kk + aseg);
    *(bf16x8*)&As[am][aseg]     = asrc[0];
    *(bf16x8*)&As[am][aseg + 8] = asrc[1];
    #pragma unroll
    for (int rr = br; rr < 32; rr += 16){
      float4 v = *(const float4*)(Wbase + (size_t)(kk+rr)*TF + bc);
      Bs[bc+0][rr] = f2bf(v.x); Bs[bc+1][rr] = f2bf(v.y);
      Bs[bc+2][rr] = f2bf(v.z); Bs[bc+3][rr] = f2bf(v.w);
    }
    __syncthreads();
    bf16x8 a0 = *(const bf16x8*)&As[32*w + lr][lh*8];
    bf16x8 a1 = *(const bf16x8*)&As[32*w + 16 + lr][lh*8];
    #pragma unroll
    for (int j = 0; j < 4; j++){
      bf16x8 b = *(const bf16x8*)&Bs[16*j + lr][lh*8];
      acc[0][j] = __builtin_amdgcn_mfma_f32_16x16x32_bf16(a0, b, acc[0][j], 0, 0, 0);
      acc[1][j] = __builtin_amdgcn_mfma_f32_16x16x32_bf16(a1, b, acc[1][j], 0, 0, 0);
    }
    __syncthreads();
  }
  short* hdst = hbf + (size_t)e*TCAP*TF;
  #pragma unroll
  for (int m = 0; m < 2; m++)
    #pragma unroll
    for (int j = 0; j < 4; j++)
      #pragma unroll
      for (int r = 0; r < 4; r++){
        int row = 32*w + 16*m + lh*4 + r;
        int col = n0 + 16*j + lr;
        hdst[(size_t)row*TF + col] = f2bf(gelu_tanh(acc[m][j][r]));
      }
}

__global__ __launch_bounds__(256) void k_gemm2(const short* __restrict__ hbf,
                                               const float* __restrict__ W2,
                                               const int* __restrict__ topi,
                                               const float* __restrict__ topv,
                                               float* __restrict__ pred){
  __shared__ __align__(16) short As[128][40];
  __shared__ __align__(16) short Bs[64][40];
  __shared__ int rows[128];
  __shared__ float tv[128];
  int e = blockIdx.y, n0 = blockIdx.x*64;
  int tid = threadIdx.x;
  if (tid < 128){ rows[tid] = topi[e*TCAP + tid]; tv[tid] = topv[e*TCAP + tid]; }
  __syncthreads();
  int w = tid >> 6, l = tid & 63;
  int lr = l & 15, lh = l >> 4;
  f32x4 acc[2][4];
  #pragma unroll
  for (int m = 0; m < 2; m++)
    #pragma unroll
    for (int j = 0; j < 4; j++)
      #pragma unroll
      for (int r = 0; r < 4; r++) acc[m][j][r] = 0.f;
  int am = tid >> 1, aseg = (tid & 1)*16;
  int br = tid >> 4, bc = (tid & 15)*4;
  const short* asrcbase = hbf + ((size_t)e*TCAP + am)*TF;
  const float* Wbase = W2 + (size_t)e*TF*TF + n0;
  for (int kk = 0; kk < TF; kk += 32){
    const bf16x8* asrc = (const bf16x8*)(asrcbase + kk + aseg);
    *(bf16x8*)&As[am][aseg]     = asrc[0];
    *(bf16x8*)&As[am][aseg + 8] = asrc[1];
    #pragma unroll
    for (int rr = br; rr < 32; rr += 16){
      float4 v = *(const float4*)(Wbase + (size_t)(kk+rr)*TF + bc);
      Bs[bc+0][rr] = f2bf(v.x); Bs[bc+1][rr] = f2bf(v.y);
      Bs[bc+2][rr] = f2bf(v.z); Bs[bc+3][rr] = f2bf(v.w);
    }
    __syncthreads();
    bf16x8 a0 = *(const bf16x8*)&As[32*w + lr][lh*8];
    bf16x8 a1 = *(const bf16x8*)&As[32*w + 16 + lr][lh*8];
    #pragma unroll
    for (int j = 0; j < 4; j++){
      bf16x8 b = *(const bf16x8*)&Bs[16*j + lr][lh*8];
      acc[0][j] = __builtin_amdgcn_mfma_f32_16x16x32_bf16(a0, b, acc[0][j], 0, 0, 0);
      acc[1][j] = __builtin_amdgcn_mfma_f32_16x16x32_bf16(a1, b, acc[1][j], 0, 0, 0);
    }
    __syncthreads();
  }
  #pragma unroll
  for (int m = 0; m < 2; m++)
    #pragma unroll
    for (int j = 0; j < 4; j++)
      #pragma unroll
      for (int r = 0; r < 4; r++){
        int row = 32*w + 16*m + lh*4 + r;
        int col = n0 + 16*j + lr;
        float v = acc[m][j][r] * tv[row];
        atomicAdd(&pred[(size_t)rows[row]*TF + col], v);
      }
}

// out = x + clip(0.05*(xt - pred))
__global__ void k_final(float* __restrict__ out, const float* __restrict__ x,
                        const float* __restrict__ xt, const float* __restrict__ pred){
  int i = blockIdx.x*256 + threadIdx.x;
  if (i >= TN*TF) return;
  float u = 0.05f*(xt[i] - pred[i]);
  u = fminf(10.0f, fmaxf(-10.0f, u));
  out[i] = x[i] + u;
}

extern "C" void kernel_launch(void* const* d_in, const int* in_sizes, int n_in,
                              void* d_out, int out_size, void* d_ws, size_t ws_size,
                              hipStream_t stream){
  (void)in_sizes; (void)n_in; (void)out_size;
  const float* x_stream = (const float*)d_in[0];
  const float* gains    = (const float*)d_in[1];
  const float* Wg       = (const float*)d_in[2];
  const float* Wr       = (const float*)d_in[3];
  const float* W1       = (const float*)d_in[4];
  const float* W2       = (const float*)d_in[5];
  const float* cosp     = (const float*)d_in[6];
  const float* sinp     = (const float*)d_in[7];

  size_t off = 0;
  char* base = (char*)d_ws;
  auto alloc = [&](size_t bytes) -> void* {
    void* p = base + off;
    off += (bytes + 255) & ~(size_t)255;
    return p;
  };
  float* X0      = (float*)alloc((size_t)TN*TF*4);   // x ping
  float* X1      = (float*)alloc((size_t)TN*TF*4);   // x pong
  float* x_targ  = (float*)alloc((size_t)TN*TF*4);
  short* xf_bf   = (short*)alloc((size_t)TN*TF*2);
  float* gateb   = (float*)alloc((size_t)TN*TE*4);
  float* scoresT = (float*)alloc((size_t)TE*TN*4);
  int*   topi    = (int*)  alloc((size_t)TE*TCAP*4);
  float* topv    = (float*)alloc((size_t)TE*TCAP*4);
  short* h_bf    = (short*)alloc((size_t)TE*TCAP*TF*2);
  float* P0      = (float*)alloc((size_t)TN*TF*4);   // pred ping
  float* P1      = (float*)alloc((size_t)TN*TF*4);   // pred pong
  short* W1t     = (short*)alloc((size_t)TE*TF*TF*2);
  short* W2t     = (short*)alloc((size_t)TE*TF*TF*2);
  bool useT = (off <= ws_size);

  k_init<<<(TN*TD + 255)/256, 256, 0, stream>>>(x_stream, cosp, sinp, X0, x_targ);
  k_gatebias<<<TN, 64, 0, stream>>>(X0, Wg, gateb);
  if (useT){
    k_castw<<<dim3(64, TE), 256, 0, stream>>>(W1, W1t);
    k_castw<<<dim3(64, TE), 256, 0, stream>>>(W2, W2t);
  }

  for (int it = 0; it < NITER; it++){
    const float* xO = (it & 1) ? X1 : X0;
    float*       xN = (it & 1) ? X0 : X1;
    float*       pW = (it & 1) ? P1 : P0;
    const float* pR = (it & 1) ? P0 : P1;
    k_fuse<<<TN/8, 256, 0, stream>>>(xO, xN, x_targ, pR, pW, gains, Wr, gateb,
                                     xf_bf, scoresT, it > 0 ? 1 : 0);
    k_topk2<<<TE, 1024, 0, stream>>>(scoresT, topi, topv);
    if (useT){
      k_gemm1c<<<TF/64*TE, 256, 0, stream>>>(xf_bf, W1t, topi, h_bf);
      k_gemm2c<<<TF/64*TE, 256, 0, stream>>>(h_bf, W2t, topi, topv, pW);
    } else {
      k_gemm1<<<dim3(TF/64, TE), 256, 0, stream>>>(xf_bf, W1, topi, h_bf);
      k_gemm2<<<dim3(TF/64, TE), 256, 0, stream>>>(h_bf, W2, topi, topv, pW);
    }
  }
  // after it=7: x_cur(7) is in X0 (xN of it=7), pred(7) is in P1 (pW of it=7)
  k_final<<<(TN*TF + 255)/256, 256, 0, stream>>>((float*)d_out, X0, x_targ, P1);
}

// Round 8
// 714.072 us; speedup vs baseline: 2.1802x; 1.0254x over previous
//
#include <hip/hip_runtime.h>
#include <hip/hip_bf16.h>

#define TB 2
#define TT 2048
#define TD 256
#define TE 64
#define TF 512
#define TN 4096      // TB*TT
#define TCAP 128     // 2*TN/TE
#define NITER 8

typedef __attribute__((ext_vector_type(8))) short bf16x8;
typedef __attribute__((ext_vector_type(4))) float f32x4;

__device__ inline float sanitize(float v){
  if (v != v) return 0.0f;
  const float FMAX = 3.402823466e+38f;
  if (v >  FMAX) return  FMAX;
  if (v < -FMAX) return -FMAX;
  return v;
}

__device__ inline short f2bf(float f){
  union { __hip_bfloat16 h; short s; } u;
  u.h = __float2bfloat16(f);
  return u.s;
}

__device__ inline float gelu_tanh(float x){
  float x3 = x*x*x;
  return 0.5f*x*(1.0f + tanhf(0.7978845608028654f*(x + 0.044715f*x3)));
}

// async global->LDS, 16B per lane; dest = wave-uniform base + lane*16
__device__ __forceinline__ void gload16(const void* g, void* l){
  __builtin_amdgcn_global_load_lds(
      (__attribute__((address_space(1))) void*)g,
      (__attribute__((address_space(3))) void*)l, 16, 0, 0);
}

// ---------------- setup kernels ----------------

__global__ void k_init(const float* __restrict__ xs, const float* __restrict__ cosp,
                       const float* __restrict__ sinp, float* __restrict__ xw,
                       float* __restrict__ xt){
  int idx = blockIdx.x*256 + threadIdx.x;          // over TN*TD
  if (idx >= TN*TD) return;
  int d = idx & (TD-1);
  int n = idx >> 8;
  int t = n & (TT-1);
  float xr = sanitize(xs[2*idx]), xi = sanitize(xs[2*idx+1]);
  xw[2*idx] = xr; xw[2*idx+1] = xi;
  float tr, ti;
  if (t == 0){ tr = xr; ti = xi; }
  else {
    float pr = sanitize(xs[2*(idx-TD)]), pi = sanitize(xs[2*(idx-TD)+1]);
    float c = cosp[d], s = sinp[d];
    tr = pr*c - pi*s;
    ti = pr*s + pi*c;
  }
  xt[2*idx] = tr; xt[2*idx+1] = ti;
}

__global__ __launch_bounds__(64) void k_gatebias(const float* __restrict__ xw,
                                                 const float* __restrict__ wg,
                                                 float* __restrict__ gb){
  __shared__ float mag[TD];
  int n = blockIdx.x, t = threadIdx.x;
  for (int d = t; d < TD; d += 64){
    float xr = xw[(size_t)n*TF + 2*d], xi = xw[(size_t)n*TF + 2*d + 1];
    mag[d] = sqrtf(xr*xr + xi*xi + 1e-8f);
  }
  __syncthreads();
  float acc = 0.f;
  for (int d = 0; d < TD; d++) acc += mag[d]*wg[d*TE + t];
  gb[(size_t)n*TE + t] = acc;
}

// cast+transpose weights: in f32 [e][k][n] -> out bf16 [e][n][k]
__global__ __launch_bounds__(256) void k_castw(const float* __restrict__ W, short* __restrict__ Wt){
  __shared__ float tile[64][68];
  int e = blockIdx.y;
  int kt = (blockIdx.x >> 3) * 64;
  int nt = (blockIdx.x & 7) * 64;
  int tid = threadIdx.x;
  {
    int row = tid >> 4;
    int c4 = (tid & 15) * 4;
    #pragma unroll
    for (int i = 0; i < 4; i++){
      int r = row + i*16;
      float4 v = *(const float4*)(W + ((size_t)e*TF + kt + r)*TF + nt + c4);
      *(float4*)&tile[r][c4] = v;
    }
  }
  __syncthreads();
  #pragma unroll
  for (int i = 0; i < 2; i++){
    int un = tid + i*256;
    int nrow = un >> 3;
    int k8 = (un & 7) * 8;
    bf16x8 o;
    #pragma unroll
    for (int j = 0; j < 8; j++) o[j] = f2bf(tile[k8+j][nrow]);
    *(bf16x8*)(Wt + ((size_t)e*TF + nt + nrow)*TF + kt + k8) = o;
  }
}

// ---------------- fused update + delay + router (gather-based pred) ----------------

// sum the ye rows selected for token nrow, 16 floats starting at kq
__device__ __forceinline__ void gather16(const float* __restrict__ ye,
                                         const int* __restrict__ cnt,
                                         const int* __restrict__ list,
                                         int nrow, int kq, float* p){
  #pragma unroll
  for (int q = 0; q < 16; q++) p[q] = 0.f;
  int c = cnt[nrow];
  for (int j = 0; j < c; j++){
    int row = list[nrow*64 + j];
    const float4* s = (const float4*)(ye + (size_t)row*TF + kq);
    #pragma unroll
    for (int k4 = 0; k4 < 4; k4++){
      float4 v = s[k4];
      p[4*k4+0] += v.x; p[4*k4+1] += v.y; p[4*k4+2] += v.z; p[4*k4+3] += v.w;
    }
  }
}

__device__ __forceinline__ void load_row16(const float* __restrict__ xw,
                                           const float* __restrict__ xt,
                                           const float* __restrict__ ye,
                                           const int* __restrict__ cnt,
                                           const int* __restrict__ list,
                                           int nrow, int kq, int upd, float* o){
  size_t off = (size_t)nrow*TF + kq;
  const float4* a4 = (const float4*)(xw + off);
  if (upd){
    float p[16];
    gather16(ye, cnt, list, nrow, kq, p);
    const float4* t4 = (const float4*)(xt + off);
    #pragma unroll
    for (int j = 0; j < 4; j++){
      float4 a = a4[j], t = t4[j];
      float u;
      u = 0.05f*(t.x - p[4*j+0]); u = fminf(10.f, fmaxf(-10.f, u)); o[4*j+0] = a.x + u;
      u = 0.05f*(t.y - p[4*j+1]); u = fminf(10.f, fmaxf(-10.f, u)); o[4*j+1] = a.y + u;
      u = 0.05f*(t.z - p[4*j+2]); u = fminf(10.f, fmaxf(-10.f, u)); o[4*j+2] = a.z + u;
      u = 0.05f*(t.w - p[4*j+3]); u = fminf(10.f, fmaxf(-10.f, u)); o[4*j+3] = a.w + u;
    }
  } else {
    #pragma unroll
    for (int j = 0; j < 4; j++){
      float4 a = a4[j];
      o[4*j+0] = a.x; o[4*j+1] = a.y; o[4*j+2] = a.z; o[4*j+3] = a.w;
    }
  }
}

// 8 tokens per block, 256 threads.
__global__ __launch_bounds__(256) void k_fuse(
    const float* __restrict__ xOld, float* __restrict__ xNew,
    const float* __restrict__ xt, const float* __restrict__ ye,
    const int* __restrict__ cnt, const int* __restrict__ list,
    const float* __restrict__ g, const float* __restrict__ wr,
    const float* __restrict__ gb, short* __restrict__ xbf,
    float* __restrict__ scoresT, int upd)
{
  __shared__ float xeff[8][516];
  __shared__ float Bt[64][68];
  int tid = threadIdx.x;
  int tok = tid >> 5;            // 0..7
  int kq  = (tid & 31) * 16;     // 16 consecutive floats
  int n   = blockIdx.x*8 + tok;
  int t   = n & (TT-1);
  size_t rowoff = (size_t)n*TF + kq;

  float cur[16], eff[16];
  load_row16(xOld, xt, ye, cnt, list, n, kq, upd, cur);
  #pragma unroll
  for (int q = 0; q < 16; q++) eff[q] = cur[q];
  const int taus[4] = {1,2,3,5};
  int d0 = kq >> 1;
  #pragma unroll
  for (int i = 0; i < 4; i++){
    int tau = taus[i];
    if (t >= tau){
      float nb[16];
      load_row16(xOld, xt, ye, cnt, list, n - tau, kq, upd, nb);
      #pragma unroll
      for (int p = 0; p < 8; p++){
        float gr = g[2*(i*TD + d0 + p)];
        float gi = g[2*(i*TD + d0 + p) + 1];
        eff[2*p]   += nb[2*p]*gr - nb[2*p+1]*gi;
        eff[2*p+1] += nb[2*p]*gi + nb[2*p+1]*gr;
      }
    }
  }
  {
    float4* xn = (float4*)(xNew + rowoff);
    #pragma unroll
    for (int j = 0; j < 4; j++)
      xn[j] = make_float4(cur[4*j], cur[4*j+1], cur[4*j+2], cur[4*j+3]);
    bf16x8 o0, o1;
    #pragma unroll
    for (int q = 0; q < 8; q++){ o0[q] = f2bf(eff[q]); o1[q] = f2bf(eff[8+q]); }
    *(bf16x8*)(xbf + rowoff)     = o0;
    *(bf16x8*)(xbf + rowoff + 8) = o1;
    #pragma unroll
    for (int j = 0; j < 4; j++)
      *(float4*)&xeff[tok][kq + 4*j] = make_float4(eff[4*j], eff[4*j+1], eff[4*j+2], eff[4*j+3]);
  }
  __syncthreads();

  // router: thread (tok, tx) computes experts {2tx, 2tx+1} for token n
  int tx = tid & 31;
  float acc0 = gb[(size_t)n*TE + 2*tx];
  float acc1 = gb[(size_t)n*TE + 2*tx + 1];
  int rB = tid >> 2, c16 = (tid & 3)*16;
  for (int kk = 0; kk < TF; kk += 64){
    #pragma unroll
    for (int jj = 0; jj < 4; jj++)
      *(float4*)&Bt[rB][c16 + 4*jj] = *(const float4*)(wr + (size_t)(kk+rB)*TE + c16 + 4*jj);
    __syncthreads();
    #pragma unroll
    for (int k = 0; k < 64; k++){
      float a = xeff[tok][kk + k];
      float2 b = *(const float2*)&Bt[k][2*tx];
      acc0 += a*b.x; acc1 += a*b.y;
    }
    __syncthreads();
  }
  float m = fmaxf(acc0, acc1);
  #pragma unroll
  for (int off = 1; off < 32; off <<= 1) m = fmaxf(m, __shfl_xor(m, off));
  float e0 = expf(acc0 - m), e1 = expf(acc1 - m);
  float s = e0 + e1;
  #pragma unroll
  for (int off = 1; off < 32; off <<= 1) s += __shfl_xor(s, off);
  float inv = 1.0f / s;
  scoresT[(size_t)(2*tx)*TN + n]     = e0*inv;
  scoresT[(size_t)(2*tx+1)*TN + n]   = e1*inv;
}

// per-expert exact top-128: registers + 3-round radix, parallel threshold find.
// Also zeroes cnt[e*64 .. e*64+63] (full cnt[TN/64*64] across the 64 blocks) for
// the inverse-index build that piggybacks on k_gemm1c.
__global__ __launch_bounds__(1024) void k_topk2(const float* __restrict__ scoresT,
                                                int* __restrict__ topi, float* __restrict__ topv,
                                                int* __restrict__ cnt){
  int e = blockIdx.x;
  const float* sc = scoresT + (size_t)e*TN;
  __shared__ unsigned int hist[4096];
  __shared__ unsigned int chunkSum[64];
  __shared__ unsigned int s_prefix;
  __shared__ int s_k, s_cnt, s_min;
  int tid = threadIdx.x;
  if (tid < 64) cnt[e*64 + tid] = 0;
  unsigned int u[4];
  #pragma unroll
  for (int i = 0; i < 4; i++) u[i] = __float_as_uint(sc[tid + i*1024]);
  if (tid == 0){ s_prefix = 0u; s_k = TCAP; }

  const int shifts[3]  = {20, 8, 0};
  const int nbins[3]   = {4096, 4096, 256};
  const unsigned int pmasks[3] = {0u, 0xFFF00000u, 0xFFFFFF00u};
  for (int r = 0; r < 3; r++){
    int shift = shifts[r], nb = nbins[r];
    unsigned int bmask = (unsigned)nb - 1u;
    int logC = (nb == 4096) ? 6 : 2;     // bins per chunk: nb/64
    for (int i = tid; i < nb; i += 1024) hist[i] = 0u;
    if (tid < 64) chunkSum[tid] = 0u;
    __syncthreads();
    unsigned int pref = s_prefix;
    unsigned int pmask = pmasks[r];
    #pragma unroll
    for (int i = 0; i < 4; i++)
      if ((u[i] & pmask) == pref) atomicAdd(&hist[(u[i] >> shift) & bmask], 1u);
    __syncthreads();
    for (int b = tid; b < nb; b += 1024){
      unsigned int h = hist[b];
      if (h) atomicAdd(&chunkSum[b >> logC], h);
    }
    __syncthreads();
    if (tid < 64){
      int chunk = 63 - tid;                     // lane order = descending chunk
      unsigned int s = chunkSum[chunk];
      unsigned int scan = s;
      #pragma unroll
      for (int d = 1; d < 64; d <<= 1){
        unsigned int t = __shfl_up(scan, d);
        if (tid >= d) scan += t;
      }
      unsigned int excl = scan - s;
      int k = s_k;
      if (excl < (unsigned)k && scan >= (unsigned)k){
        int C = 1 << logC;
        unsigned int cum = excl;
        for (int b = C-1; b >= 0; b--){
          unsigned int h = hist[(chunk << logC) + b];
          cum += h;
          if (cum >= (unsigned)k){
            s_k = k - (int)(cum - h);
            s_prefix = pref | ((unsigned)((chunk << logC) + b) << shift);
            break;
          }
        }
      }
    }
    __syncthreads();
  }
  unsigned int thr = s_prefix;
  int need_eq = s_k;
  if (tid == 0) s_cnt = 0;
  __syncthreads();
  #pragma unroll
  for (int i = 0; i < 4; i++){
    if (u[i] > thr){
      int p = atomicAdd(&s_cnt, 1);
      topi[e*TCAP + p] = tid + i*1024;
      topv[e*TCAP + p] = __uint_as_float(u[i]);
    }
  }
  __syncthreads();
  int base = s_cnt;
  int last = -1;
  for (int i = 0; i < need_eq; i++){
    __syncthreads();
    if (tid == 0) s_min = TN;
    __syncthreads();
    #pragma unroll
    for (int j = 0; j < 4; j++){
      int n = tid + j*1024;
      if (u[j] == thr && n > last) atomicMin(&s_min, n);
    }
    __syncthreads();
    int nsel = s_min;
    if (tid == 0){ topi[e*TCAP + base + i] = nsel; topv[e*TCAP + base + i] = __uint_as_float(thr); }
    last = nsel;
  }
}

// ---- GEMMs: bf16 Wt [e][n][k], gload_lds + XOR-swizzle + 3-deep counted-vmcnt pipeline ----

__global__ __launch_bounds__(256) void k_gemm1c(const short* __restrict__ xbf,
                                                const short* __restrict__ W1t,
                                                const int* __restrict__ topi,
                                                short* __restrict__ hbf,
                                                int* __restrict__ cnt,
                                                int* __restrict__ list){
  __shared__ __align__(16) short As[3][128*32];
  __shared__ __align__(16) short Bs[3][64*32];
  __shared__ int rows[128];
  int bid = blockIdx.x;
  int swz = (bid & 7)*64 + (bid >> 3);     // XCD-contiguous: one XCD = 8 consecutive experts
  int e = swz >> 3, n0 = (swz & 7)*64;
  int tid = threadIdx.x;
  if (tid < 128) rows[tid] = topi[e*TCAP + tid];
  __syncthreads();
  // piggyback: n0==0 blocks build the token -> ye-row inverse index (cnt zeroed by k_topk2)
  if (n0 == 0 && tid < 128){
    int n = rows[tid];
    int slot = atomicAdd(&cnt[n], 1);
    list[n*64 + slot] = e*TCAP + tid;
  }
  int r4 = tid >> 2;
  int cs = (((tid & 3) ^ ((r4 >> 1) & 3)))*8;     // swizzled source k-chunk (shorts)
  const short* sA0 = xbf + (size_t)rows[r4]*TF + cs;
  const short* sA1 = xbf + (size_t)rows[r4 + 64]*TF + cs;
  const short* sB  = W1t + ((size_t)e*TF + n0 + r4)*TF + cs;

  int w = tid >> 6, l = tid & 63;
  int lr = l & 15, lh = l >> 4;
  int ch = (lh ^ ((lr >> 1) & 3))*8;              // swizzled read chunk (shorts)
  int aOff0 = (32*w + lr)*32 + ch;
  int aOff1 = aOff0 + 16*32;
  int bOff0 = lr*32 + ch;

  f32x4 acc[2][4];
  #pragma unroll
  for (int m = 0; m < 2; m++)
    #pragma unroll
    for (int j = 0; j < 4; j++)
      #pragma unroll
      for (int r = 0; r < 4; r++) acc[m][j][r] = 0.f;

  // prologue: stage steps 0 and 1
  gload16(sA0, &As[0][tid*8]);
  gload16(sA1, &As[0][2048 + tid*8]);
  gload16(sB,  &Bs[0][tid*8]);
  gload16(sA0 + 32, &As[1][tid*8]);
  gload16(sA1 + 32, &As[1][2048 + tid*8]);
  gload16(sB  + 32, &Bs[1][tid*8]);

  int cur = 0;
  for (int t16 = 0; t16 < 16; t16++){
    if (t16 < 14){
      int kk = (t16+2)*32;
      int ld = cur + 2; if (ld >= 3) ld -= 3;
      gload16(sA0 + kk, &As[ld][tid*8]);
      gload16(sA1 + kk, &As[ld][2048 + tid*8]);
      gload16(sB  + kk, &Bs[ld][tid*8]);
      asm volatile("s_waitcnt vmcnt(6)" ::: "memory");
    } else if (t16 == 14){
      asm volatile("s_waitcnt vmcnt(3)" ::: "memory");
    } else {
      asm volatile("s_waitcnt vmcnt(0)" ::: "memory");
    }
    __builtin_amdgcn_sched_barrier(0);
    __builtin_amdgcn_s_barrier();          // current buffer loaded by ALL waves
    __builtin_amdgcn_sched_barrier(0);
    bf16x8 a0 = *(const bf16x8*)&As[cur][aOff0];
    bf16x8 a1 = *(const bf16x8*)&As[cur][aOff1];
    #pragma unroll
    for (int j = 0; j < 4; j++){
      bf16x8 b = *(const bf16x8*)&Bs[cur][bOff0 + j*16*32];
      acc[0][j] = __builtin_amdgcn_mfma_f32_16x16x32_bf16(a0, b, acc[0][j], 0, 0, 0);
      acc[1][j] = __builtin_amdgcn_mfma_f32_16x16x32_bf16(a1, b, acc[1][j], 0, 0, 0);
    }
    __builtin_amdgcn_sched_barrier(0);
    __builtin_amdgcn_s_barrier();          // all waves done reading -> safe to overwrite
    cur++; if (cur >= 3) cur = 0;
  }
  short* hdst = hbf + (size_t)e*TCAP*TF;
  #pragma unroll
  for (int m = 0; m < 2; m++)
    #pragma unroll
    for (int j = 0; j < 4; j++)
      #pragma unroll
      for (int r = 0; r < 4; r++){
        int row = 32*w + 16*m + lh*4 + r;
        int col = n0 + 16*j + lr;
        hdst[(size_t)row*TF + col] = f2bf(gelu_tanh(acc[m][j][r]));
      }
}

__global__ __launch_bounds__(256) void k_gemm2c(const short* __restrict__ hbf,
                                                const short* __restrict__ W2t,
                                                const int* __restrict__ topi,
                                                const float* __restrict__ topv,
                                                float* __restrict__ ye){
  __shared__ __align__(16) short As[3][128*32];
  __shared__ __align__(16) short Bs[3][64*32];
  __shared__ float tv[128];
  int bid = blockIdx.x;
  int swz = (bid & 7)*64 + (bid >> 3);
  int e = swz >> 3, n0 = (swz & 7)*64;
  int tid = threadIdx.x;
  if (tid < 128) tv[tid] = topv[e*TCAP + tid];
  __syncthreads();
  int r4 = tid >> 2;
  int cs = (((tid & 3) ^ ((r4 >> 1) & 3)))*8;
  const short* sA0 = hbf + ((size_t)e*TCAP + r4)*TF + cs;
  const short* sA1 = sA0 + (size_t)64*TF;
  const short* sB  = W2t + ((size_t)e*TF + n0 + r4)*TF + cs;

  int w = tid >> 6, l = tid & 63;
  int lr = l & 15, lh = l >> 4;
  int ch = (lh ^ ((lr >> 1) & 3))*8;
  int aOff0 = (32*w + lr)*32 + ch;
  int aOff1 = aOff0 + 16*32;
  int bOff0 = lr*32 + ch;

  f32x4 acc[2][4];
  #pragma unroll
  for (int m = 0; m < 2; m++)
    #pragma unroll
    for (int j = 0; j < 4; j++)
      #pragma unroll
      for (int r = 0; r < 4; r++) acc[m][j][r] = 0.f;

  gload16(sA0, &As[0][tid*8]);
  gload16(sA1, &As[0][2048 + tid*8]);
  gload16(sB,  &Bs[0][tid*8]);
  gload16(sA0 + 32, &As[1][tid*8]);
  gload16(sA1 + 32, &As[1][2048 + tid*8]);
  gload16(sB  + 32, &Bs[1][tid*8]);

  int cur = 0;
  for (int t16 = 0; t16 < 16; t16++){
    if (t16 < 14){
      int kk = (t16+2)*32;
      int ld = cur + 2; if (ld >= 3) ld -= 3;
      gload16(sA0 + kk, &As[ld][tid*8]);
      gload16(sA1 + kk, &As[ld][2048 + tid*8]);
      gload16(sB  + kk, &Bs[ld][tid*8]);
      asm volatile("s_waitcnt vmcnt(6)" ::: "memory");
    } else if (t16 == 14){
      asm volatile("s_waitcnt vmcnt(3)" ::: "memory");
    } else {
      asm volatile("s_waitcnt vmcnt(0)" ::: "memory");
    }
    __builtin_amdgcn_sched_barrier(0);
    __builtin_amdgcn_s_barrier();
    __builtin_amdgcn_sched_barrier(0);
    bf16x8 a0 = *(const bf16x8*)&As[cur][aOff0];
    bf16x8 a1 = *(const bf16x8*)&As[cur][aOff1];
    #pragma unroll
    for (int j = 0; j < 4; j++){
      bf16x8 b = *(const bf16x8*)&Bs[cur][bOff0 + j*16*32];
      acc[0][j] = __builtin_amdgcn_mfma_f32_16x16x32_bf16(a0, b, acc[0][j], 0, 0, 0);
      acc[1][j] = __builtin_amdgcn_mfma_f32_16x16x32_bf16(a1, b, acc[1][j], 0, 0, 0);
    }
    __builtin_amdgcn_sched_barrier(0);
    __builtin_amdgcn_s_barrier();
    cur++; if (cur >= 3) cur = 0;
  }
  // dense ye write (scaled by gate value) — no atomics
  float* ydst = ye + (size_t)e*TCAP*TF;
  #pragma unroll
  for (int m = 0; m < 2; m++)
    #pragma unroll
    for (int j = 0; j < 4; j++)
      #pragma unroll
      for (int r = 0; r < 4; r++){
        int row = 32*w + 16*m + lh*4 + r;
        int col = n0 + 16*j + lr;
        ydst[(size_t)row*TF + col] = acc[m][j][r] * tv[row];
      }
}

// out = x + clip(0.05*(xt - gather(ye)))
__global__ void k_final(float* __restrict__ out, const float* __restrict__ x,
                        const float* __restrict__ xt, const float* __restrict__ ye,
                        const int* __restrict__ cnt, const int* __restrict__ list){
  int i = blockIdx.x*256 + threadIdx.x;
  if (i >= TN*TF) return;
  int n = i >> 9;           // TF = 512
  int f = i & (TF-1);
  float p = 0.f;
  int c = cnt[n];
  for (int j = 0; j < c; j++)
    p += ye[(size_t)list[n*64 + j]*TF + f];
  float u = 0.05f*(xt[i] - p);
  u = fminf(10.0f, fmaxf(-10.0f, u));
  out[i] = x[i] + u;
}

extern "C" void kernel_launch(void* const* d_in, const int* in_sizes, int n_in,
                              void* d_out, int out_size, void* d_ws, size_t ws_size,
                              hipStream_t stream){
  (void)in_sizes; (void)n_in; (void)out_size; (void)ws_size;
  const float* x_stream = (const float*)d_in[0];
  const float* gains    = (const float*)d_in[1];
  const float* Wg       = (const float*)d_in[2];
  const float* Wr       = (const float*)d_in[3];
  const float* W1       = (const float*)d_in[4];
  const float* W2       = (const float*)d_in[5];
  const float* cosp     = (const float*)d_in[6];
  const float* sinp     = (const float*)d_in[7];

  size_t off = 0;
  char* base = (char*)d_ws;
  auto alloc = [&](size_t bytes) -> void* {
    void* p = base + off;
    off += (bytes + 255) & ~(size_t)255;
    return p;
  };
  float* X0      = (float*)alloc((size_t)TN*TF*4);   // x ping
  float* X1      = (float*)alloc((size_t)TN*TF*4);   // x pong
  float* x_targ  = (float*)alloc((size_t)TN*TF*4);
  short* xf_bf   = (short*)alloc((size_t)TN*TF*2);
  float* gateb   = (float*)alloc((size_t)TN*TE*4);
  float* scoresT = (float*)alloc((size_t)TE*TN*4);
  int*   topi    = (int*)  alloc((size_t)TE*TCAP*4);
  float* topv    = (float*)alloc((size_t)TE*TCAP*4);
  short* h_bf    = (short*)alloc((size_t)TE*TCAP*TF*2);
  float* ye      = (float*)alloc((size_t)TE*TCAP*TF*4);   // dense expert outputs (scaled)
  int*   cnt     = (int*)  alloc((size_t)TN*4);
  int*   list    = (int*)  alloc((size_t)TN*64*4);
  short* W1t     = (short*)alloc((size_t)TE*TF*TF*2);
  short* W2t     = (short*)alloc((size_t)TE*TF*TF*2);

  k_init<<<(TN*TD + 255)/256, 256, 0, stream>>>(x_stream, cosp, sinp, X0, x_targ);
  k_gatebias<<<TN, 64, 0, stream>>>(X0, Wg, gateb);
  k_castw<<<dim3(64, TE), 256, 0, stream>>>(W1, W1t);
  k_castw<<<dim3(64, TE), 256, 0, stream>>>(W2, W2t);

  for (int it = 0; it < NITER; it++){
    const float* xO = (it & 1) ? X1 : X0;
    float*       xN = (it & 1) ? X0 : X1;
    k_fuse<<<TN/8, 256, 0, stream>>>(xO, xN, x_targ, ye, cnt, list, gains, Wr, gateb,
                                     xf_bf, scoresT, it > 0 ? 1 : 0);
    k_topk2<<<TE, 1024, 0, stream>>>(scoresT, topi, topv, cnt);
    k_gemm1c<<<TF/64*TE, 256, 0, stream>>>(xf_bf, W1t, topi, h_bf, cnt, list);
    k_gemm2c<<<TF/64*TE, 256, 0, stream>>>(h_bf, W2t, topi, topv, ye);
  }
  // after it=7: x_cur(7) is in X0 (xN of it=7); ye/cnt/list hold iter-7 predictions
  k_final<<<(TN*TF + 255)/256, 256, 0, stream>>>((float*)d_out, X0, x_targ, ye, cnt, list);
}

// Round 9
// 662.358 us; speedup vs baseline: 2.3504x; 1.0781x over previous
//
#include <hip/hip_runtime.h>
#include <hip/hip_bf16.h>

#define TB 2
#define TT 2048
#define TD 256
#define TE 64
#define TF 512
#define TN 4096      // TB*TT
#define TCAP 128     // 2*TN/TE
#define NITER 8

typedef __attribute__((ext_vector_type(8))) short bf16x8;
typedef __attribute__((ext_vector_type(4))) float f32x4;

__device__ inline float sanitize(float v){
  if (v != v) return 0.0f;
  const float FMAX = 3.402823466e+38f;
  if (v >  FMAX) return  FMAX;
  if (v < -FMAX) return -FMAX;
  return v;
}

__device__ inline short f2bf(float f){
  union { __hip_bfloat16 h; short s; } u;
  u.h = __float2bfloat16(f);
  return u.s;
}

__device__ inline float gelu_tanh(float x){
  float x3 = x*x*x;
  return 0.5f*x*(1.0f + tanhf(0.7978845608028654f*(x + 0.044715f*x3)));
}

// async global->LDS, 16B per lane; dest = wave-uniform base + lane*16
__device__ __forceinline__ void gload16(const void* g, void* l){
  __builtin_amdgcn_global_load_lds(
      (__attribute__((address_space(1))) void*)g,
      (__attribute__((address_space(3))) void*)l, 16, 0, 0);
}

// ---------------- setup kernels ----------------

__global__ void k_init(const float* __restrict__ xs, const float* __restrict__ cosp,
                       const float* __restrict__ sinp, float* __restrict__ xw,
                       float* __restrict__ xt){
  int idx = blockIdx.x*256 + threadIdx.x;          // over TN*TD
  if (idx >= TN*TD) return;
  int d = idx & (TD-1);
  int n = idx >> 8;
  int t = n & (TT-1);
  float xr = sanitize(xs[2*idx]), xi = sanitize(xs[2*idx+1]);
  xw[2*idx] = xr; xw[2*idx+1] = xi;
  float tr, ti;
  if (t == 0){ tr = xr; ti = xi; }
  else {
    float pr = sanitize(xs[2*(idx-TD)]), pi = sanitize(xs[2*(idx-TD)+1]);
    float c = cosp[d], s = sinp[d];
    tr = pr*c - pi*s;
    ti = pr*s + pi*c;
  }
  xt[2*idx] = tr; xt[2*idx+1] = ti;
}

__global__ __launch_bounds__(64) void k_gatebias(const float* __restrict__ xw,
                                                 const float* __restrict__ wg,
                                                 float* __restrict__ gb){
  __shared__ float mag[TD];
  int n = blockIdx.x, t = threadIdx.x;
  for (int d = t; d < TD; d += 64){
    float xr = xw[(size_t)n*TF + 2*d], xi = xw[(size_t)n*TF + 2*d + 1];
    mag[d] = sqrtf(xr*xr + xi*xi + 1e-8f);
  }
  __syncthreads();
  float acc = 0.f;
  for (int d = 0; d < TD; d++) acc += mag[d]*wg[d*TE + t];
  gb[(size_t)n*TE + t] = acc;
}

// cast+transpose weights: in f32 [e][k][n] -> out bf16 [e][n][k]
__global__ __launch_bounds__(256) void k_castw(const float* __restrict__ W, short* __restrict__ Wt){
  __shared__ float tile[64][68];
  int e = blockIdx.y;
  int kt = (blockIdx.x >> 3) * 64;
  int nt = (blockIdx.x & 7) * 64;
  int tid = threadIdx.x;
  {
    int row = tid >> 4;
    int c4 = (tid & 15) * 4;
    #pragma unroll
    for (int i = 0; i < 4; i++){
      int r = row + i*16;
      float4 v = *(const float4*)(W + ((size_t)e*TF + kt + r)*TF + nt + c4);
      *(float4*)&tile[r][c4] = v;
    }
  }
  __syncthreads();
  #pragma unroll
  for (int i = 0; i < 2; i++){
    int un = tid + i*256;
    int nrow = un >> 3;
    int k8 = (un & 7) * 8;
    bf16x8 o;
    #pragma unroll
    for (int j = 0; j < 8; j++) o[j] = f2bf(tile[k8+j][nrow]);
    *(bf16x8*)(Wt + ((size_t)e*TF + nt + nrow)*TF + kt + k8) = o;
  }
}

// ---------------- combine: xNew = xOld + clip(lr*(xt - gather(ye))) ----------------
// 8 rows per block, 32 lanes per row, coalesced 2KB ye-row reads, each row combined ONCE.

__global__ __launch_bounds__(256) void k_combine(
    const float* __restrict__ xOld, float* __restrict__ xNew,
    const float* __restrict__ xt, const float* __restrict__ ye,
    const int* __restrict__ cnt, const int* __restrict__ list)
{
  int tid = threadIdx.x;
  int tok = tid >> 5;
  int kq  = (tid & 31) * 16;
  int n   = blockIdx.x*8 + tok;
  size_t off = (size_t)n*TF + kq;
  float p[16];
  #pragma unroll
  for (int q = 0; q < 16; q++) p[q] = 0.f;
  int c = cnt[n];
  for (int j = 0; j < c; j++){
    const float4* s = (const float4*)(ye + (size_t)list[n*64 + j]*TF + kq);
    #pragma unroll
    for (int k4 = 0; k4 < 4; k4++){
      float4 v = s[k4];
      p[4*k4+0] += v.x; p[4*k4+1] += v.y; p[4*k4+2] += v.z; p[4*k4+3] += v.w;
    }
  }
  const float4* a4 = (const float4*)(xOld + off);
  const float4* t4 = (const float4*)(xt + off);
  float4* o4 = (float4*)(xNew + off);
  #pragma unroll
  for (int j = 0; j < 4; j++){
    float4 a = a4[j], t = t4[j], o;
    float u;
    u = 0.05f*(t.x - p[4*j+0]); u = fminf(10.f, fmaxf(-10.f, u)); o.x = a.x + u;
    u = 0.05f*(t.y - p[4*j+1]); u = fminf(10.f, fmaxf(-10.f, u)); o.y = a.y + u;
    u = 0.05f*(t.z - p[4*j+2]); u = fminf(10.f, fmaxf(-10.f, u)); o.z = a.z + u;
    u = 0.05f*(t.w - p[4*j+3]); u = fminf(10.f, fmaxf(-10.f, u)); o.w = a.w + u;
    o4[j] = o;
  }
}

// ---------------- delay embed + router + bf16 cast (dense x_state input) ----------------
// 8 tokens per block, 256 threads.

__global__ __launch_bounds__(256) void k_fuse2(
    const float* __restrict__ xcur, const float* __restrict__ g,
    const float* __restrict__ wr, const float* __restrict__ gb,
    short* __restrict__ xbf, float* __restrict__ scoresT)
{
  __shared__ float xeff[8][516];
  __shared__ float Bt[64][68];
  int tid = threadIdx.x;
  int tok = tid >> 5;            // 0..7
  int lane5 = tid & 31;
  int kq  = lane5 * 16;          // 16 consecutive floats
  int n   = blockIdx.x*8 + tok;
  int t   = n & (TT-1);
  size_t rowoff = (size_t)n*TF + kq;

  float eff[16];
  {
    const float4* a4 = (const float4*)(xcur + rowoff);
    #pragma unroll
    for (int j = 0; j < 4; j++){
      float4 v = a4[j];
      eff[4*j+0] = v.x; eff[4*j+1] = v.y; eff[4*j+2] = v.z; eff[4*j+3] = v.w;
    }
  }
  const int taus[4] = {1,2,3,5};
  int d0 = kq >> 1;
  #pragma unroll
  for (int i = 0; i < 4; i++){
    int tau = taus[i];
    if (t >= tau){
      const float4* b4 = (const float4*)(xcur + rowoff - (size_t)tau*TF);
      float nb[16];
      #pragma unroll
      for (int j = 0; j < 4; j++){
        float4 v = b4[j];
        nb[4*j+0] = v.x; nb[4*j+1] = v.y; nb[4*j+2] = v.z; nb[4*j+3] = v.w;
      }
      #pragma unroll
      for (int p = 0; p < 8; p++){
        float gr = g[2*(i*TD + d0 + p)];
        float gi = g[2*(i*TD + d0 + p) + 1];
        eff[2*p]   += nb[2*p]*gr - nb[2*p+1]*gi;
        eff[2*p+1] += nb[2*p]*gi + nb[2*p+1]*gr;
      }
    }
  }
  {
    bf16x8 o0, o1;
    #pragma unroll
    for (int q = 0; q < 8; q++){ o0[q] = f2bf(eff[q]); o1[q] = f2bf(eff[8+q]); }
    *(bf16x8*)(xbf + rowoff)     = o0;
    *(bf16x8*)(xbf + rowoff + 8) = o1;
    // lane-staggered write order: cuts 16-way bank conflict to ~4-way
    #pragma unroll
    for (int jj = 0; jj < 4; jj++){
      int j = (jj + lane5) & 3;
      *(float4*)&xeff[tok][kq + 4*j] =
        make_float4(eff[4*j], eff[4*j+1], eff[4*j+2], eff[4*j+3]);
    }
  }
  __syncthreads();

  // router: thread (tok, tx) computes experts {2tx, 2tx+1} for token n
  int tx = lane5;
  float acc0 = gb[(size_t)n*TE + 2*tx];
  float acc1 = gb[(size_t)n*TE + 2*tx + 1];
  int rB = tid >> 2, c16 = (tid & 3)*16;
  for (int kk = 0; kk < TF; kk += 64){
    #pragma unroll
    for (int jj = 0; jj < 4; jj++)
      *(float4*)&Bt[rB][c16 + 4*jj] = *(const float4*)(wr + (size_t)(kk+rB)*TE + c16 + 4*jj);
    __syncthreads();
    #pragma unroll
    for (int k = 0; k < 64; k++){
      float a = xeff[tok][kk + k];
      float2 b = *(const float2*)&Bt[k][2*tx];
      acc0 += a*b.x; acc1 += a*b.y;
    }
    __syncthreads();
  }
  float m = fmaxf(acc0, acc1);
  #pragma unroll
  for (int off = 1; off < 32; off <<= 1) m = fmaxf(m, __shfl_xor(m, off));
  float e0 = expf(acc0 - m), e1 = expf(acc1 - m);
  float s = e0 + e1;
  #pragma unroll
  for (int off = 1; off < 32; off <<= 1) s += __shfl_xor(s, off);
  float inv = 1.0f / s;
  scoresT[(size_t)(2*tx)*TN + n]     = e0*inv;
  scoresT[(size_t)(2*tx+1)*TN + n]   = e1*inv;
}

// per-expert exact top-128: registers + 3-round radix, parallel threshold find.
// Also zeroes cnt for the inverse-index build that piggybacks on k_gemm1c.
__global__ __launch_bounds__(1024) void k_topk2(const float* __restrict__ scoresT,
                                                int* __restrict__ topi, float* __restrict__ topv,
                                                int* __restrict__ cnt){
  int e = blockIdx.x;
  const float* sc = scoresT + (size_t)e*TN;
  __shared__ unsigned int hist[4096];
  __shared__ unsigned int chunkSum[64];
  __shared__ unsigned int s_prefix;
  __shared__ int s_k, s_cnt, s_min;
  int tid = threadIdx.x;
  if (tid < 64) cnt[e*64 + tid] = 0;
  unsigned int u[4];
  #pragma unroll
  for (int i = 0; i < 4; i++) u[i] = __float_as_uint(sc[tid + i*1024]);
  if (tid == 0){ s_prefix = 0u; s_k = TCAP; }

  const int shifts[3]  = {20, 8, 0};
  const int nbins[3]   = {4096, 4096, 256};
  const unsigned int pmasks[3] = {0u, 0xFFF00000u, 0xFFFFFF00u};
  for (int r = 0; r < 3; r++){
    int shift = shifts[r], nb = nbins[r];
    unsigned int bmask = (unsigned)nb - 1u;
    int logC = (nb == 4096) ? 6 : 2;     // bins per chunk: nb/64
    for (int i = tid; i < nb; i += 1024) hist[i] = 0u;
    if (tid < 64) chunkSum[tid] = 0u;
    __syncthreads();
    unsigned int pref = s_prefix;
    unsigned int pmask = pmasks[r];
    #pragma unroll
    for (int i = 0; i < 4; i++)
      if ((u[i] & pmask) == pref) atomicAdd(&hist[(u[i] >> shift) & bmask], 1u);
    __syncthreads();
    for (int b = tid; b < nb; b += 1024){
      unsigned int h = hist[b];
      if (h) atomicAdd(&chunkSum[b >> logC], h);
    }
    __syncthreads();
    if (tid < 64){
      int chunk = 63 - tid;                     // lane order = descending chunk
      unsigned int s = chunkSum[chunk];
      unsigned int scan = s;
      #pragma unroll
      for (int d = 1; d < 64; d <<= 1){
        unsigned int t = __shfl_up(scan, d);
        if (tid >= d) scan += t;
      }
      unsigned int excl = scan - s;
      int k = s_k;
      if (excl < (unsigned)k && scan >= (unsigned)k){
        int C = 1 << logC;
        unsigned int cum = excl;
        for (int b = C-1; b >= 0; b--){
          unsigned int h = hist[(chunk << logC) + b];
          cum += h;
          if (cum >= (unsigned)k){
            s_k = k - (int)(cum - h);
            s_prefix = pref | ((unsigned)((chunk << logC) + b) << shift);
            break;
          }
        }
      }
    }
    __syncthreads();
  }
  unsigned int thr = s_prefix;
  int need_eq = s_k;
  if (tid == 0) s_cnt = 0;
  __syncthreads();
  #pragma unroll
  for (int i = 0; i < 4; i++){
    if (u[i] > thr){
      int p = atomicAdd(&s_cnt, 1);
      topi[e*TCAP + p] = tid + i*1024;
      topv[e*TCAP + p] = __uint_as_float(u[i]);
    }
  }
  __syncthreads();
  int base = s_cnt;
  int last = -1;
  for (int i = 0; i < need_eq; i++){
    __syncthreads();
    if (tid == 0) s_min = TN;
    __syncthreads();
    #pragma unroll
    for (int j = 0; j < 4; j++){
      int n = tid + j*1024;
      if (u[j] == thr && n > last) atomicMin(&s_min, n);
    }
    __syncthreads();
    int nsel = s_min;
    if (tid == 0){ topi[e*TCAP + base + i] = nsel; topv[e*TCAP + base + i] = __uint_as_float(thr); }
    last = nsel;
  }
}

// ---- GEMMs: bf16 Wt [e][n][k], gload_lds + XOR-swizzle + 3-deep counted-vmcnt pipeline ----

__global__ __launch_bounds__(256) void k_gemm1c(const short* __restrict__ xbf,
                                                const short* __restrict__ W1t,
                                                const int* __restrict__ topi,
                                                short* __restrict__ hbf,
                                                int* __restrict__ cnt,
                                                int* __restrict__ list){
  __shared__ __align__(16) short As[3][128*32];
  __shared__ __align__(16) short Bs[3][64*32];
  __shared__ int rows[128];
  int bid = blockIdx.x;
  int swz = (bid & 7)*64 + (bid >> 3);     // XCD-contiguous: one XCD = 8 consecutive experts
  int e = swz >> 3, n0 = (swz & 7)*64;
  int tid = threadIdx.x;
  if (tid < 128) rows[tid] = topi[e*TCAP + tid];
  __syncthreads();
  // piggyback: n0==0 blocks build the token -> ye-row inverse index (cnt zeroed by k_topk2)
  if (n0 == 0 && tid < 128){
    int n = rows[tid];
    int slot = atomicAdd(&cnt[n], 1);
    list[n*64 + slot] = e*TCAP + tid;
  }
  int r4 = tid >> 2;
  int cs = (((tid & 3) ^ ((r4 >> 1) & 3)))*8;     // swizzled source k-chunk (shorts)
  const short* sA0 = xbf + (size_t)rows[r4]*TF + cs;
  const short* sA1 = xbf + (size_t)rows[r4 + 64]*TF + cs;
  const short* sB  = W1t + ((size_t)e*TF + n0 + r4)*TF + cs;

  int w = tid >> 6, l = tid & 63;
  int lr = l & 15, lh = l >> 4;
  int ch = (lh ^ ((lr >> 1) & 3))*8;              // swizzled read chunk (shorts)
  int aOff0 = (32*w + lr)*32 + ch;
  int aOff1 = aOff0 + 16*32;
  int bOff0 = lr*32 + ch;

  f32x4 acc[2][4];
  #pragma unroll
  for (int m = 0; m < 2; m++)
    #pragma unroll
    for (int j = 0; j < 4; j++)
      #pragma unroll
      for (int r = 0; r < 4; r++) acc[m][j][r] = 0.f;

  // prologue: stage steps 0 and 1
  gload16(sA0, &As[0][tid*8]);
  gload16(sA1, &As[0][2048 + tid*8]);
  gload16(sB,  &Bs[0][tid*8]);
  gload16(sA0 + 32, &As[1][tid*8]);
  gload16(sA1 + 32, &As[1][2048 + tid*8]);
  gload16(sB  + 32, &Bs[1][tid*8]);

  int cur = 0;
  for (int t16 = 0; t16 < 16; t16++){
    if (t16 < 14){
      int kk = (t16+2)*32;
      int ld = cur + 2; if (ld >= 3) ld -= 3;
      gload16(sA0 + kk, &As[ld][tid*8]);
      gload16(sA1 + kk, &As[ld][2048 + tid*8]);
      gload16(sB  + kk, &Bs[ld][tid*8]);
      asm volatile("s_waitcnt vmcnt(6)" ::: "memory");
    } else if (t16 == 14){
      asm volatile("s_waitcnt vmcnt(3)" ::: "memory");
    } else {
      asm volatile("s_waitcnt vmcnt(0)" ::: "memory");
    }
    __builtin_amdgcn_sched_barrier(0);
    __builtin_amdgcn_s_barrier();          // current buffer loaded by ALL waves
    __builtin_amdgcn_sched_barrier(0);
    bf16x8 a0 = *(const bf16x8*)&As[cur][aOff0];
    bf16x8 a1 = *(const bf16x8*)&As[cur][aOff1];
    #pragma unroll
    for (int j = 0; j < 4; j++){
      bf16x8 b = *(const bf16x8*)&Bs[cur][bOff0 + j*16*32];
      acc[0][j] = __builtin_amdgcn_mfma_f32_16x16x32_bf16(a0, b, acc[0][j], 0, 0, 0);
      acc[1][j] = __builtin_amdgcn_mfma_f32_16x16x32_bf16(a1, b, acc[1][j], 0, 0, 0);
    }
    __builtin_amdgcn_sched_barrier(0);
    __builtin_amdgcn_s_barrier();          // all waves done reading -> safe to overwrite
    cur++; if (cur >= 3) cur = 0;
  }
  short* hdst = hbf + (size_t)e*TCAP*TF;
  #pragma unroll
  for (int m = 0; m < 2; m++)
    #pragma unroll
    for (int j = 0; j < 4; j++)
      #pragma unroll
      for (int r = 0; r < 4; r++){
        int row = 32*w + 16*m + lh*4 + r;
        int col = n0 + 16*j + lr;
        hdst[(size_t)row*TF + col] = f2bf(gelu_tanh(acc[m][j][r]));
      }
}

__global__ __launch_bounds__(256) void k_gemm2c(const short* __restrict__ hbf,
                                                const short* __restrict__ W2t,
                                                const int* __restrict__ topi,
                                                const float* __restrict__ topv,
                                                float* __restrict__ ye){
  __shared__ __align__(16) short As[3][128*32];
  __shared__ __align__(16) short Bs[3][64*32];
  __shared__ float tv[128];
  int bid = blockIdx.x;
  int swz = (bid & 7)*64 + (bid >> 3);
  int e = swz >> 3, n0 = (swz & 7)*64;
  int tid = threadIdx.x;
  if (tid < 128) tv[tid] = topv[e*TCAP + tid];
  __syncthreads();
  int r4 = tid >> 2;
  int cs = (((tid & 3) ^ ((r4 >> 1) & 3)))*8;
  const short* sA0 = hbf + ((size_t)e*TCAP + r4)*TF + cs;
  const short* sA1 = sA0 + (size_t)64*TF;
  const short* sB  = W2t + ((size_t)e*TF + n0 + r4)*TF + cs;

  int w = tid >> 6, l = tid & 63;
  int lr = l & 15, lh = l >> 4;
  int ch = (lh ^ ((lr >> 1) & 3))*8;
  int aOff0 = (32*w + lr)*32 + ch;
  int aOff1 = aOff0 + 16*32;
  int bOff0 = lr*32 + ch;

  f32x4 acc[2][4];
  #pragma unroll
  for (int m = 0; m < 2; m++)
    #pragma unroll
    for (int j = 0; j < 4; j++)
      #pragma unroll
      for (int r = 0; r < 4; r++) acc[m][j][r] = 0.f;

  gload16(sA0, &As[0][tid*8]);
  gload16(sA1, &As[0][2048 + tid*8]);
  gload16(sB,  &Bs[0][tid*8]);
  gload16(sA0 + 32, &As[1][tid*8]);
  gload16(sA1 + 32, &As[1][2048 + tid*8]);
  gload16(sB  + 32, &Bs[1][tid*8]);

  int cur = 0;
  for (int t16 = 0; t16 < 16; t16++){
    if (t16 < 14){
      int kk = (t16+2)*32;
      int ld = cur + 2; if (ld >= 3) ld -= 3;
      gload16(sA0 + kk, &As[ld][tid*8]);
      gload16(sA1 + kk, &As[ld][2048 + tid*8]);
      gload16(sB  + kk, &Bs[ld][tid*8]);
      asm volatile("s_waitcnt vmcnt(6)" ::: "memory");
    } else if (t16 == 14){
      asm volatile("s_waitcnt vmcnt(3)" ::: "memory");
    } else {
      asm volatile("s_waitcnt vmcnt(0)" ::: "memory");
    }
    __builtin_amdgcn_sched_barrier(0);
    __builtin_amdgcn_s_barrier();
    __builtin_amdgcn_sched_barrier(0);
    bf16x8 a0 = *(const bf16x8*)&As[cur][aOff0];
    bf16x8 a1 = *(const bf16x8*)&As[cur][aOff1];
    #pragma unroll
    for (int j = 0; j < 4; j++){
      bf16x8 b = *(const bf16x8*)&Bs[cur][bOff0 + j*16*32];
      acc[0][j] = __builtin_amdgcn_mfma_f32_16x16x32_bf16(a0, b, acc[0][j], 0, 0, 0);
      acc[1][j] = __builtin_amdgcn_mfma_f32_16x16x32_bf16(a1, b, acc[1][j], 0, 0, 0);
    }
    __builtin_amdgcn_sched_barrier(0);
    __builtin_amdgcn_s_barrier();
    cur++; if (cur >= 3) cur = 0;
  }
  // dense ye write (scaled by gate value) — no atomics
  float* ydst = ye + (size_t)e*TCAP*TF;
  #pragma unroll
  for (int m = 0; m < 2; m++)
    #pragma unroll
    for (int j = 0; j < 4; j++)
      #pragma unroll
      for (int r = 0; r < 4; r++){
        int row = 32*w + 16*m + lh*4 + r;
        int col = n0 + 16*j + lr;
        ydst[(size_t)row*TF + col] = acc[m][j][r] * tv[row];
      }
}

extern "C" void kernel_launch(void* const* d_in, const int* in_sizes, int n_in,
                              void* d_out, int out_size, void* d_ws, size_t ws_size,
                              hipStream_t stream){
  (void)in_sizes; (void)n_in; (void)out_size; (void)ws_size;
  const float* x_stream = (const float*)d_in[0];
  const float* gains    = (const float*)d_in[1];
  const float* Wg       = (const float*)d_in[2];
  const float* Wr       = (const float*)d_in[3];
  const float* W1       = (const float*)d_in[4];
  const float* W2       = (const float*)d_in[5];
  const float* cosp     = (const float*)d_in[6];
  const float* sinp     = (const float*)d_in[7];

  size_t off = 0;
  char* base = (char*)d_ws;
  auto alloc = [&](size_t bytes) -> void* {
    void* p = base + off;
    off += (bytes + 255) & ~(size_t)255;
    return p;
  };
  float* X0      = (float*)alloc((size_t)TN*TF*4);   // x ping
  float* X1      = (float*)alloc((size_t)TN*TF*4);   // x pong
  float* x_targ  = (float*)alloc((size_t)TN*TF*4);
  short* xf_bf   = (short*)alloc((size_t)TN*TF*2);
  float* gateb   = (float*)alloc((size_t)TN*TE*4);
  float* scoresT = (float*)alloc((size_t)TE*TN*4);
  int*   topi    = (int*)  alloc((size_t)TE*TCAP*4);
  float* topv    = (float*)alloc((size_t)TE*TCAP*4);
  short* h_bf    = (short*)alloc((size_t)TE*TCAP*TF*2);
  float* ye      = (float*)alloc((size_t)TE*TCAP*TF*4);   // dense expert outputs (scaled)
  int*   cnt     = (int*)  alloc((size_t)TN*4);
  int*   list    = (int*)  alloc((size_t)TN*64*4);
  short* W1t     = (short*)alloc((size_t)TE*TF*TF*2);
  short* W2t     = (short*)alloc((size_t)TE*TF*TF*2);

  k_init<<<(TN*TD + 255)/256, 256, 0, stream>>>(x_stream, cosp, sinp, X0, x_targ);
  k_gatebias<<<TN, 64, 0, stream>>>(X0, Wg, gateb);
  k_castw<<<dim3(64, TE), 256, 0, stream>>>(W1, W1t);
  k_castw<<<dim3(64, TE), 256, 0, stream>>>(W2, W2t);

  float* cur = X0;   // x_state(0)
  float* nxt = X1;
  for (int it = 0; it < NITER; it++){
    if (it > 0){
      // x_state(it) = update(x_state(it-1), pred(it-1)); each row combined once
      k_combine<<<TN/8, 256, 0, stream>>>(cur, nxt, x_targ, ye, cnt, list);
      float* tmp = cur; cur = nxt; nxt = tmp;
    }
    k_fuse2<<<TN/8, 256, 0, stream>>>(cur, gains, Wr, gateb, xf_bf, scoresT);
    k_topk2<<<TE, 1024, 0, stream>>>(scoresT, topi, topv, cnt);
    k_gemm1c<<<TF/64*TE, 256, 0, stream>>>(xf_bf, W1t, topi, h_bf, cnt, list);
    k_gemm2c<<<TF/64*TE, 256, 0, stream>>>(h_bf, W2t, topi, topv, ye);
  }
  // out = x_state(8) = update(x_state(7), pred(7))
  k_combine<<<TN/8, 256, 0, stream>>>(cur, (float*)d_out, x_targ, ye, cnt, list);
}

// Round 10
// 628.905 us; speedup vs baseline: 2.4754x; 1.0532x over previous
//
#include <hip/hip_runtime.h>
#include <hip/hip_bf16.h>

#define TB 2
#define TT 2048
#define TD 256
#define TE 64
#define TF 512
#define TN 4096      // TB*TT
#define TCAP 128     // 2*TN/TE
#define NITER 8

typedef __attribute__((ext_vector_type(8))) short bf16x8;
typedef __attribute__((ext_vector_type(4))) float f32x4;

__device__ inline float sanitize(float v){
  if (v != v) return 0.0f;
  const float FMAX = 3.402823466e+38f;
  if (v >  FMAX) return  FMAX;
  if (v < -FMAX) return -FMAX;
  return v;
}

__device__ inline short f2bf(float f){
  union { __hip_bfloat16 h; short s; } u;
  u.h = __float2bfloat16(f);
  return u.s;
}

__device__ inline float gelu_tanh(float x){
  float x3 = x*x*x;
  return 0.5f*x*(1.0f + tanhf(0.7978845608028654f*(x + 0.044715f*x3)));
}

// async global->LDS, 16B per lane; dest = wave-uniform base + lane*16
__device__ __forceinline__ void gload16(const void* g, void* l){
  __builtin_amdgcn_global_load_lds(
      (__attribute__((address_space(1))) void*)g,
      (__attribute__((address_space(3))) void*)l, 16, 0, 0);
}

// ---------------- setup kernels ----------------

__global__ void k_init(const float* __restrict__ xs, const float* __restrict__ cosp,
                       const float* __restrict__ sinp, float* __restrict__ xw,
                       float* __restrict__ xt){
  int idx = blockIdx.x*256 + threadIdx.x;          // over TN*TD
  if (idx >= TN*TD) return;
  int d = idx & (TD-1);
  int n = idx >> 8;
  int t = n & (TT-1);
  float xr = sanitize(xs[2*idx]), xi = sanitize(xs[2*idx+1]);
  xw[2*idx] = xr; xw[2*idx+1] = xi;
  float tr, ti;
  if (t == 0){ tr = xr; ti = xi; }
  else {
    float pr = sanitize(xs[2*(idx-TD)]), pi = sanitize(xs[2*(idx-TD)+1]);
    float c = cosp[d], s = sinp[d];
    tr = pr*c - pi*s;
    ti = pr*s + pi*c;
  }
  xt[2*idx] = tr; xt[2*idx+1] = ti;
}

__global__ __launch_bounds__(64) void k_gatebias(const float* __restrict__ xw,
                                                 const float* __restrict__ wg,
                                                 float* __restrict__ gb){
  __shared__ float mag[TD];
  int n = blockIdx.x, t = threadIdx.x;
  for (int d = t; d < TD; d += 64){
    float xr = xw[(size_t)n*TF + 2*d], xi = xw[(size_t)n*TF + 2*d + 1];
    mag[d] = sqrtf(xr*xr + xi*xi + 1e-8f);
  }
  __syncthreads();
  float acc = 0.f;
  for (int d = 0; d < TD; d++) acc += mag[d]*wg[d*TE + t];
  gb[(size_t)n*TE + t] = acc;
}

// cast+transpose weights: in f32 [e][k][n] -> out bf16 [e][n][k]
__global__ __launch_bounds__(256) void k_castw(const float* __restrict__ W, short* __restrict__ Wt){
  __shared__ float tile[64][68];
  int e = blockIdx.y;
  int kt = (blockIdx.x >> 3) * 64;
  int nt = (blockIdx.x & 7) * 64;
  int tid = threadIdx.x;
  {
    int row = tid >> 4;
    int c4 = (tid & 15) * 4;
    #pragma unroll
    for (int i = 0; i < 4; i++){
      int r = row + i*16;
      float4 v = *(const float4*)(W + ((size_t)e*TF + kt + r)*TF + nt + c4);
      *(float4*)&tile[r][c4] = v;
    }
  }
  __syncthreads();
  #pragma unroll
  for (int i = 0; i < 2; i++){
    int un = tid + i*256;
    int nrow = un >> 3;
    int k8 = (un & 7) * 8;
    bf16x8 o;
    #pragma unroll
    for (int j = 0; j < 8; j++) o[j] = f2bf(tile[k8+j][nrow]);
    *(bf16x8*)(Wt + ((size_t)e*TF + nt + nrow)*TF + kt + k8) = o;
  }
}

// ---------------- combine: xNew = xOld + clip(lr*(xt - gather(ye))) ----------------

__global__ __launch_bounds__(256) void k_combine(
    const float* __restrict__ xOld, float* __restrict__ xNew,
    const float* __restrict__ xt, const float* __restrict__ ye,
    const int* __restrict__ cnt, const int* __restrict__ list)
{
  int tid = threadIdx.x;
  int tok = tid >> 5;
  int kq  = (tid & 31) * 16;
  int n   = blockIdx.x*8 + tok;
  size_t off = (size_t)n*TF + kq;
  float p[16];
  #pragma unroll
  for (int q = 0; q < 16; q++) p[q] = 0.f;
  int c = cnt[n];
  for (int j = 0; j < c; j++){
    const float4* s = (const float4*)(ye + (size_t)list[n*64 + j]*TF + kq);
    #pragma unroll
    for (int k4 = 0; k4 < 4; k4++){
      float4 v = s[k4];
      p[4*k4+0] += v.x; p[4*k4+1] += v.y; p[4*k4+2] += v.z; p[4*k4+3] += v.w;
    }
  }
  const float4* a4 = (const float4*)(xOld + off);
  const float4* t4 = (const float4*)(xt + off);
  float4* o4 = (float4*)(xNew + off);
  #pragma unroll
  for (int j = 0; j < 4; j++){
    float4 a = a4[j], t = t4[j], o;
    float u;
    u = 0.05f*(t.x - p[4*j+0]); u = fminf(10.f, fmaxf(-10.f, u)); o.x = a.x + u;
    u = 0.05f*(t.y - p[4*j+1]); u = fminf(10.f, fmaxf(-10.f, u)); o.y = a.y + u;
    u = 0.05f*(t.z - p[4*j+2]); u = fminf(10.f, fmaxf(-10.f, u)); o.z = a.z + u;
    u = 0.05f*(t.w - p[4*j+3]); u = fminf(10.f, fmaxf(-10.f, u)); o.w = a.w + u;
    o4[j] = o;
  }
}

// ---------------- delay embed + router + bf16 cast (dense x_state input) ----------------

__global__ __launch_bounds__(256) void k_fuse2(
    const float* __restrict__ xcur, const float* __restrict__ g,
    const float* __restrict__ wr, const float* __restrict__ gb,
    short* __restrict__ xbf, float* __restrict__ scoresT)
{
  __shared__ float xeff[8][516];
  __shared__ float Bt[64][68];
  int tid = threadIdx.x;
  int tok = tid >> 5;            // 0..7
  int lane5 = tid & 31;
  int kq  = lane5 * 16;          // 16 consecutive floats
  int n   = blockIdx.x*8 + tok;
  int t   = n & (TT-1);
  size_t rowoff = (size_t)n*TF + kq;

  float eff[16];
  {
    const float4* a4 = (const float4*)(xcur + rowoff);
    #pragma unroll
    for (int j = 0; j < 4; j++){
      float4 v = a4[j];
      eff[4*j+0] = v.x; eff[4*j+1] = v.y; eff[4*j+2] = v.z; eff[4*j+3] = v.w;
    }
  }
  const int taus[4] = {1,2,3,5};
  int d0 = kq >> 1;
  #pragma unroll
  for (int i = 0; i < 4; i++){
    int tau = taus[i];
    if (t >= tau){
      const float4* b4 = (const float4*)(xcur + rowoff - (size_t)tau*TF);
      float nb[16];
      #pragma unroll
      for (int j = 0; j < 4; j++){
        float4 v = b4[j];
        nb[4*j+0] = v.x; nb[4*j+1] = v.y; nb[4*j+2] = v.z; nb[4*j+3] = v.w;
      }
      #pragma unroll
      for (int p = 0; p < 8; p++){
        float gr = g[2*(i*TD + d0 + p)];
        float gi = g[2*(i*TD + d0 + p) + 1];
        eff[2*p]   += nb[2*p]*gr - nb[2*p+1]*gi;
        eff[2*p+1] += nb[2*p]*gi + nb[2*p+1]*gr;
      }
    }
  }
  {
    bf16x8 o0, o1;
    #pragma unroll
    for (int q = 0; q < 8; q++){ o0[q] = f2bf(eff[q]); o1[q] = f2bf(eff[8+q]); }
    *(bf16x8*)(xbf + rowoff)     = o0;
    *(bf16x8*)(xbf + rowoff + 8) = o1;
    #pragma unroll
    for (int jj = 0; jj < 4; jj++){
      int j = (jj + lane5) & 3;
      *(float4*)&xeff[tok][kq + 4*j] =
        make_float4(eff[4*j], eff[4*j+1], eff[4*j+2], eff[4*j+3]);
    }
  }
  __syncthreads();

  // router: thread (tok, tx) computes experts {2tx, 2tx+1} for token n
  int tx = lane5;
  float acc0 = gb[(size_t)n*TE + 2*tx];
  float acc1 = gb[(size_t)n*TE + 2*tx + 1];
  int rB = tid >> 2, c16 = (tid & 3)*16;
  for (int kk = 0; kk < TF; kk += 64){
    #pragma unroll
    for (int jj = 0; jj < 4; jj++)
      *(float4*)&Bt[rB][c16 + 4*jj] = *(const float4*)(wr + (size_t)(kk+rB)*TE + c16 + 4*jj);
    __syncthreads();
    #pragma unroll
    for (int k = 0; k < 64; k++){
      float a = xeff[tok][kk + k];
      float2 b = *(const float2*)&Bt[k][2*tx];
      acc0 += a*b.x; acc1 += a*b.y;
    }
    __syncthreads();
  }
  float m = fmaxf(acc0, acc1);
  #pragma unroll
  for (int off = 1; off < 32; off <<= 1) m = fmaxf(m, __shfl_xor(m, off));
  float e0 = expf(acc0 - m), e1 = expf(acc1 - m);
  float s = e0 + e1;
  #pragma unroll
  for (int off = 1; off < 32; off <<= 1) s += __shfl_xor(s, off);
  float inv = 1.0f / s;
  scoresT[(size_t)(2*tx)*TN + n]     = e0*inv;
  scoresT[(size_t)(2*tx+1)*TN + n]   = e1*inv;
}

// per-expert exact top-128: registers + 3-round radix, parallel threshold find.
__global__ __launch_bounds__(1024) void k_topk2(const float* __restrict__ scoresT,
                                                int* __restrict__ topi, float* __restrict__ topv,
                                                int* __restrict__ cnt){
  int e = blockIdx.x;
  const float* sc = scoresT + (size_t)e*TN;
  __shared__ unsigned int hist[4096];
  __shared__ unsigned int chunkSum[64];
  __shared__ unsigned int s_prefix;
  __shared__ int s_k, s_cnt, s_min;
  int tid = threadIdx.x;
  if (tid < 64) cnt[e*64 + tid] = 0;
  unsigned int u[4];
  #pragma unroll
  for (int i = 0; i < 4; i++) u[i] = __float_as_uint(sc[tid + i*1024]);
  if (tid == 0){ s_prefix = 0u; s_k = TCAP; }

  const int shifts[3]  = {20, 8, 0};
  const int nbins[3]   = {4096, 4096, 256};
  const unsigned int pmasks[3] = {0u, 0xFFF00000u, 0xFFFFFF00u};
  for (int r = 0; r < 3; r++){
    int shift = shifts[r], nb = nbins[r];
    unsigned int bmask = (unsigned)nb - 1u;
    int logC = (nb == 4096) ? 6 : 2;     // bins per chunk: nb/64
    for (int i = tid; i < nb; i += 1024) hist[i] = 0u;
    if (tid < 64) chunkSum[tid] = 0u;
    __syncthreads();
    unsigned int pref = s_prefix;
    unsigned int pmask = pmasks[r];
    #pragma unroll
    for (int i = 0; i < 4; i++)
      if ((u[i] & pmask) == pref) atomicAdd(&hist[(u[i] >> shift) & bmask], 1u);
    __syncthreads();
    for (int b = tid; b < nb; b += 1024){
      unsigned int h = hist[b];
      if (h) atomicAdd(&chunkSum[b >> logC], h);
    }
    __syncthreads();
    if (tid < 64){
      int chunk = 63 - tid;                     // lane order = descending chunk
      unsigned int s = chunkSum[chunk];
      unsigned int scan = s;
      #pragma unroll
      for (int d = 1; d < 64; d <<= 1){
        unsigned int t = __shfl_up(scan, d);
        if (tid >= d) scan += t;
      }
      unsigned int excl = scan - s;
      int k = s_k;
      if (excl < (unsigned)k && scan >= (unsigned)k){
        int C = 1 << logC;
        unsigned int cum = excl;
        for (int b = C-1; b >= 0; b--){
          unsigned int h = hist[(chunk << logC) + b];
          cum += h;
          if (cum >= (unsigned)k){
            s_k = k - (int)(cum - h);
            s_prefix = pref | ((unsigned)((chunk << logC) + b) << shift);
            break;
          }
        }
      }
    }
    __syncthreads();
  }
  unsigned int thr = s_prefix;
  int need_eq = s_k;
  if (tid == 0) s_cnt = 0;
  __syncthreads();
  #pragma unroll
  for (int i = 0; i < 4; i++){
    if (u[i] > thr){
      int p = atomicAdd(&s_cnt, 1);
      topi[e*TCAP + p] = tid + i*1024;
      topv[e*TCAP + p] = __uint_as_float(u[i]);
    }
  }
  __syncthreads();
  int base = s_cnt;
  int last = -1;
  for (int i = 0; i < need_eq; i++){
    __syncthreads();
    if (tid == 0) s_min = TN;
    __syncthreads();
    #pragma unroll
    for (int j = 0; j < 4; j++){
      int n = tid + j*1024;
      if (u[j] == thr && n > last) atomicMin(&s_min, n);
    }
    __syncthreads();
    int nsel = s_min;
    if (tid == 0){ topi[e*TCAP + base + i] = nsel; topv[e*TCAP + base + i] = __uint_as_float(thr); }
    last = nsel;
  }
}

// ---- GEMMs: bf16 Wt [e][n][k], BK=64, gload_lds + involution swizzle + counted vmcnt ----
// Stage: issue i covers rows [i*32,i*32+32); thread -> (row = i*32 + tid/8, chunk_pos = tid%8),
// global chunk = pos ^ (row&7); LDS dest linear (i*2048 + tid*8 shorts). Read: logical chunk
// c = kk*4+lh of row r lives at pos c ^ (r&7). Bank-group == pos -> 2-way max (free).

__global__ __launch_bounds__(256) void k_gemm1c(const short* __restrict__ xbf,
                                                const short* __restrict__ W1t,
                                                const int* __restrict__ topi,
                                                short* __restrict__ hbf,
                                                int* __restrict__ cnt,
                                                int* __restrict__ list){
  __shared__ __align__(16) short As[2][128*64];
  __shared__ __align__(16) short Bs[2][64*64];
  __shared__ int rows[128];
  int bid = blockIdx.x;
  int swz = (bid & 7)*64 + (bid >> 3);     // XCD-contiguous: one XCD = 8 consecutive experts
  int e = swz >> 3, n0 = (swz & 7)*64;
  int tid = threadIdx.x;
  if (tid < 128) rows[tid] = topi[e*TCAP + tid];
  __syncthreads();
  // piggyback: n0==0 blocks build token -> ye-row inverse index (cnt zeroed by k_topk2)
  if (n0 == 0 && tid < 128){
    int n = rows[tid];
    int slot = atomicAdd(&cnt[n], 1);
    list[n*64 + slot] = e*TCAP + tid;
  }
  int rsub = tid >> 3;                                // 0..31
  int cs = ((tid & 7) ^ (rsub & 7))*8;                // swizzled source chunk (shorts)
  const short* sA0 = xbf + (size_t)rows[rsub      ]*TF + cs;
  const short* sA1 = xbf + (size_t)rows[rsub +  32]*TF + cs;
  const short* sA2 = xbf + (size_t)rows[rsub +  64]*TF + cs;
  const short* sA3 = xbf + (size_t)rows[rsub +  96]*TF + cs;
  const short* sB0 = W1t + ((size_t)e*TF + n0 + rsub)*TF + cs;
  const short* sB1 = sB0 + (size_t)32*TF;

  int w = tid >> 6, l = tid & 63;
  int lr = l & 15, lh = l >> 4;
  int lx = lr & 7;
  int ar0 = (32*w + lr)*64;
  int ar1 = ar0 + 16*64;
  int p0 = (lh ^ lx)*8;            // kk=0 chunk pos (shorts)
  int p1 = ((4 + lh) ^ lx)*8;      // kk=1

  f32x4 acc[2][4];
  #pragma unroll
  for (int m = 0; m < 2; m++)
    #pragma unroll
    for (int j = 0; j < 4; j++)
      #pragma unroll
      for (int r = 0; r < 4; r++) acc[m][j][r] = 0.f;

  // prologue: stage step 0 into buf 0
  gload16(sA0, &As[0][        tid*8]);
  gload16(sA1, &As[0][2048 +  tid*8]);
  gload16(sA2, &As[0][4096 +  tid*8]);
  gload16(sA3, &As[0][6144 +  tid*8]);
  gload16(sB0, &Bs[0][        tid*8]);
  gload16(sB1, &Bs[0][2048 +  tid*8]);

  int cur = 0;
  for (int t = 0; t < 8; t++){
    if (t < 7){
      int kk = (t+1)*64;
      gload16(sA0 + kk, &As[cur^1][        tid*8]);
      gload16(sA1 + kk, &As[cur^1][2048 +  tid*8]);
      gload16(sA2 + kk, &As[cur^1][4096 +  tid*8]);
      gload16(sA3 + kk, &As[cur^1][6144 +  tid*8]);
      gload16(sB0 + kk, &Bs[cur^1][        tid*8]);
      gload16(sB1 + kk, &Bs[cur^1][2048 +  tid*8]);
      asm volatile("s_waitcnt vmcnt(6)" ::: "memory");
    } else {
      asm volatile("s_waitcnt vmcnt(0)" ::: "memory");
    }
    __builtin_amdgcn_sched_barrier(0);
    __builtin_amdgcn_s_barrier();          // current buffer loaded by ALL waves
    __builtin_amdgcn_sched_barrier(0);
    #pragma unroll
    for (int kk = 0; kk < 2; kk++){
      int pc = kk ? p1 : p0;
      bf16x8 a0 = *(const bf16x8*)&As[cur][ar0 + pc];
      bf16x8 a1 = *(const bf16x8*)&As[cur][ar1 + pc];
      #pragma unroll
      for (int j = 0; j < 4; j++){
        bf16x8 b = *(const bf16x8*)&Bs[cur][(16*j + lr)*64 + pc];
        acc[0][j] = __builtin_amdgcn_mfma_f32_16x16x32_bf16(a0, b, acc[0][j], 0, 0, 0);
        acc[1][j] = __builtin_amdgcn_mfma_f32_16x16x32_bf16(a1, b, acc[1][j], 0, 0, 0);
      }
    }
    __builtin_amdgcn_sched_barrier(0);
    __builtin_amdgcn_s_barrier();          // all waves done reading -> safe to overwrite
    cur ^= 1;
  }
  short* hdst = hbf + (size_t)e*TCAP*TF;
  #pragma unroll
  for (int m = 0; m < 2; m++)
    #pragma unroll
    for (int j = 0; j < 4; j++)
      #pragma unroll
      for (int r = 0; r < 4; r++){
        int row = 32*w + 16*m + lh*4 + r;
        int col = n0 + 16*j + lr;
        hdst[(size_t)row*TF + col] = f2bf(gelu_tanh(acc[m][j][r]));
      }
}

__global__ __launch_bounds__(256) void k_gemm2c(const short* __restrict__ hbf,
                                                const short* __restrict__ W2t,
                                                const int* __restrict__ topi,
                                                const float* __restrict__ topv,
                                                float* __restrict__ ye){
  __shared__ __align__(16) short As[2][128*64];
  __shared__ __align__(16) short Bs[2][64*64];
  __shared__ float tv[128];
  int bid = blockIdx.x;
  int swz = (bid & 7)*64 + (bid >> 3);
  int e = swz >> 3, n0 = (swz & 7)*64;
  int tid = threadIdx.x;
  if (tid < 128) tv[tid] = topv[e*TCAP + tid];
  __syncthreads();
  int rsub = tid >> 3;
  int cs = ((tid & 7) ^ (rsub & 7))*8;
  const short* sA0 = hbf + ((size_t)e*TCAP + rsub)*TF + cs;
  const short* sA1 = sA0 + (size_t)32*TF;
  const short* sA2 = sA0 + (size_t)64*TF;
  const short* sA3 = sA0 + (size_t)96*TF;
  const short* sB0 = W2t + ((size_t)e*TF + n0 + rsub)*TF + cs;
  const short* sB1 = sB0 + (size_t)32*TF;

  int w = tid >> 6, l = tid & 63;
  int lr = l & 15, lh = l >> 4;
  int lx = lr & 7;
  int ar0 = (32*w + lr)*64;
  int ar1 = ar0 + 16*64;
  int p0 = (lh ^ lx)*8;
  int p1 = ((4 + lh) ^ lx)*8;

  f32x4 acc[2][4];
  #pragma unroll
  for (int m = 0; m < 2; m++)
    #pragma unroll
    for (int j = 0; j < 4; j++)
      #pragma unroll
      for (int r = 0; r < 4; r++) acc[m][j][r] = 0.f;

  gload16(sA0, &As[0][        tid*8]);
  gload16(sA1, &As[0][2048 +  tid*8]);
  gload16(sA2, &As[0][4096 +  tid*8]);
  gload16(sA3, &As[0][6144 +  tid*8]);
  gload16(sB0, &Bs[0][        tid*8]);
  gload16(sB1, &Bs[0][2048 +  tid*8]);

  int cur = 0;
  for (int t = 0; t < 8; t++){
    if (t < 7){
      int kk = (t+1)*64;
      gload16(sA0 + kk, &As[cur^1][        tid*8]);
      gload16(sA1 + kk, &As[cur^1][2048 +  tid*8]);
      gload16(sA2 + kk, &As[cur^1][4096 +  tid*8]);
      gload16(sA3 + kk, &As[cur^1][6144 +  tid*8]);
      gload16(sB0 + kk, &Bs[cur^1][        tid*8]);
      gload16(sB1 + kk, &Bs[cur^1][2048 +  tid*8]);
      asm volatile("s_waitcnt vmcnt(6)" ::: "memory");
    } else {
      asm volatile("s_waitcnt vmcnt(0)" ::: "memory");
    }
    __builtin_amdgcn_sched_barrier(0);
    __builtin_amdgcn_s_barrier();
    __builtin_amdgcn_sched_barrier(0);
    #pragma unroll
    for (int kk = 0; kk < 2; kk++){
      int pc = kk ? p1 : p0;
      bf16x8 a0 = *(const bf16x8*)&As[cur][ar0 + pc];
      bf16x8 a1 = *(const bf16x8*)&As[cur][ar1 + pc];
      #pragma unroll
      for (int j = 0; j < 4; j++){
        bf16x8 b = *(const bf16x8*)&Bs[cur][(16*j + lr)*64 + pc];
        acc[0][j] = __builtin_amdgcn_mfma_f32_16x16x32_bf16(a0, b, acc[0][j], 0, 0, 0);
        acc[1][j] = __builtin_amdgcn_mfma_f32_16x16x32_bf16(a1, b, acc[1][j], 0, 0, 0);
      }
    }
    __builtin_amdgcn_sched_barrier(0);
    __builtin_amdgcn_s_barrier();
    cur ^= 1;
  }
  // dense ye write (scaled by gate value) — no atomics
  float* ydst = ye + (size_t)e*TCAP*TF;
  #pragma unroll
  for (int m = 0; m < 2; m++)
    #pragma unroll
    for (int j = 0; j < 4; j++)
      #pragma unroll
      for (int r = 0; r < 4; r++){
        int row = 32*w + 16*m + lh*4 + r;
        int col = n0 + 16*j + lr;
        ydst[(size_t)row*TF + col] = acc[m][j][r] * tv[row];
      }
}

extern "C" void kernel_launch(void* const* d_in, const int* in_sizes, int n_in,
                              void* d_out, int out_size, void* d_ws, size_t ws_size,
                              hipStream_t stream){
  (void)in_sizes; (void)n_in; (void)out_size; (void)ws_size;
  const float* x_stream = (const float*)d_in[0];
  const float* gains    = (const float*)d_in[1];
  const float* Wg       = (const float*)d_in[2];
  const float* Wr       = (const float*)d_in[3];
  const float* W1       = (const float*)d_in[4];
  const float* W2       = (const float*)d_in[5];
  const float* cosp     = (const float*)d_in[6];
  const float* sinp     = (const float*)d_in[7];

  size_t off = 0;
  char* base = (char*)d_ws;
  auto alloc = [&](size_t bytes) -> void* {
    void* p = base + off;
    off += (bytes + 255) & ~(size_t)255;
    return p;
  };
  float* X0      = (float*)alloc((size_t)TN*TF*4);   // x ping
  float* X1      = (float*)alloc((size_t)TN*TF*4);   // x pong
  float* x_targ  = (float*)alloc((size_t)TN*TF*4);
  short* xf_bf   = (short*)alloc((size_t)TN*TF*2);
  float* gateb   = (float*)alloc((size_t)TN*TE*4);
  float* scoresT = (float*)alloc((size_t)TE*TN*4);
  int*   topi    = (int*)  alloc((size_t)TE*TCAP*4);
  float* topv    = (float*)alloc((size_t)TE*TCAP*4);
  short* h_bf    = (short*)alloc((size_t)TE*TCAP*TF*2);
  float* ye      = (float*)alloc((size_t)TE*TCAP*TF*4);   // dense expert outputs (scaled)
  int*   cnt     = (int*)  alloc((size_t)TN*4);
  int*   list    = (int*)  alloc((size_t)TN*64*4);
  short* W1t     = (short*)alloc((size_t)TE*TF*TF*2);
  short* W2t     = (short*)alloc((size_t)TE*TF*TF*2);

  k_init<<<(TN*TD + 255)/256, 256, 0, stream>>>(x_stream, cosp, sinp, X0, x_targ);
  k_gatebias<<<TN, 64, 0, stream>>>(X0, Wg, gateb);
  k_castw<<<dim3(64, TE), 256, 0, stream>>>(W1, W1t);
  k_castw<<<dim3(64, TE), 256, 0, stream>>>(W2, W2t);

  float* cur = X0;   // x_state(0)
  float* nxt = X1;
  for (int it = 0; it < NITER; it++){
    if (it > 0){
      k_combine<<<TN/8, 256, 0, stream>>>(cur, nxt, x_targ, ye, cnt, list);
      float* tmp = cur; cur = nxt; nxt = tmp;
    }
    k_fuse2<<<TN/8, 256, 0, stream>>>(cur, gains, Wr, gateb, xf_bf, scoresT);
    k_topk2<<<TE, 1024, 0, stream>>>(scoresT, topi, topv, cnt);
    k_gemm1c<<<TF/64*TE, 256, 0, stream>>>(xf_bf, W1t, topi, h_bf, cnt, list);
    k_gemm2c<<<TF/64*TE, 256, 0, stream>>>(h_bf, W2t, topi, topv, ye);
  }
  // out = x_state(8) = update(x_state(7), pred(7))
  k_combine<<<TN/8, 256, 0, stream>>>(cur, (float*)d_out, x_targ, ye, cnt, list);
}